// Round 1
// baseline (1416.526 us; speedup 1.0000x reference)
//
#include <hip/hip_runtime.h>
#include <hip/hip_bf16.h>
#include <math.h>

#define TB 16
#define TS 512
#define TF 512
#define TH 8
#define TFF 2048
#define TL 3

typedef unsigned short u16;
typedef short bf16x8 __attribute__((ext_vector_type(8)));
typedef float f32x4 __attribute__((ext_vector_type(4)));

__device__ __forceinline__ u16 f2b(float f) {
    __hip_bfloat16 h = __float2bfloat16(f);
    return *reinterpret_cast<u16*>(&h);
}

__device__ __forceinline__ void gload_lds16(const void* g, void* l) {
    __builtin_amdgcn_global_load_lds(
        (const __attribute__((address_space(1))) unsigned int*)g,
        (__attribute__((address_space(3))) unsigned int*)l, 16, 0, 0);
}

// ---------------------------------------------------------------------------
// Batched transpose + fp32->bf16: src z matrices K x N (row-major) -> dst N x K
// ---------------------------------------------------------------------------
__global__ __launch_bounds__(256) void k_transpose_w(
    const float* __restrict__ src, u16* __restrict__ dst, int K, int N)
{
    __shared__ float tile[32][33];
    const int z = blockIdx.z;
    src += (size_t)z * K * N;
    dst += (size_t)z * K * N;
    const int n0 = blockIdx.x * 32, k0 = blockIdx.y * 32;
    const int tx = threadIdx.x & 31, ty = threadIdx.x >> 5;  // 32 x 8
    #pragma unroll
    for (int i = 0; i < 32; i += 8)
        tile[ty + i][tx] = src[(size_t)(k0 + ty + i) * N + n0 + tx];
    __syncthreads();
    #pragma unroll
    for (int i = 0; i < 32; i += 8)
        dst[(size_t)(n0 + ty + i) * K + k0 + tx] = f2b(tile[tx][ty + i]);
}

// ---------------------------------------------------------------------------
// fp32 -> fp32 copy + bf16 convert (vectorized by 4)
// ---------------------------------------------------------------------------
__global__ __launch_bounds__(256) void k_cvt(
    const float* __restrict__ src, float* __restrict__ d32,
    u16* __restrict__ d16, int n4)
{
    const int i = blockIdx.x * 256 + threadIdx.x;
    if (i >= n4) return;
    float4 v = ((const float4*)src)[i];
    if (d32) ((float4*)d32)[i] = v;
    ushort4 p;
    p.x = f2b(v.x); p.y = f2b(v.y); p.z = f2b(v.z); p.w = f2b(v.w);
    ((ushort4*)d16)[i] = p;
}

// ---------------------------------------------------------------------------
// bf16 GEMM: C(MxN) = A(MxK) @ BT(NxK)^T + epilogue
// EPI 0: +bias -> bf16 out (ldo, coloff)
// EPI 1: +bias, exact gelu -> bf16 out
// EPI 2: +bias, +resid -> f32 out (ldo==N, coloff==0)
// 128x128 tile, BK=32, 4 waves each 64x64.
// ---------------------------------------------------------------------------
template<int EPI>
__global__ __launch_bounds__(256) void k_gemm(
    const u16* __restrict__ A, const u16* __restrict__ BT,
    const float* __restrict__ bias, const float* __restrict__ resid,
    u16* __restrict__ outb, float* __restrict__ outf,
    int N, int K, int ldo, int coloff)
{
    __shared__ __align__(16) u16 As[128 * 32];
    __shared__ __align__(16) u16 Bs[128 * 32];
    const int bn = blockIdx.x, bm = blockIdx.y;
    const int t = threadIdx.x;
    const int w = t >> 6, l = t & 63;
    const int wm = w >> 1, wn = w & 1;
    const int lhi = l >> 4, llo = l & 15;

    f32x4 acc[4][4];
    #pragma unroll
    for (int m = 0; m < 4; ++m)
        #pragma unroll
        for (int n = 0; n < 4; ++n)
            acc[m][n] = f32x4{0.f, 0.f, 0.f, 0.f};

    const int srow = w * 16 + (l >> 2);
    const int scol = (l & 3) * 8;
    const u16* Ag = A + (size_t)(bm * 128 + srow) * K + scol;
    const u16* Bg = BT + (size_t)(bn * 128 + srow) * K + scol;
    u16* Al = As + w * 512;  // HW adds lane*16B
    u16* Bl = Bs + w * 512;

    for (int kt = 0; kt < K; kt += 32) {
        gload_lds16(Ag + kt,          Al);
        gload_lds16(Ag + 64 * K + kt, Al + 2048);
        gload_lds16(Bg + kt,          Bl);
        gload_lds16(Bg + 64 * K + kt, Bl + 2048);
        __syncthreads();
        bf16x8 af[4], bfr[4];
        #pragma unroll
        for (int m = 0; m < 4; ++m)
            af[m] = *(const bf16x8*)(As + (wm * 64 + m * 16 + llo) * 32 + lhi * 8);
        #pragma unroll
        for (int n = 0; n < 4; ++n)
            bfr[n] = *(const bf16x8*)(Bs + (wn * 64 + n * 16 + llo) * 32 + lhi * 8);
        #pragma unroll
        for (int m = 0; m < 4; ++m)
            #pragma unroll
            for (int n = 0; n < 4; ++n)
                acc[m][n] = __builtin_amdgcn_mfma_f32_16x16x32_bf16(
                    af[m], bfr[n], acc[m][n], 0, 0, 0);
        __syncthreads();
    }

    const int colb = bn * 128 + wn * 64;
    const int rowb = bm * 128 + wm * 64 + lhi * 4;
    #pragma unroll
    for (int n = 0; n < 4; ++n) {
        const int col = colb + n * 16 + llo;
        const float bv = bias[col];
        #pragma unroll
        for (int m = 0; m < 4; ++m) {
            const int row = rowb + m * 16;
            #pragma unroll
            for (int r = 0; r < 4; ++r) {
                float v = acc[m][n][r] + bv;
                const size_t off = (size_t)(row + r) * ldo + coloff + col;
                if (EPI == 0) {
                    outb[off] = f2b(v);
                } else if (EPI == 1) {
                    v = 0.5f * v * (1.f + erff(v * 0.70710678118654752f));
                    outb[off] = f2b(v);
                } else {
                    outf[off] = v + resid[off];
                }
            }
        }
    }
}

// ---------------------------------------------------------------------------
// V transpose per (b,h): vt[bh][d][s] = qkv[b*S+s][1024 + h*64 + d]
// ---------------------------------------------------------------------------
__global__ __launch_bounds__(256) void k_vt(
    const u16* __restrict__ qkv, u16* __restrict__ vt)
{
    __shared__ __align__(16) u16 tile[64][80];
    const int s0 = blockIdx.x * 64;
    const int bh = blockIdx.y;
    const int b = bh >> 3, h = bh & 7;
    const int t = threadIdx.x;
    #pragma unroll
    for (int r = 0; r < 2; ++r) {
        const int idx = r * 256 + t;
        const int s = idx >> 3, d0 = (idx & 7) * 8;
        bf16x8 v = *(const bf16x8*)(qkv + (size_t)(b * TS + s0 + s) * 1536 + 1024 + h * 64 + d0);
        *(bf16x8*)&tile[s][d0] = v;
    }
    __syncthreads();
    #pragma unroll
    for (int r = 0; r < 2; ++r) {
        const int idx = r * 256 + t;
        const int d = idx >> 3, sp = (idx & 7) * 8;
        bf16x8 o;
        #pragma unroll
        for (int u = 0; u < 8; ++u) o[u] = (short)tile[sp + u][d];
        *(bf16x8*)(vt + (size_t)(bh * 64 + d) * 512 + s0 + sp) = o;
    }
}

// ---------------------------------------------------------------------------
// Fused flash attention. qkv: (B*S) x 1536 bf16 (q|k|v), vt: (B*H*64) x 512.
// DEC=0: key valid iff key < len[b].  DEC=1: key < min(max(q,1), len[b]).
// Block = 4 waves; wave w handles 16 query rows of a 64-row q-tile.
// ---------------------------------------------------------------------------
template<int DEC>
__global__ __launch_bounds__(256) void k_attn(
    const u16* __restrict__ qkv, const u16* __restrict__ vt,
    const int* __restrict__ lengths, u16* __restrict__ out)
{
    __shared__ __align__(16) u16 plds[4][16][80];
    const int qt = blockIdx.x;      // 0..7
    const int bh = blockIdx.y;      // 0..127
    const int b = bh >> 3, h = bh & 7;
    const int t = threadIdx.x, w = t >> 6, l = t & 63;
    const int lhi = l >> 4, llo = l & 15;
    const int len = lengths[b];
    const int qrow0 = qt * 64 + w * 16;

    const u16* qp = qkv + (size_t)(b * TS + qrow0 + llo) * 1536 + h * 64 + lhi * 8;
    bf16x8 qf0 = *(const bf16x8*)(qp);
    bf16x8 qf1 = *(const bf16x8*)(qp + 32);

    f32x4 o[4];
    float mrun[4], lrun[4];
    #pragma unroll
    for (int j = 0; j < 4; ++j) { mrun[j] = -1e30f; lrun[j] = 0.f; }
    #pragma unroll
    for (int g = 0; g < 4; ++g) o[g] = f32x4{0.f, 0.f, 0.f, 0.f};

    for (int kt = 0; kt < 8; ++kt) {
        f32x4 s[4];
        #pragma unroll
        for (int g = 0; g < 4; ++g) {
            s[g] = f32x4{0.f, 0.f, 0.f, 0.f};
            const u16* kp = qkv + (size_t)(b * TS + kt * 64 + g * 16 + llo) * 1536
                          + 512 + h * 64 + lhi * 8;
            bf16x8 kf0 = *(const bf16x8*)kp;
            bf16x8 kf1 = *(const bf16x8*)(kp + 32);
            s[g] = __builtin_amdgcn_mfma_f32_16x16x32_bf16(qf0, kf0, s[g], 0, 0, 0);
            s[g] = __builtin_amdgcn_mfma_f32_16x16x32_bf16(qf1, kf1, s[g], 0, 0, 0);
        }
        // scale + mask
        #pragma unroll
        for (int g = 0; g < 4; ++g) {
            const int key = kt * 64 + g * 16 + llo;
            #pragma unroll
            for (int j = 0; j < 4; ++j) {
                float v = s[g][j] * 0.125f;
                int lim;
                if (DEC) {
                    const int r = qrow0 + lhi * 4 + j;
                    lim = min(max(r, 1), len);
                } else {
                    lim = len;
                }
                s[g][j] = (key < lim) ? v : -1e30f;
            }
        }
        // online softmax per row (rows live in 16-lane groups)
        #pragma unroll
        for (int j = 0; j < 4; ++j) {
            float tm = fmaxf(fmaxf(s[0][j], s[1][j]), fmaxf(s[2][j], s[3][j]));
            tm = fmaxf(tm, __shfl_xor(tm, 1));
            tm = fmaxf(tm, __shfl_xor(tm, 2));
            tm = fmaxf(tm, __shfl_xor(tm, 4));
            tm = fmaxf(tm, __shfl_xor(tm, 8));
            const float mnew = fmaxf(mrun[j], tm);
            const float alpha = __expf(mrun[j] - mnew);
            mrun[j] = mnew;
            float rs = 0.f;
            #pragma unroll
            for (int g = 0; g < 4; ++g) {
                const float p = __expf(s[g][j] - mnew);
                s[g][j] = p;
                rs += p;
            }
            rs += __shfl_xor(rs, 1);
            rs += __shfl_xor(rs, 2);
            rs += __shfl_xor(rs, 4);
            rs += __shfl_xor(rs, 8);
            lrun[j] = lrun[j] * alpha + rs;
            #pragma unroll
            for (int g = 0; g < 4; ++g) o[g][j] *= alpha;
        }
        // P -> LDS (bf16), C-layout -> A-layout transpose (wave-private region)
        #pragma unroll
        for (int g = 0; g < 4; ++g)
            #pragma unroll
            for (int j = 0; j < 4; ++j)
                plds[w][lhi * 4 + j][g * 16 + llo] = f2b(s[g][j]);
        // PV
        #pragma unroll
        for (int ks = 0; ks < 2; ++ks) {
            bf16x8 pa = *(const bf16x8*)&plds[w][llo][ks * 32 + lhi * 8];
            #pragma unroll
            for (int g = 0; g < 4; ++g) {
                const u16* vp = vt + (size_t)(bh * 64 + g * 16 + llo) * 512
                              + kt * 64 + ks * 32 + lhi * 8;
                bf16x8 vf = *(const bf16x8*)vp;
                o[g] = __builtin_amdgcn_mfma_f32_16x16x32_bf16(pa, vf, o[g], 0, 0, 0);
            }
        }
    }
    #pragma unroll
    for (int g = 0; g < 4; ++g) {
        const int d = h * 64 + g * 16 + llo;
        #pragma unroll
        for (int j = 0; j < 4; ++j) {
            const int r = qrow0 + lhi * 4 + j;
            out[(size_t)(b * TS + r) * 512 + d] = f2b(o[g][j] / lrun[j]);
        }
    }
}

// ---------------------------------------------------------------------------
// LayerNorm over F=512; one wave per row; writes f32 + bf16
// ---------------------------------------------------------------------------
__global__ __launch_bounds__(256) void k_ln(
    const float* __restrict__ in, const float* __restrict__ gam,
    const float* __restrict__ bet, float* __restrict__ o32, u16* __restrict__ o16)
{
    const int row = blockIdx.x * 4 + (threadIdx.x >> 6);
    const int l = threadIdx.x & 63;
    const float* p = in + (size_t)row * 512 + l * 8;
    float x[8];
    *(float4*)&x[0] = *(const float4*)p;
    *(float4*)&x[4] = *(const float4*)(p + 4);
    float s = x[0] + x[1] + x[2] + x[3] + x[4] + x[5] + x[6] + x[7];
    #pragma unroll
    for (int off = 32; off; off >>= 1) s += __shfl_xor(s, off);
    const float mu = s * (1.f / 512.f);
    float v = 0.f;
    #pragma unroll
    for (int i = 0; i < 8; ++i) { const float d = x[i] - mu; v += d * d; }
    #pragma unroll
    for (int off = 32; off; off >>= 1) v += __shfl_xor(v, off);
    const float rstd = rsqrtf(v * (1.f / 512.f) + 1e-5f);
    float gg[8], bb[8];
    *(float4*)&gg[0] = *(const float4*)(gam + l * 8);
    *(float4*)&gg[4] = *(const float4*)(gam + l * 8 + 4);
    *(float4*)&bb[0] = *(const float4*)(bet + l * 8);
    *(float4*)&bb[4] = *(const float4*)(bet + l * 8 + 4);
    float y[8];
    #pragma unroll
    for (int i = 0; i < 8; ++i) y[i] = (x[i] - mu) * rstd * gg[i] + bb[i];
    float* op = o32 + (size_t)row * 512 + l * 8;
    *(float4*)op = *(float4*)&y[0];
    *(float4*)(op + 4) = *(float4*)&y[4];
    ushort4 pk0, pk1;
    pk0.x = f2b(y[0]); pk0.y = f2b(y[1]); pk0.z = f2b(y[2]); pk0.w = f2b(y[3]);
    pk1.x = f2b(y[4]); pk1.y = f2b(y[5]); pk1.z = f2b(y[6]); pk1.w = f2b(y[7]);
    ushort4* o16p = (ushort4*)(o16 + (size_t)row * 512 + l * 8);
    o16p[0] = pk0; o16p[1] = pk1;
}

// ---------------------------------------------------------------------------
// Row dot with a length-512 vector: out[row] = x[row,:] . wv
// ---------------------------------------------------------------------------
__global__ __launch_bounds__(256) void k_rowdot(
    const float* __restrict__ x, const float* __restrict__ wv, float* __restrict__ out)
{
    const int row = blockIdx.x * 4 + (threadIdx.x >> 6);
    const int l = threadIdx.x & 63;
    const float* p = x + (size_t)row * 512 + l * 8;
    float4 a = *(const float4*)p;
    float4 b = *(const float4*)(p + 4);
    float4 wa = *(const float4*)(wv + l * 8);
    float4 wb = *(const float4*)(wv + l * 8 + 4);
    float s = a.x * wa.x + a.y * wa.y + a.z * wa.z + a.w * wa.w
            + b.x * wb.x + b.y * wb.y + b.z * wb.z + b.w * wb.w;
    #pragma unroll
    for (int off = 32; off; off >>= 1) s += __shfl_xor(s, off);
    if (l == 0) out[row] = s;
}

// ---------------------------------------------------------------------------
// Pointer output: out[b,i,j] = (j==0) ? 0 : sigmoid((wq[b,j]+wk[b,i])/sqrt(F))
// ---------------------------------------------------------------------------
__global__ __launch_bounds__(256) void k_ptr_out(
    const float* __restrict__ wq, const float* __restrict__ wk, float* __restrict__ out)
{
    const int bi = blockIdx.x;          // b*512 + i
    const int b = bi >> 9;
    const float wki = wk[bi];
    #pragma unroll
    for (int j = threadIdx.x; j < 512; j += 256) {
        float r = 0.f;
        if (j != 0) {
            const float z = (wq[b * 512 + j] + wki) * 0.044194173824159216f;
            r = 1.f / (1.f + __expf(-z));
        }
        out[(size_t)bi * 512 + j] = r;
    }
}

// ---------------------------------------------------------------------------
extern "C" void kernel_launch(void* const* d_in, const int* in_sizes, int n_in,
                              void* d_out, int out_size, void* d_ws, size_t ws_size,
                              hipStream_t stream)
{
    const float* emb = (const float*)d_in[0];
    const int* lengths = (const int*)d_in[1];
    struct Pw {
        const float *wqkv, *bqkv, *wo, *bo, *ln1g, *ln1b, *w1, *b1, *w2, *b2, *ln2g, *ln2b;
    } pp[2];
    for (int p = 0; p < 2; ++p) {
        const int base = 2 + p * 12;
        pp[p].wqkv = (const float*)d_in[base + 0];
        pp[p].bqkv = (const float*)d_in[base + 1];
        pp[p].wo   = (const float*)d_in[base + 2];
        pp[p].bo   = (const float*)d_in[base + 3];
        pp[p].ln1g = (const float*)d_in[base + 4];
        pp[p].ln1b = (const float*)d_in[base + 5];
        pp[p].w1   = (const float*)d_in[base + 6];
        pp[p].b1   = (const float*)d_in[base + 7];
        pp[p].w2   = (const float*)d_in[base + 8];
        pp[p].b2   = (const float*)d_in[base + 9];
        pp[p].ln2g = (const float*)d_in[base + 10];
        pp[p].ln2b = (const float*)d_in[base + 11];
    }
    const float* pwq = (const float*)d_in[26];
    const float* pwk = (const float*)d_in[27];

    // workspace layout
    char* ws = (char*)d_ws;
    auto alloc = [&](size_t bytes) {
        char* p = ws;
        ws += (bytes + 255) & ~(size_t)255;
        return p;
    };
    u16* wqkvT[2], *woT[2], *w1T[2], *w2T[2];
    for (int p = 0; p < 2; ++p) {
        wqkvT[p] = (u16*)alloc((size_t)TL * 1536 * 512 * 2);
        woT[p]   = (u16*)alloc((size_t)TL * 512 * 512 * 2);
        w1T[p]   = (u16*)alloc((size_t)TL * 2048 * 512 * 2);
        w2T[p]   = (u16*)alloc((size_t)TL * 512 * 2048 * 2);
    }
    const size_t MR = (size_t)TB * TS;  // 8192 rows
    float* x32   = (float*)alloc(MR * 512 * 4);
    u16*   x16   = (u16*)alloc(MR * 512 * 2);
    float* mem32 = (float*)alloc(MR * 512 * 4);
    u16*   mem16 = (u16*)alloc(MR * 512 * 2);
    u16*   qkv   = (u16*)alloc(MR * 1536 * 2);
    u16*   vt    = (u16*)alloc((size_t)TB * TH * 64 * 512 * 2);
    u16*   att16 = (u16*)alloc(MR * 512 * 2);
    float* preln = (float*)alloc(MR * 512 * 4);
    u16*   h16   = (u16*)alloc(MR * 2048 * 2);
    float* wqb   = (float*)alloc(MR * 4);
    float* wkb   = (float*)alloc(MR * 4);

    // weight transposes (fp32 -> bf16 N x K)
    for (int p = 0; p < 2; ++p) {
        k_transpose_w<<<dim3(16, 16, 9), 256, 0, stream>>>(pp[p].wqkv, wqkvT[p], 512, 512);
        k_transpose_w<<<dim3(16, 16, 3), 256, 0, stream>>>(pp[p].wo, woT[p], 512, 512);
        k_transpose_w<<<dim3(64, 16, 3), 256, 0, stream>>>(pp[p].w1, w1T[p], 512, 2048);
        k_transpose_w<<<dim3(16, 64, 3), 256, 0, stream>>>(pp[p].w2, w2T[p], 2048, 512);
    }

    const int n4 = (int)(MR * 512 / 4);  // 1048576
    k_cvt<<<4096, 256, 0, stream>>>(emb, x32, x16, n4);

    // ---------------- encoder ----------------
    for (int i = 0; i < TL; ++i) {
        k_gemm<0><<<dim3(12, 64), 256, 0, stream>>>(
            x16, wqkvT[0] + (size_t)i * 1536 * 512, pp[0].bqkv + i * 1536,
            nullptr, qkv, nullptr, 1536, 512, 1536, 0);
        k_vt<<<dim3(8, 128), 256, 0, stream>>>(qkv, vt);
        k_attn<0><<<dim3(8, 128), 256, 0, stream>>>(qkv, vt, lengths, att16);
        k_gemm<2><<<dim3(4, 64), 256, 0, stream>>>(
            att16, woT[0] + (size_t)i * 512 * 512, pp[0].bo + i * 512,
            x32, nullptr, preln, 512, 512, 512, 0);
        k_ln<<<2048, 256, 0, stream>>>(preln, pp[0].ln1g + i * 512, pp[0].ln1b + i * 512, x32, x16);
        k_gemm<1><<<dim3(16, 64), 256, 0, stream>>>(
            x16, w1T[0] + (size_t)i * 2048 * 512, pp[0].b1 + i * 2048,
            nullptr, h16, nullptr, 2048, 512, 2048, 0);
        k_gemm<2><<<dim3(4, 64), 256, 0, stream>>>(
            h16, w2T[0] + (size_t)i * 512 * 2048, pp[0].b2 + i * 512,
            x32, nullptr, preln, 512, 2048, 512, 0);
        k_ln<<<2048, 256, 0, stream>>>(preln, pp[0].ln2g + i * 512, pp[0].ln2b + i * 512, x32, x16);
    }
    k_cvt<<<4096, 256, 0, stream>>>(x32, mem32, mem16, n4);   // memory
    k_cvt<<<4096, 256, 0, stream>>>(emb, x32, x16, n4);       // decoder input

    // ---------------- decoder ----------------
    for (int i = 0; i < TL; ++i) {
        // q from y
        k_gemm<0><<<dim3(4, 64), 256, 0, stream>>>(
            x16, wqkvT[1] + (size_t)i * 1536 * 512, pp[1].bqkv + i * 1536,
            nullptr, qkv, nullptr, 512, 512, 1536, 0);
        // k,v from memory
        k_gemm<0><<<dim3(8, 64), 256, 0, stream>>>(
            mem16, wqkvT[1] + (size_t)i * 1536 * 512 + 512 * 512, pp[1].bqkv + i * 1536 + 512,
            nullptr, qkv, nullptr, 1024, 512, 1536, 512);
        k_vt<<<dim3(8, 128), 256, 0, stream>>>(qkv, vt);
        k_attn<1><<<dim3(8, 128), 256, 0, stream>>>(qkv, vt, lengths, att16);
        k_gemm<2><<<dim3(4, 64), 256, 0, stream>>>(
            att16, woT[1] + (size_t)i * 512 * 512, pp[1].bo + i * 512,
            x32, nullptr, preln, 512, 512, 512, 0);
        k_ln<<<2048, 256, 0, stream>>>(preln, pp[1].ln1g + i * 512, pp[1].ln1b + i * 512, x32, x16);
        k_gemm<1><<<dim3(16, 64), 256, 0, stream>>>(
            x16, w1T[1] + (size_t)i * 2048 * 512, pp[1].b1 + i * 2048,
            nullptr, h16, nullptr, 2048, 512, 2048, 0);
        k_gemm<2><<<dim3(4, 64), 256, 0, stream>>>(
            h16, w2T[1] + (size_t)i * 512 * 2048, pp[1].b2 + i * 512,
            x32, nullptr, preln, 512, 2048, 512, 0);
        k_ln<<<2048, 256, 0, stream>>>(preln, pp[1].ln2g + i * 512, pp[1].ln2b + i * 512, x32, x16);
    }

    // ---------------- pointer head ----------------
    k_rowdot<<<2048, 256, 0, stream>>>(x32, pwq, wqb);
    k_rowdot<<<2048, 256, 0, stream>>>(mem32, pwk, wkb);
    k_ptr_out<<<TB * TS, 256, 0, stream>>>(wqb, wkb, (float*)d_out);
}

// Round 2
// 1347.902 us; speedup vs baseline: 1.0509x; 1.0509x over previous
//
#include <hip/hip_runtime.h>
#include <hip/hip_bf16.h>
#include <math.h>

#define TB 16
#define TS 512
#define TF 512
#define TH 8
#define TFF 2048
#define TL 3

typedef unsigned short u16;
typedef short bf16x8 __attribute__((ext_vector_type(8)));
typedef float f32x4 __attribute__((ext_vector_type(4)));

__device__ __forceinline__ u16 f2b(float f) {
    __hip_bfloat16 h = __float2bfloat16(f);
    return *reinterpret_cast<u16*>(&h);
}

__device__ __forceinline__ void gload_lds16(const void* g, void* l) {
    __builtin_amdgcn_global_load_lds(
        (const __attribute__((address_space(1))) unsigned int*)g,
        (__attribute__((address_space(3))) unsigned int*)l, 16, 0, 0);
}

// ---------------------------------------------------------------------------
// Batched transpose + fp32->bf16: src z matrices K x N (row-major) -> dst N x K
// ---------------------------------------------------------------------------
__global__ __launch_bounds__(256) void k_transpose_w(
    const float* __restrict__ src, u16* __restrict__ dst, int K, int N)
{
    __shared__ float tile[32][33];
    const int z = blockIdx.z;
    src += (size_t)z * K * N;
    dst += (size_t)z * K * N;
    const int n0 = blockIdx.x * 32, k0 = blockIdx.y * 32;
    const int tx = threadIdx.x & 31, ty = threadIdx.x >> 5;  // 32 x 8
    #pragma unroll
    for (int i = 0; i < 32; i += 8)
        tile[ty + i][tx] = src[(size_t)(k0 + ty + i) * N + n0 + tx];
    __syncthreads();
    #pragma unroll
    for (int i = 0; i < 32; i += 8)
        dst[(size_t)(n0 + ty + i) * K + k0 + tx] = f2b(tile[tx][ty + i]);
}

// ---------------------------------------------------------------------------
// fp32 -> fp32 copy + bf16 convert (vectorized by 4)
// ---------------------------------------------------------------------------
__global__ __launch_bounds__(256) void k_cvt(
    const float* __restrict__ src, float* __restrict__ d32,
    u16* __restrict__ d16, int n4)
{
    const int i = blockIdx.x * 256 + threadIdx.x;
    if (i >= n4) return;
    float4 v = ((const float4*)src)[i];
    if (d32) ((float4*)d32)[i] = v;
    ushort4 p;
    p.x = f2b(v.x); p.y = f2b(v.y); p.z = f2b(v.z); p.w = f2b(v.w);
    ((ushort4*)d16)[i] = p;
}

// ---------------------------------------------------------------------------
// bf16 GEMM: C(MxN) = A(MxK) @ BT(NxK)^T + epilogue
// EPI 0: +bias -> bf16 out (ldo, coloff)
// EPI 1: +bias, exact gelu -> bf16 out
// EPI 2: +bias, +resid -> f32 out (ldo==N, coloff==0)
// EPI 3: +bias, scatter to q/k/v attention layouts:
//        global col c = coloff+col; c<512 -> qb[row][c]
//        512<=c<1024 -> kc[(b*8+h)][s][d]   (h=(c>>6)&7, d=c&63, b=row>>9, s=row&511)
//        c>=1024     -> vtp[(b*8+h)][d][s]  (packed ushort4 over 4 consecutive s)
// 128x128 tile, BK=32, 4 waves each 64x64.
// ---------------------------------------------------------------------------
template<int EPI>
__global__ __launch_bounds__(256) void k_gemm(
    const u16* __restrict__ A, const u16* __restrict__ BT,
    const float* __restrict__ bias, const float* __restrict__ resid,
    u16* __restrict__ outb, float* __restrict__ outf,
    u16* __restrict__ out_k, u16* __restrict__ out_v,
    int N, int K, int ldo, int coloff)
{
    __shared__ __align__(16) u16 As[128 * 32];
    __shared__ __align__(16) u16 Bs[128 * 32];
    const int bn = blockIdx.x, bm = blockIdx.y;
    const int t = threadIdx.x;
    const int w = t >> 6, l = t & 63;
    const int wm = w >> 1, wn = w & 1;
    const int lhi = l >> 4, llo = l & 15;

    f32x4 acc[4][4];
    #pragma unroll
    for (int m = 0; m < 4; ++m)
        #pragma unroll
        for (int n = 0; n < 4; ++n)
            acc[m][n] = f32x4{0.f, 0.f, 0.f, 0.f};

    const int srow = w * 16 + (l >> 2);
    const int scol = (l & 3) * 8;
    const u16* Ag = A + (size_t)(bm * 128 + srow) * K + scol;
    const u16* Bg = BT + (size_t)(bn * 128 + srow) * K + scol;
    u16* Al = As + w * 512;  // HW adds lane*16B
    u16* Bl = Bs + w * 512;

    for (int kt = 0; kt < K; kt += 32) {
        gload_lds16(Ag + kt,          Al);
        gload_lds16(Ag + 64 * K + kt, Al + 2048);
        gload_lds16(Bg + kt,          Bl);
        gload_lds16(Bg + 64 * K + kt, Bl + 2048);
        __syncthreads();
        bf16x8 af[4], bfr[4];
        #pragma unroll
        for (int m = 0; m < 4; ++m)
            af[m] = *(const bf16x8*)(As + (wm * 64 + m * 16 + llo) * 32 + lhi * 8);
        #pragma unroll
        for (int n = 0; n < 4; ++n)
            bfr[n] = *(const bf16x8*)(Bs + (wn * 64 + n * 16 + llo) * 32 + lhi * 8);
        #pragma unroll
        for (int m = 0; m < 4; ++m)
            #pragma unroll
            for (int n = 0; n < 4; ++n)
                acc[m][n] = __builtin_amdgcn_mfma_f32_16x16x32_bf16(
                    af[m], bfr[n], acc[m][n], 0, 0, 0);
        __syncthreads();
    }

    const int colb = bn * 128 + wn * 64;
    const int rowb = bm * 128 + wm * 64 + lhi * 4;
    #pragma unroll
    for (int n = 0; n < 4; ++n) {
        const int col = colb + n * 16 + llo;
        const float bv = bias[col];
        #pragma unroll
        for (int m = 0; m < 4; ++m) {
            const int row = rowb + m * 16;
            if (EPI == 3) {
                float vv[4];
                #pragma unroll
                for (int r = 0; r < 4; ++r) vv[r] = acc[m][n][r] + bv;
                const int c = coloff + col;
                const int region = c >> 9;  // uniform per n-block
                if (region == 0) {
                    #pragma unroll
                    for (int r = 0; r < 4; ++r)
                        outb[(size_t)(row + r) * 512 + c] = f2b(vv[r]);
                } else if (region == 1) {
                    const int hh = (c >> 6) & 7, d = c & 63;
                    #pragma unroll
                    for (int r = 0; r < 4; ++r) {
                        const int rr = row + r;
                        out_k[((size_t)(rr >> 9) * 8 + hh) * 32768 + (rr & 511) * 64 + d] = f2b(vv[r]);
                    }
                } else {
                    const int hh = (c >> 6) & 7, d = c & 63;
                    ushort4 pk;
                    pk.x = f2b(vv[0]); pk.y = f2b(vv[1]);
                    pk.z = f2b(vv[2]); pk.w = f2b(vv[3]);
                    const size_t idx = ((size_t)(row >> 9) * 8 + hh) * 32768
                                     + (size_t)d * 512 + (row & 511);
                    *(ushort4*)&out_v[idx] = pk;
                }
            } else {
                #pragma unroll
                for (int r = 0; r < 4; ++r) {
                    float v = acc[m][n][r] + bv;
                    const size_t off = (size_t)(row + r) * ldo + coloff + col;
                    if (EPI == 0) {
                        outb[off] = f2b(v);
                    } else if (EPI == 1) {
                        v = 0.5f * v * (1.f + erff(v * 0.70710678118654752f));
                        outb[off] = f2b(v);
                    } else {
                        outf[off] = v + resid[off];
                    }
                }
            }
        }
    }
}

// ---------------------------------------------------------------------------
// Fused flash attention.
// qb: (B*S) x 512 bf16 (Q).  kc: [b,h][s][64].  vtp: [b,h][d][s].
// DEC=0: key valid iff key < len[b].  DEC=1: key < min(max(q,1), len[b]).
// Block = 4 waves; wave w handles 16 query rows; early-exits at its own kt_end.
// ---------------------------------------------------------------------------
template<int DEC>
__global__ __launch_bounds__(256) void k_attn(
    const u16* __restrict__ qb, const u16* __restrict__ kc,
    const u16* __restrict__ vtp, const int* __restrict__ lengths,
    u16* __restrict__ out)
{
    __shared__ __align__(16) u16 plds[4][16][64];  // per-wave, XOR-swizzled chunks
    const int qt = blockIdx.x;      // 0..7
    const int bh = blockIdx.y;      // 0..127
    const int b = bh >> 3;
    const int h = bh & 7;
    const int t = threadIdx.x, w = t >> 6, l = t & 63;
    const int lhi = l >> 4, llo = l & 15;
    const int len = lengths[b];
    const int qrow0 = qt * 64 + w * 16;

    const u16* qp = qb + (size_t)(b * TS + qrow0 + llo) * 512 + h * 64 + lhi * 8;
    bf16x8 qf0 = *(const bf16x8*)(qp);
    bf16x8 qf1 = *(const bf16x8*)(qp + 32);

    const u16* kb = kc  + (size_t)bh * 32768;
    const u16* vb = vtp + (size_t)bh * 32768;

    int lim[4];
    #pragma unroll
    for (int j = 0; j < 4; ++j) {
        const int r = qrow0 + lhi * 4 + j;
        lim[j] = DEC ? min(max(r, 1), len) : len;
    }
    const int limw = DEC ? min(qrow0 + 15, len) : len;
    const int ktend = (limw + 63) >> 6;

    f32x4 o[4];
    float mrun[4], lrun[4];
    #pragma unroll
    for (int j = 0; j < 4; ++j) { mrun[j] = -1e30f; lrun[j] = 0.f; }
    #pragma unroll
    for (int g = 0; g < 4; ++g) o[g] = f32x4{0.f, 0.f, 0.f, 0.f};

    const float SC = 0.18033688011112042f;  // 0.125 * log2(e)

    for (int kt = 0; kt < ktend; ++kt) {
        // load all K and V fragments for this tile (16 independent b128 loads)
        bf16x8 kf[4][2], vf[4][2];
        #pragma unroll
        for (int g = 0; g < 4; ++g) {
            const u16* kp = kb + ((kt * 64 + g * 16 + llo) << 6) + lhi * 8;
            kf[g][0] = *(const bf16x8*)kp;
            kf[g][1] = *(const bf16x8*)(kp + 32);
            const u16* vp = vb + (((g * 16 + llo) << 9) + kt * 64 + lhi * 8);
            vf[g][0] = *(const bf16x8*)vp;
            vf[g][1] = *(const bf16x8*)(vp + 32);
        }
        // QK^T
        f32x4 s[4];
        #pragma unroll
        for (int g = 0; g < 4; ++g) {
            s[g] = f32x4{0.f, 0.f, 0.f, 0.f};
            s[g] = __builtin_amdgcn_mfma_f32_16x16x32_bf16(qf0, kf[g][0], s[g], 0, 0, 0);
            s[g] = __builtin_amdgcn_mfma_f32_16x16x32_bf16(qf1, kf[g][1], s[g], 0, 0, 0);
        }
        // scale + mask (exp2 domain)
        #pragma unroll
        for (int g = 0; g < 4; ++g) {
            const int key = kt * 64 + g * 16 + llo;
            #pragma unroll
            for (int j = 0; j < 4; ++j)
                s[g][j] = (key < lim[j]) ? s[g][j] * SC : -1e30f;
        }
        // online softmax per row (rows live in 16-lane groups)
        #pragma unroll
        for (int j = 0; j < 4; ++j) {
            float tm = fmaxf(fmaxf(s[0][j], s[1][j]), fmaxf(s[2][j], s[3][j]));
            tm = fmaxf(tm, __shfl_xor(tm, 1));
            tm = fmaxf(tm, __shfl_xor(tm, 2));
            tm = fmaxf(tm, __shfl_xor(tm, 4));
            tm = fmaxf(tm, __shfl_xor(tm, 8));
            const float mnew = fmaxf(mrun[j], tm);
            const float alpha = exp2f(mrun[j] - mnew);
            mrun[j] = mnew;
            float rs = 0.f;
            #pragma unroll
            for (int g = 0; g < 4; ++g) {
                const float p = exp2f(s[g][j] - mnew);
                s[g][j] = p;
                rs += p;
            }
            rs += __shfl_xor(rs, 1);
            rs += __shfl_xor(rs, 2);
            rs += __shfl_xor(rs, 4);
            rs += __shfl_xor(rs, 8);
            lrun[j] = lrun[j] * alpha + rs;
            #pragma unroll
            for (int g = 0; g < 4; ++g) o[g][j] *= alpha;
        }
        // P -> LDS (bf16), swizzled 16B chunks: slot(row, ch) = ch ^ (row&7)
        #pragma unroll
        for (int g = 0; g < 4; ++g)
            #pragma unroll
            for (int j = 0; j < 4; ++j) {
                const int qr = lhi * 4 + j;
                const int ch = ((g << 1) | (llo >> 3)) ^ (qr & 7);
                plds[w][qr][ch * 8 + (llo & 7)] = f2b(s[g][j]);
            }
        // PV
        #pragma unroll
        for (int ks = 0; ks < 2; ++ks) {
            const int ch = ((ks << 2) | lhi) ^ (llo & 7);
            bf16x8 pa = *(const bf16x8*)&plds[w][llo][ch * 8];
            #pragma unroll
            for (int g = 0; g < 4; ++g)
                o[g] = __builtin_amdgcn_mfma_f32_16x16x32_bf16(pa, vf[g][ks], o[g], 0, 0, 0);
        }
    }
    #pragma unroll
    for (int g = 0; g < 4; ++g) {
        const int d = h * 64 + g * 16 + llo;
        #pragma unroll
        for (int j = 0; j < 4; ++j) {
            const int r = qrow0 + lhi * 4 + j;
            out[(size_t)(b * TS + r) * 512 + d] = f2b(o[g][j] / lrun[j]);
        }
    }
}

// ---------------------------------------------------------------------------
// LayerNorm over F=512; one wave per row; writes f32 + bf16
// ---------------------------------------------------------------------------
__global__ __launch_bounds__(256) void k_ln(
    const float* __restrict__ in, const float* __restrict__ gam,
    const float* __restrict__ bet, float* __restrict__ o32, u16* __restrict__ o16)
{
    const int row = blockIdx.x * 4 + (threadIdx.x >> 6);
    const int l = threadIdx.x & 63;
    const float* p = in + (size_t)row * 512 + l * 8;
    float x[8];
    *(float4*)&x[0] = *(const float4*)p;
    *(float4*)&x[4] = *(const float4*)(p + 4);
    float s = x[0] + x[1] + x[2] + x[3] + x[4] + x[5] + x[6] + x[7];
    #pragma unroll
    for (int off = 32; off; off >>= 1) s += __shfl_xor(s, off);
    const float mu = s * (1.f / 512.f);
    float v = 0.f;
    #pragma unroll
    for (int i = 0; i < 8; ++i) { const float d = x[i] - mu; v += d * d; }
    #pragma unroll
    for (int off = 32; off; off >>= 1) v += __shfl_xor(v, off);
    const float rstd = rsqrtf(v * (1.f / 512.f) + 1e-5f);
    float gg[8], bb[8];
    *(float4*)&gg[0] = *(const float4*)(gam + l * 8);
    *(float4*)&gg[4] = *(const float4*)(gam + l * 8 + 4);
    *(float4*)&bb[0] = *(const float4*)(bet + l * 8);
    *(float4*)&bb[4] = *(const float4*)(bet + l * 8 + 4);
    float y[8];
    #pragma unroll
    for (int i = 0; i < 8; ++i) y[i] = (x[i] - mu) * rstd * gg[i] + bb[i];
    float* op = o32 + (size_t)row * 512 + l * 8;
    *(float4*)op = *(float4*)&y[0];
    *(float4*)(op + 4) = *(float4*)&y[4];
    ushort4 pk0, pk1;
    pk0.x = f2b(y[0]); pk0.y = f2b(y[1]); pk0.z = f2b(y[2]); pk0.w = f2b(y[3]);
    pk1.x = f2b(y[4]); pk1.y = f2b(y[5]); pk1.z = f2b(y[6]); pk1.w = f2b(y[7]);
    ushort4* o16p = (ushort4*)(o16 + (size_t)row * 512 + l * 8);
    o16p[0] = pk0; o16p[1] = pk1;
}

// ---------------------------------------------------------------------------
// Row dot with a length-512 vector: out[row] = x[row,:] . wv
// ---------------------------------------------------------------------------
__global__ __launch_bounds__(256) void k_rowdot(
    const float* __restrict__ x, const float* __restrict__ wv, float* __restrict__ out)
{
    const int row = blockIdx.x * 4 + (threadIdx.x >> 6);
    const int l = threadIdx.x & 63;
    const float* p = x + (size_t)row * 512 + l * 8;
    float4 a = *(const float4*)p;
    float4 b = *(const float4*)(p + 4);
    float4 wa = *(const float4*)(wv + l * 8);
    float4 wb = *(const float4*)(wv + l * 8 + 4);
    float s = a.x * wa.x + a.y * wa.y + a.z * wa.z + a.w * wa.w
            + b.x * wb.x + b.y * wb.y + b.z * wb.z + b.w * wb.w;
    #pragma unroll
    for (int off = 32; off; off >>= 1) s += __shfl_xor(s, off);
    if (l == 0) out[row] = s;
}

// ---------------------------------------------------------------------------
// Pointer output: out[b,i,j] = (j==0) ? 0 : sigmoid((wq[b,j]+wk[b,i])/sqrt(F))
// ---------------------------------------------------------------------------
__global__ __launch_bounds__(256) void k_ptr_out(
    const float* __restrict__ wq, const float* __restrict__ wk, float* __restrict__ out)
{
    const int bi = blockIdx.x;          // b*512 + i
    const int b = bi >> 9;
    const float wki = wk[bi];
    #pragma unroll
    for (int j = threadIdx.x; j < 512; j += 256) {
        float r = 0.f;
        if (j != 0) {
            const float z = (wq[b * 512 + j] + wki) * 0.044194173824159216f;
            r = 1.f / (1.f + __expf(-z));
        }
        out[(size_t)bi * 512 + j] = r;
    }
}

// ---------------------------------------------------------------------------
extern "C" void kernel_launch(void* const* d_in, const int* in_sizes, int n_in,
                              void* d_out, int out_size, void* d_ws, size_t ws_size,
                              hipStream_t stream)
{
    const float* emb = (const float*)d_in[0];
    const int* lengths = (const int*)d_in[1];
    struct Pw {
        const float *wqkv, *bqkv, *wo, *bo, *ln1g, *ln1b, *w1, *b1, *w2, *b2, *ln2g, *ln2b;
    } pp[2];
    for (int p = 0; p < 2; ++p) {
        const int base = 2 + p * 12;
        pp[p].wqkv = (const float*)d_in[base + 0];
        pp[p].bqkv = (const float*)d_in[base + 1];
        pp[p].wo   = (const float*)d_in[base + 2];
        pp[p].bo   = (const float*)d_in[base + 3];
        pp[p].ln1g = (const float*)d_in[base + 4];
        pp[p].ln1b = (const float*)d_in[base + 5];
        pp[p].w1   = (const float*)d_in[base + 6];
        pp[p].b1   = (const float*)d_in[base + 7];
        pp[p].w2   = (const float*)d_in[base + 8];
        pp[p].b2   = (const float*)d_in[base + 9];
        pp[p].ln2g = (const float*)d_in[base + 10];
        pp[p].ln2b = (const float*)d_in[base + 11];
    }
    const float* pwq = (const float*)d_in[26];
    const float* pwk = (const float*)d_in[27];

    // workspace layout
    char* ws = (char*)d_ws;
    auto alloc = [&](size_t bytes) {
        char* p = ws;
        ws += (bytes + 255) & ~(size_t)255;
        return p;
    };
    u16* wqkvT[2], *woT[2], *w1T[2], *w2T[2];
    for (int p = 0; p < 2; ++p) {
        wqkvT[p] = (u16*)alloc((size_t)TL * 1536 * 512 * 2);
        woT[p]   = (u16*)alloc((size_t)TL * 512 * 512 * 2);
        w1T[p]   = (u16*)alloc((size_t)TL * 2048 * 512 * 2);
        w2T[p]   = (u16*)alloc((size_t)TL * 512 * 2048 * 2);
    }
    const size_t MR = (size_t)TB * TS;  // 8192 rows
    float* x32   = (float*)alloc(MR * 512 * 4);
    u16*   x16   = (u16*)alloc(MR * 512 * 2);
    float* mem32 = (float*)alloc(MR * 512 * 4);
    u16*   mem16 = (u16*)alloc(MR * 512 * 2);
    u16*   qbuf  = (u16*)alloc(MR * 512 * 2);
    u16*   kcb   = (u16*)alloc((size_t)TB * TH * 512 * 64 * 2);
    u16*   vtb   = (u16*)alloc((size_t)TB * TH * 64 * 512 * 2);
    u16*   att16 = (u16*)alloc(MR * 512 * 2);
    float* preln = (float*)alloc(MR * 512 * 4);
    u16*   h16   = (u16*)alloc(MR * 2048 * 2);
    float* wqb   = (float*)alloc(MR * 4);
    float* wkb   = (float*)alloc(MR * 4);

    // weight transposes (fp32 -> bf16 N x K)
    for (int p = 0; p < 2; ++p) {
        k_transpose_w<<<dim3(16, 16, 9), 256, 0, stream>>>(pp[p].wqkv, wqkvT[p], 512, 512);
        k_transpose_w<<<dim3(16, 16, 3), 256, 0, stream>>>(pp[p].wo, woT[p], 512, 512);
        k_transpose_w<<<dim3(64, 16, 3), 256, 0, stream>>>(pp[p].w1, w1T[p], 512, 2048);
        k_transpose_w<<<dim3(16, 64, 3), 256, 0, stream>>>(pp[p].w2, w2T[p], 2048, 512);
    }

    const int n4 = (int)(MR * 512 / 4);  // 1048576
    k_cvt<<<4096, 256, 0, stream>>>(emb, x32, x16, n4);

    // ---------------- encoder ----------------
    for (int i = 0; i < TL; ++i) {
        k_gemm<3><<<dim3(12, 64), 256, 0, stream>>>(
            x16, wqkvT[0] + (size_t)i * 1536 * 512, pp[0].bqkv + i * 1536,
            nullptr, qbuf, nullptr, kcb, vtb, 1536, 512, 1536, 0);
        k_attn<0><<<dim3(8, 128), 256, 0, stream>>>(qbuf, kcb, vtb, lengths, att16);
        k_gemm<2><<<dim3(4, 64), 256, 0, stream>>>(
            att16, woT[0] + (size_t)i * 512 * 512, pp[0].bo + i * 512,
            x32, nullptr, preln, nullptr, nullptr, 512, 512, 512, 0);
        k_ln<<<2048, 256, 0, stream>>>(preln, pp[0].ln1g + i * 512, pp[0].ln1b + i * 512, x32, x16);
        k_gemm<1><<<dim3(16, 64), 256, 0, stream>>>(
            x16, w1T[0] + (size_t)i * 2048 * 512, pp[0].b1 + i * 2048,
            nullptr, h16, nullptr, nullptr, nullptr, 2048, 512, 2048, 0);
        k_gemm<2><<<dim3(4, 64), 256, 0, stream>>>(
            h16, w2T[0] + (size_t)i * 512 * 2048, pp[0].b2 + i * 512,
            x32, nullptr, preln, nullptr, nullptr, 512, 2048, 512, 0);
        k_ln<<<2048, 256, 0, stream>>>(preln, pp[0].ln2g + i * 512, pp[0].ln2b + i * 512, x32, x16);
    }
    k_cvt<<<4096, 256, 0, stream>>>(x32, mem32, mem16, n4);   // memory
    k_cvt<<<4096, 256, 0, stream>>>(emb, x32, x16, n4);       // decoder input

    // ---------------- decoder ----------------
    for (int i = 0; i < TL; ++i) {
        // q from y
        k_gemm<3><<<dim3(4, 64), 256, 0, stream>>>(
            x16, wqkvT[1] + (size_t)i * 1536 * 512, pp[1].bqkv + i * 1536,
            nullptr, qbuf, nullptr, kcb, vtb, 512, 512, 1536, 0);
        // k,v from memory
        k_gemm<3><<<dim3(8, 64), 256, 0, stream>>>(
            mem16, wqkvT[1] + (size_t)i * 1536 * 512 + 512 * 512, pp[1].bqkv + i * 1536 + 512,
            nullptr, qbuf, nullptr, kcb, vtb, 1024, 512, 1536, 512);
        k_attn<1><<<dim3(8, 128), 256, 0, stream>>>(qbuf, kcb, vtb, lengths, att16);
        k_gemm<2><<<dim3(4, 64), 256, 0, stream>>>(
            att16, woT[1] + (size_t)i * 512 * 512, pp[1].bo + i * 512,
            x32, nullptr, preln, nullptr, nullptr, 512, 512, 512, 0);
        k_ln<<<2048, 256, 0, stream>>>(preln, pp[1].ln1g + i * 512, pp[1].ln1b + i * 512, x32, x16);
        k_gemm<1><<<dim3(16, 64), 256, 0, stream>>>(
            x16, w1T[1] + (size_t)i * 2048 * 512, pp[1].b1 + i * 2048,
            nullptr, h16, nullptr, nullptr, nullptr, 2048, 512, 2048, 0);
        k_gemm<2><<<dim3(4, 64), 256, 0, stream>>>(
            h16, w2T[1] + (size_t)i * 512 * 2048, pp[1].b2 + i * 512,
            x32, nullptr, preln, nullptr, nullptr, 512, 2048, 512, 0);
        k_ln<<<2048, 256, 0, stream>>>(preln, pp[1].ln2g + i * 512, pp[1].ln2b + i * 512, x32, x16);
    }

    // ---------------- pointer head ----------------
    k_rowdot<<<2048, 256, 0, stream>>>(x32, pwq, wqb);
    k_rowdot<<<2048, 256, 0, stream>>>(mem32, pwk, wkb);
    k_ptr_out<<<TB * TS, 256, 0, stream>>>(wqb, wkb, (float*)d_out);
}

// Round 3
// 1244.501 us; speedup vs baseline: 1.1382x; 1.0831x over previous
//
#include <hip/hip_runtime.h>
#include <hip/hip_bf16.h>
#include <math.h>

#define TB 16
#define TS 512
#define TF 512
#define TH 8
#define TFF 2048
#define TL 3

typedef unsigned short u16;
typedef short bf16x8 __attribute__((ext_vector_type(8)));
typedef float f32x4 __attribute__((ext_vector_type(4)));

__device__ __forceinline__ u16 f2b(float f) {
    __hip_bfloat16 h = __float2bfloat16(f);
    return *reinterpret_cast<u16*>(&h);
}

__device__ __forceinline__ void gload_lds16(const void* g, void* l) {
    __builtin_amdgcn_global_load_lds(
        (const __attribute__((address_space(1))) unsigned int*)g,
        (__attribute__((address_space(3))) unsigned int*)l, 16, 0, 0);
}

// ---------------------------------------------------------------------------
// Batched transpose + fp32->bf16: src z matrices K x N (row-major) -> dst N x K
// ---------------------------------------------------------------------------
__global__ __launch_bounds__(256) void k_transpose_w(
    const float* __restrict__ src, u16* __restrict__ dst, int K, int N)
{
    __shared__ float tile[32][33];
    const int z = blockIdx.z;
    src += (size_t)z * K * N;
    dst += (size_t)z * K * N;
    const int n0 = blockIdx.x * 32, k0 = blockIdx.y * 32;
    const int tx = threadIdx.x & 31, ty = threadIdx.x >> 5;  // 32 x 8
    #pragma unroll
    for (int i = 0; i < 32; i += 8)
        tile[ty + i][tx] = src[(size_t)(k0 + ty + i) * N + n0 + tx];
    __syncthreads();
    #pragma unroll
    for (int i = 0; i < 32; i += 8)
        dst[(size_t)(n0 + ty + i) * K + k0 + tx] = f2b(tile[tx][ty + i]);
}

// ---------------------------------------------------------------------------
// fp32 -> fp32 copy + bf16 convert (vectorized by 4)
// ---------------------------------------------------------------------------
__global__ __launch_bounds__(256) void k_cvt(
    const float* __restrict__ src, float* __restrict__ d32,
    u16* __restrict__ d16, int n4)
{
    const int i = blockIdx.x * 256 + threadIdx.x;
    if (i >= n4) return;
    float4 v = ((const float4*)src)[i];
    if (d32) ((float4*)d32)[i] = v;
    ushort4 p;
    p.x = f2b(v.x); p.y = f2b(v.y); p.z = f2b(v.z); p.w = f2b(v.w);
    ((ushort4*)d16)[i] = p;
}

// ---------------------------------------------------------------------------
// bf16 GEMM: C(MxN) = A(MxK) @ BT(NxK)^T + epilogue.  BK=64, XOR-swizzled LDS.
// Tile: 128 x BN (BN = 128 or 64), 4 waves as 2x2, per-wave 64 x BN/2.
// EPI 0: +bias -> bf16 out (ldo, coloff)
// EPI 1: +bias, exact gelu -> bf16 out
// EPI 2: +bias, +resid -> f32 out
// EPI 3: +bias, scatter to q/k/v attention layouts (see round-1 comment)
// ---------------------------------------------------------------------------
template<int EPI, int BN>
__global__ __launch_bounds__(256) void k_gemm(
    const u16* __restrict__ A, const u16* __restrict__ BT,
    const float* __restrict__ bias, const float* __restrict__ resid,
    u16* __restrict__ outb, float* __restrict__ outf,
    u16* __restrict__ out_k, u16* __restrict__ out_v,
    int N, int K, int ldo, int coloff)
{
    __shared__ __align__(16) u16 As[128 * 64];
    __shared__ __align__(16) u16 Bs[BN * 64];
    const int bn = blockIdx.x, bm = blockIdx.y;
    const int t = threadIdx.x;
    const int w = t >> 6, l = t & 63;
    const int wm = w >> 1, wn = w & 1;
    const int lhi = l >> 4, llo = l & 15;
    constexpr int NR = BN / 64;  // 2 or 1 n-fragments per k-half... (BN/2)/16 below
    constexpr int NFR = BN / 64 * 2;  // fragments per wave col dir: 4 (BN=128) or 2

    f32x4 acc[4][NFR];
    #pragma unroll
    for (int m = 0; m < 4; ++m)
        #pragma unroll
        for (int n = 0; n < NFR; ++n)
            acc[m][n] = f32x4{0.f, 0.f, 0.f, 0.f};

    // staging: per instruction a wave covers 8 rows x 64 cols (linear LDS dest);
    // global source col is inverse-XOR-swizzled so ds_read can XOR-deswizzle.
    const int lr = l >> 3;                       // 0..7 row within strip
    const int lcz = ((l & 7) ^ lr) * 8;          // swizzled col chunk
    const u16* Ag = A + (size_t)(bm * 128 + w * 8 + lr) * K + lcz;
    const u16* Bg = BT + (size_t)(bn * BN + w * 8 + lr) * K + lcz;
    u16* Al = As + w * 8 * 64;
    u16* Bl = Bs + w * 8 * 64;

    for (int kt = 0; kt < K; kt += 64) {
        #pragma unroll
        for (int ro = 0; ro < 4; ++ro)
            gload_lds16(Ag + (size_t)ro * 32 * K + kt, Al + ro * 32 * 64);
        #pragma unroll
        for (int ro = 0; ro < BN / 32; ++ro)
            gload_lds16(Bg + (size_t)ro * 32 * K + kt, Bl + ro * 32 * 64);
        __syncthreads();
        #pragma unroll
        for (int kk = 0; kk < 2; ++kk) {
            bf16x8 af[4], bfr[NFR];
            #pragma unroll
            for (int m = 0; m < 4; ++m) {
                const int row = wm * 64 + m * 16 + llo;
                const int ch = (kk * 4 + lhi) ^ (llo & 7);
                af[m] = *(const bf16x8*)(As + row * 64 + ch * 8);
            }
            #pragma unroll
            for (int n = 0; n < NFR; ++n) {
                const int row = wn * (BN / 2) + n * 16 + llo;
                const int ch = (kk * 4 + lhi) ^ (llo & 7);
                bfr[n] = *(const bf16x8*)(Bs + row * 64 + ch * 8);
            }
            #pragma unroll
            for (int m = 0; m < 4; ++m)
                #pragma unroll
                for (int n = 0; n < NFR; ++n)
                    acc[m][n] = __builtin_amdgcn_mfma_f32_16x16x32_bf16(
                        af[m], bfr[n], acc[m][n], 0, 0, 0);
        }
        __syncthreads();
    }

    const int colb = bn * BN + wn * (BN / 2);
    const int rowb = bm * 128 + wm * 64 + lhi * 4;
    #pragma unroll
    for (int n = 0; n < NFR; ++n) {
        const int col = colb + n * 16 + llo;
        const float bv = bias[col];
        #pragma unroll
        for (int m = 0; m < 4; ++m) {
            const int row = rowb + m * 16;
            if (EPI == 3) {
                float vv[4];
                #pragma unroll
                for (int r = 0; r < 4; ++r) vv[r] = acc[m][n][r] + bv;
                const int c = coloff + col;
                const int region = c >> 9;
                if (region == 0) {
                    #pragma unroll
                    for (int r = 0; r < 4; ++r)
                        outb[(size_t)(row + r) * 512 + c] = f2b(vv[r]);
                } else if (region == 1) {
                    const int hh = (c >> 6) & 7, d = c & 63;
                    #pragma unroll
                    for (int r = 0; r < 4; ++r) {
                        const int rr = row + r;
                        out_k[((size_t)(rr >> 9) * 8 + hh) * 32768 + (rr & 511) * 64 + d] = f2b(vv[r]);
                    }
                } else {
                    const int hh = (c >> 6) & 7, d = c & 63;
                    ushort4 pk;
                    pk.x = f2b(vv[0]); pk.y = f2b(vv[1]);
                    pk.z = f2b(vv[2]); pk.w = f2b(vv[3]);
                    const size_t idx = ((size_t)(row >> 9) * 8 + hh) * 32768
                                     + (size_t)d * 512 + (row & 511);
                    *(ushort4*)&out_v[idx] = pk;
                }
            } else {
                #pragma unroll
                for (int r = 0; r < 4; ++r) {
                    float v = acc[m][n][r] + bv;
                    const size_t off = (size_t)(row + r) * ldo + coloff + col;
                    if (EPI == 0) {
                        outb[off] = f2b(v);
                    } else if (EPI == 1) {
                        v = 0.5f * v * (1.f + erff(v * 0.70710678118654752f));
                        outb[off] = f2b(v);
                    } else {
                        outf[off] = v + resid[off];
                    }
                }
            }
        }
    }
}

// ---------------------------------------------------------------------------
// Fused flash attention, swapped QK^T (S^T = K.Q layout).
// qb: (B*S) x 512 (Q).  kc: [b,h][s][64].  vtp: [b,h][d][s].
// Per lane: q = qrow0 + llo owns its softmax row entirely in registers
// (16 values) -> row reduce = 15 in-reg ops + 2 shfls (over lhi groups).
// K register ping-pong prefetch; V loaded at body top (hidden under QK+SM).
// ---------------------------------------------------------------------------
template<int DEC>
__global__ __launch_bounds__(256) void k_attn(
    const u16* __restrict__ qb, const u16* __restrict__ kc,
    const u16* __restrict__ vtp, const int* __restrict__ lengths,
    u16* __restrict__ out)
{
    __shared__ __align__(16) u16 plds[4][16][64];   // swizzled 16B chunks
    __shared__ float alds[4][16];
    __shared__ float llds[4][16];
    const int qt = blockIdx.x;      // 0..7
    const int bh = blockIdx.y;      // 0..127
    const int b = bh >> 3;
    const int h = bh & 7;
    const int t = threadIdx.x, w = t >> 6, l = t & 63;
    const int lhi = l >> 4, llo = l & 15;
    const int len = lengths[b];
    const int qrow0 = qt * 64 + w * 16;
    const int q = qrow0 + llo;

    // Q as B-operand: col=llo=q, k-chunk = lhi*8 within d 0..31 / 32..63
    const u16* qp = qb + (size_t)(b * TS + q) * 512 + h * 64 + lhi * 8;
    bf16x8 qf0 = *(const bf16x8*)(qp);
    bf16x8 qf1 = *(const bf16x8*)(qp + 32);

    const u16* kb = kc  + (size_t)bh * 32768;
    const u16* vb = vtp + (size_t)bh * 32768;

    const int qlim = DEC ? min(max(q, 1), len) : len;
    const int limw = DEC ? min(qrow0 + 15, len) : len;
    const int ktend = (limw + 63) >> 6;

    f32x4 o[4];
    #pragma unroll
    for (int g = 0; g < 4; ++g) o[g] = f32x4{0.f, 0.f, 0.f, 0.f};
    float mrun = -1e30f, lrun = 0.f;

    const float SC = 0.18033688011112042f;  // 0.125 * log2(e)

    auto loadK = [&](int kt, bf16x8 (&kf)[4][2]) {
        #pragma unroll
        for (int g = 0; g < 4; ++g) {
            // K as A-operand: row=llo=key within 16-block, k-chunk=lhi*8 over d
            const u16* kp = kb + ((kt * 64 + g * 16 + llo) << 6) + lhi * 8;
            kf[g][0] = *(const bf16x8*)kp;
            kf[g][1] = *(const bf16x8*)(kp + 32);
        }
    };

    int kt = 0;
    auto body = [&](bf16x8 (&kfc)[4][2], bf16x8 (&kfn)[4][2]) {
        // V for current tile (used at end; latency hidden under QK + softmax)
        bf16x8 vf[4][2];
        #pragma unroll
        for (int g = 0; g < 4; ++g) {
            const u16* vp = vb + (((g * 16 + llo) << 9) + kt * 64 + lhi * 8);
            vf[g][0] = *(const bf16x8*)vp;
            vf[g][1] = *(const bf16x8*)(vp + 32);
        }
        // S^T = K.Q : s[g][r] -> key = kt*64+g*16+lhi*4+r, query = llo
        f32x4 s[4];
        #pragma unroll
        for (int g = 0; g < 4; ++g) {
            s[g] = f32x4{0.f, 0.f, 0.f, 0.f};
            s[g] = __builtin_amdgcn_mfma_f32_16x16x32_bf16(kfc[g][0], qf0, s[g], 0, 0, 0);
            s[g] = __builtin_amdgcn_mfma_f32_16x16x32_bf16(kfc[g][1], qf1, s[g], 0, 0, 0);
        }
        // prefetch next K tile (stays in flight across softmax+PV)
        loadK(min(kt + 1, 7), kfn);
        // mask + scale (exp2 domain)
        #pragma unroll
        for (int g = 0; g < 4; ++g) {
            const int key = kt * 64 + g * 16 + lhi * 4;
            #pragma unroll
            for (int r = 0; r < 4; ++r)
                s[g][r] = (key + r < qlim) ? s[g][r] * SC : -1e30f;
        }
        // in-register row max, cross-lhi reduce (2 shfls)
        float tm = fmaxf(fmaxf(fmaxf(s[0][0], s[0][1]), fmaxf(s[0][2], s[0][3])),
                         fmaxf(fmaxf(s[1][0], s[1][1]), fmaxf(s[1][2], s[1][3])));
        tm = fmaxf(tm, fmaxf(fmaxf(fmaxf(s[2][0], s[2][1]), fmaxf(s[2][2], s[2][3])),
                             fmaxf(fmaxf(s[3][0], s[3][1]), fmaxf(s[3][2], s[3][3]))));
        tm = fmaxf(tm, __shfl_xor(tm, 16));
        tm = fmaxf(tm, __shfl_xor(tm, 32));
        const float mnew = fmaxf(mrun, tm);
        const float alpha = exp2f(mrun - mnew);
        mrun = mnew;
        float rs = 0.f;
        ushort4 pk[4];
        #pragma unroll
        for (int g = 0; g < 4; ++g) {
            #pragma unroll
            for (int r = 0; r < 4; ++r) {
                const float p = exp2f(s[g][r] - mnew);
                rs += p;
                ((u16*)&pk[g])[r] = f2b(p);
            }
        }
        rs += __shfl_xor(rs, 16);
        rs += __shfl_xor(rs, 32);
        lrun = lrun * alpha + rs;
        if (lhi == 0) alds[w][llo] = alpha;
        // P -> LDS: lane writes keys g*16+lhi*4..+3 for row q=llo (8B each)
        #pragma unroll
        for (int g = 0; g < 4; ++g) {
            const int chw = (g * 2 + (lhi >> 1)) ^ (llo & 7);
            *(ushort4*)((char*)&plds[w][0][0] + llo * 128 + chw * 16 + (lhi & 1) * 8) = pk[g];
        }
        // rescale o by alpha of q = qrow0 + lhi*4 + r
        const float4 av = *(const float4*)&alds[w][lhi * 4];
        #pragma unroll
        for (int g = 0; g < 4; ++g) {
            o[g][0] *= av.x; o[g][1] *= av.y; o[g][2] *= av.z; o[g][3] *= av.w;
        }
        // PV: pa = P[q=llo][keys ks*32+lhi*8..+7]
        #pragma unroll
        for (int ks = 0; ks < 2; ++ks) {
            const int chr = (ks * 4 + lhi) ^ (llo & 7);
            bf16x8 pa = *(const bf16x8*)((const char*)&plds[w][0][0] + llo * 128 + chr * 16);
            #pragma unroll
            for (int g = 0; g < 4; ++g)
                o[g] = __builtin_amdgcn_mfma_f32_16x16x32_bf16(pa, vf[g][ks], o[g], 0, 0, 0);
        }
        ++kt;
    };

    bf16x8 kfA[4][2], kfB[4][2];
    loadK(0, kfA);
    while (kt < ktend) {
        body(kfA, kfB);
        if (kt >= ktend) break;
        body(kfB, kfA);
    }

    if (lhi == 0) llds[w][llo] = 1.f / lrun;
    __builtin_amdgcn_s_waitcnt(0);  // lgkm drain before cross-lane read
    const float4 linv = *(const float4*)&llds[w][lhi * 4];
    #pragma unroll
    for (int g = 0; g < 4; ++g) {
        const int d = h * 64 + g * 16 + llo;
        #pragma unroll
        for (int r = 0; r < 4; ++r) {
            const int qq = qrow0 + lhi * 4 + r;
            out[(size_t)(b * TS + qq) * 512 + d] = f2b(o[g][r] * ((const float*)&linv)[r]);
        }
    }
}

// ---------------------------------------------------------------------------
// LayerNorm over F=512; one wave per row; writes f32 + bf16
// ---------------------------------------------------------------------------
__global__ __launch_bounds__(256) void k_ln(
    const float* __restrict__ in, const float* __restrict__ gam,
    const float* __restrict__ bet, float* __restrict__ o32, u16* __restrict__ o16)
{
    const int row = blockIdx.x * 4 + (threadIdx.x >> 6);
    const int l = threadIdx.x & 63;
    const float* p = in + (size_t)row * 512 + l * 8;
    float x[8];
    *(float4*)&x[0] = *(const float4*)p;
    *(float4*)&x[4] = *(const float4*)(p + 4);
    float s = x[0] + x[1] + x[2] + x[3] + x[4] + x[5] + x[6] + x[7];
    #pragma unroll
    for (int off = 32; off; off >>= 1) s += __shfl_xor(s, off);
    const float mu = s * (1.f / 512.f);
    float v = 0.f;
    #pragma unroll
    for (int i = 0; i < 8; ++i) { const float d = x[i] - mu; v += d * d; }
    #pragma unroll
    for (int off = 32; off; off >>= 1) v += __shfl_xor(v, off);
    const float rstd = rsqrtf(v * (1.f / 512.f) + 1e-5f);
    float gg[8], bb[8];
    *(float4*)&gg[0] = *(const float4*)(gam + l * 8);
    *(float4*)&gg[4] = *(const float4*)(gam + l * 8 + 4);
    *(float4*)&bb[0] = *(const float4*)(bet + l * 8);
    *(float4*)&bb[4] = *(const float4*)(bet + l * 8 + 4);
    float y[8];
    #pragma unroll
    for (int i = 0; i < 8; ++i) y[i] = (x[i] - mu) * rstd * gg[i] + bb[i];
    float* op = o32 + (size_t)row * 512 + l * 8;
    *(float4*)op = *(float4*)&y[0];
    *(float4*)(op + 4) = *(float4*)&y[4];
    ushort4 pk0, pk1;
    pk0.x = f2b(y[0]); pk0.y = f2b(y[1]); pk0.z = f2b(y[2]); pk0.w = f2b(y[3]);
    pk1.x = f2b(y[4]); pk1.y = f2b(y[5]); pk1.z = f2b(y[6]); pk1.w = f2b(y[7]);
    ushort4* o16p = (ushort4*)(o16 + (size_t)row * 512 + l * 8);
    o16p[0] = pk0; o16p[1] = pk1;
}

// ---------------------------------------------------------------------------
__global__ __launch_bounds__(256) void k_rowdot(
    const float* __restrict__ x, const float* __restrict__ wv, float* __restrict__ out)
{
    const int row = blockIdx.x * 4 + (threadIdx.x >> 6);
    const int l = threadIdx.x & 63;
    const float* p = x + (size_t)row * 512 + l * 8;
    float4 a = *(const float4*)p;
    float4 b = *(const float4*)(p + 4);
    float4 wa = *(const float4*)(wv + l * 8);
    float4 wb = *(const float4*)(wv + l * 8 + 4);
    float s = a.x * wa.x + a.y * wa.y + a.z * wa.z + a.w * wa.w
            + b.x * wb.x + b.y * wb.y + b.z * wb.z + b.w * wb.w;
    #pragma unroll
    for (int off = 32; off; off >>= 1) s += __shfl_xor(s, off);
    if (l == 0) out[row] = s;
}

// ---------------------------------------------------------------------------
__global__ __launch_bounds__(256) void k_ptr_out(
    const float* __restrict__ wq, const float* __restrict__ wk, float* __restrict__ out)
{
    const int bi = blockIdx.x;          // b*512 + i
    const int b = bi >> 9;
    const float wki = wk[bi];
    #pragma unroll
    for (int j = threadIdx.x; j < 512; j += 256) {
        float r = 0.f;
        if (j != 0) {
            const float z = (wq[b * 512 + j] + wki) * 0.044194173824159216f;
            r = 1.f / (1.f + __expf(-z));
        }
        out[(size_t)bi * 512 + j] = r;
    }
}

// ---------------------------------------------------------------------------
extern "C" void kernel_launch(void* const* d_in, const int* in_sizes, int n_in,
                              void* d_out, int out_size, void* d_ws, size_t ws_size,
                              hipStream_t stream)
{
    const float* emb = (const float*)d_in[0];
    const int* lengths = (const int*)d_in[1];
    struct Pw {
        const float *wqkv, *bqkv, *wo, *bo, *ln1g, *ln1b, *w1, *b1, *w2, *b2, *ln2g, *ln2b;
    } pp[2];
    for (int p = 0; p < 2; ++p) {
        const int base = 2 + p * 12;
        pp[p].wqkv = (const float*)d_in[base + 0];
        pp[p].bqkv = (const float*)d_in[base + 1];
        pp[p].wo   = (const float*)d_in[base + 2];
        pp[p].bo   = (const float*)d_in[base + 3];
        pp[p].ln1g = (const float*)d_in[base + 4];
        pp[p].ln1b = (const float*)d_in[base + 5];
        pp[p].w1   = (const float*)d_in[base + 6];
        pp[p].b1   = (const float*)d_in[base + 7];
        pp[p].w2   = (const float*)d_in[base + 8];
        pp[p].b2   = (const float*)d_in[base + 9];
        pp[p].ln2g = (const float*)d_in[base + 10];
        pp[p].ln2b = (const float*)d_in[base + 11];
    }
    const float* pwq = (const float*)d_in[26];
    const float* pwk = (const float*)d_in[27];

    // workspace layout
    char* ws = (char*)d_ws;
    auto alloc = [&](size_t bytes) {
        char* p = ws;
        ws += (bytes + 255) & ~(size_t)255;
        return p;
    };
    u16* wqkvT[2], *woT[2], *w1T[2], *w2T[2];
    for (int p = 0; p < 2; ++p) {
        wqkvT[p] = (u16*)alloc((size_t)TL * 1536 * 512 * 2);
        woT[p]   = (u16*)alloc((size_t)TL * 512 * 512 * 2);
        w1T[p]   = (u16*)alloc((size_t)TL * 2048 * 512 * 2);
        w2T[p]   = (u16*)alloc((size_t)TL * 512 * 2048 * 2);
    }
    const size_t MR = (size_t)TB * TS;  // 8192 rows
    float* x32   = (float*)alloc(MR * 512 * 4);
    u16*   x16   = (u16*)alloc(MR * 512 * 2);
    float* mem32 = (float*)alloc(MR * 512 * 4);
    u16*   mem16 = (u16*)alloc(MR * 512 * 2);
    u16*   qbuf  = (u16*)alloc(MR * 512 * 2);
    u16*   kcb   = (u16*)alloc((size_t)TB * TH * 512 * 64 * 2);
    u16*   vtb   = (u16*)alloc((size_t)TB * TH * 64 * 512 * 2);
    u16*   att16 = (u16*)alloc(MR * 512 * 2);
    float* preln = (float*)alloc(MR * 512 * 4);
    u16*   h16   = (u16*)alloc(MR * 2048 * 2);
    float* wqb   = (float*)alloc(MR * 4);
    float* wkb   = (float*)alloc(MR * 4);

    // weight transposes (fp32 -> bf16 N x K)
    for (int p = 0; p < 2; ++p) {
        k_transpose_w<<<dim3(16, 16, 9), 256, 0, stream>>>(pp[p].wqkv, wqkvT[p], 512, 512);
        k_transpose_w<<<dim3(16, 16, 3), 256, 0, stream>>>(pp[p].wo, woT[p], 512, 512);
        k_transpose_w<<<dim3(64, 16, 3), 256, 0, stream>>>(pp[p].w1, w1T[p], 512, 2048);
        k_transpose_w<<<dim3(16, 64, 3), 256, 0, stream>>>(pp[p].w2, w2T[p], 2048, 512);
    }

    const int n4 = (int)(MR * 512 / 4);  // 1048576
    k_cvt<<<4096, 256, 0, stream>>>(emb, x32, x16, n4);

    // ---------------- encoder ----------------
    for (int i = 0; i < TL; ++i) {
        k_gemm<3, 128><<<dim3(12, 64), 256, 0, stream>>>(
            x16, wqkvT[0] + (size_t)i * 1536 * 512, pp[0].bqkv + i * 1536,
            nullptr, qbuf, nullptr, kcb, vtb, 1536, 512, 1536, 0);
        k_attn<0><<<dim3(8, 128), 256, 0, stream>>>(qbuf, kcb, vtb, lengths, att16);
        k_gemm<2, 64><<<dim3(8, 64), 256, 0, stream>>>(
            att16, woT[0] + (size_t)i * 512 * 512, pp[0].bo + i * 512,
            x32, nullptr, preln, nullptr, nullptr, 512, 512, 512, 0);
        k_ln<<<2048, 256, 0, stream>>>(preln, pp[0].ln1g + i * 512, pp[0].ln1b + i * 512, x32, x16);
        k_gemm<1, 128><<<dim3(16, 64), 256, 0, stream>>>(
            x16, w1T[0] + (size_t)i * 2048 * 512, pp[0].b1 + i * 2048,
            nullptr, h16, nullptr, nullptr, nullptr, 2048, 512, 2048, 0);
        k_gemm<2, 64><<<dim3(8, 64), 256, 0, stream>>>(
            h16, w2T[0] + (size_t)i * 512 * 2048, pp[0].b2 + i * 512,
            x32, nullptr, preln, nullptr, nullptr, 512, 2048, 512, 0);
        k_ln<<<2048, 256, 0, stream>>>(preln, pp[0].ln2g + i * 512, pp[0].ln2b + i * 512, x32, x16);
    }
    k_cvt<<<4096, 256, 0, stream>>>(x32, mem32, mem16, n4);   // memory
    k_cvt<<<4096, 256, 0, stream>>>(emb, x32, x16, n4);       // decoder input

    // ---------------- decoder ----------------
    for (int i = 0; i < TL; ++i) {
        // q from y
        k_gemm<3, 64><<<dim3(8, 64), 256, 0, stream>>>(
            x16, wqkvT[1] + (size_t)i * 1536 * 512, pp[1].bqkv + i * 1536,
            nullptr, qbuf, nullptr, kcb, vtb, 512, 512, 1536, 0);
        // k,v from memory
        k_gemm<3, 128><<<dim3(8, 64), 256, 0, stream>>>(
            mem16, wqkvT[1] + (size_t)i * 1536 * 512 + 512 * 512, pp[1].bqkv + i * 1536 + 512,
            nullptr, qbuf, nullptr, kcb, vtb, 1024, 512, 1536, 512);
        k_attn<1><<<dim3(8, 128), 256, 0, stream>>>(qbuf, kcb, vtb, lengths, att16);
        k_gemm<2, 64><<<dim3(8, 64), 256, 0, stream>>>(
            att16, woT[1] + (size_t)i * 512 * 512, pp[1].bo + i * 512,
            x32, nullptr, preln, nullptr, nullptr, 512, 512, 512, 0);
        k_ln<<<2048, 256, 0, stream>>>(preln, pp[1].ln1g + i * 512, pp[1].ln1b + i * 512, x32, x16);
        k_gemm<1, 128><<<dim3(16, 64), 256, 0, stream>>>(
            x16, w1T[1] + (size_t)i * 2048 * 512, pp[1].b1 + i * 2048,
            nullptr, h16, nullptr, nullptr, nullptr, 2048, 512, 2048, 0);
        k_gemm<2, 64><<<dim3(8, 64), 256, 0, stream>>>(
            h16, w2T[1] + (size_t)i * 512 * 2048, pp[1].b2 + i * 512,
            x32, nullptr, preln, nullptr, nullptr, 512, 2048, 512, 0);
        k_ln<<<2048, 256, 0, stream>>>(preln, pp[1].ln2g + i * 512, pp[1].ln2b + i * 512, x32, x16);
    }

    // ---------------- pointer head ----------------
    k_rowdot<<<2048, 256, 0, stream>>>(x32, pwq, wqb);
    k_rowdot<<<2048, 256, 0, stream>>>(mem32, pwk, wkb);
    k_ptr_out<<<TB * TS, 256, 0, stream>>>(wqb, wkb, (float*)d_out);
}

// Round 4
// 1209.667 us; speedup vs baseline: 1.1710x; 1.0288x over previous
//
#include <hip/hip_runtime.h>
#include <hip/hip_bf16.h>
#include <math.h>

#define TB 16
#define TS 512
#define TF 512
#define TH 8
#define TFF 2048
#define TL 3

typedef unsigned short u16;
typedef short bf16x8 __attribute__((ext_vector_type(8)));
typedef float f32x4 __attribute__((ext_vector_type(4)));

__device__ __forceinline__ u16 f2b(float f) {
    __hip_bfloat16 h = __float2bfloat16(f);
    return *reinterpret_cast<u16*>(&h);
}

__device__ __forceinline__ void gload_lds16(const void* g, void* l) {
    __builtin_amdgcn_global_load_lds(
        (const __attribute__((address_space(1))) unsigned int*)g,
        (__attribute__((address_space(3))) unsigned int*)l, 16, 0, 0);
}

// ---------------------------------------------------------------------------
// Batched transpose + fp32->bf16: src z matrices K x N (row-major) -> dst N x K
// ---------------------------------------------------------------------------
__global__ __launch_bounds__(256) void k_transpose_w(
    const float* __restrict__ src, u16* __restrict__ dst, int K, int N)
{
    __shared__ float tile[32][33];
    const int z = blockIdx.z;
    src += (size_t)z * K * N;
    dst += (size_t)z * K * N;
    const int n0 = blockIdx.x * 32, k0 = blockIdx.y * 32;
    const int tx = threadIdx.x & 31, ty = threadIdx.x >> 5;  // 32 x 8
    #pragma unroll
    for (int i = 0; i < 32; i += 8)
        tile[ty + i][tx] = src[(size_t)(k0 + ty + i) * N + n0 + tx];
    __syncthreads();
    #pragma unroll
    for (int i = 0; i < 32; i += 8)
        dst[(size_t)(n0 + ty + i) * K + k0 + tx] = f2b(tile[tx][ty + i]);
}

// ---------------------------------------------------------------------------
// fp32 -> fp32 copy + bf16 convert (vectorized by 4)
// ---------------------------------------------------------------------------
__global__ __launch_bounds__(256) void k_cvt(
    const float* __restrict__ src, float* __restrict__ d32,
    u16* __restrict__ d16, int n4)
{
    const int i = blockIdx.x * 256 + threadIdx.x;
    if (i >= n4) return;
    float4 v = ((const float4*)src)[i];
    if (d32) ((float4*)d32)[i] = v;
    ushort4 p;
    p.x = f2b(v.x); p.y = f2b(v.y); p.z = f2b(v.z); p.w = f2b(v.w);
    ((ushort4*)d16)[i] = p;
}

// ---------------------------------------------------------------------------
// bf16 GEMM: C(MxN) = A(MxK) @ BT(NxK)^T + epilogue.  BK=64, XOR-swizzled LDS.
// Tile: 128 x BN (BN = 128 or 64), 4 waves as 2x2, per-wave 64 x BN/2.
// Dual-A: blocks with bn*BN >= asplit read A2 instead of A (decoder qkv fuse).
// EPI 0: +bias -> bf16 out (ldo, coloff)
// EPI 1: +bias, exact gelu -> bf16 out
// EPI 2: +bias, +resid -> f32 out
// EPI 3: +bias, scatter to q/k/v attention layouts
// ---------------------------------------------------------------------------
template<int EPI, int BN>
__global__ __launch_bounds__(256) void k_gemm(
    const u16* __restrict__ A, const u16* __restrict__ A2, int asplit,
    const u16* __restrict__ BT,
    const float* __restrict__ bias, const float* __restrict__ resid,
    u16* __restrict__ outb, float* __restrict__ outf,
    u16* __restrict__ out_k, u16* __restrict__ out_v,
    int N, int K, int ldo, int coloff)
{
    __shared__ __align__(16) u16 As[128 * 64];
    __shared__ __align__(16) u16 Bs[BN * 64];
    const int bn = blockIdx.x, bm = blockIdx.y;
    const int t = threadIdx.x;
    const int w = t >> 6, l = t & 63;
    const int wm = w >> 1, wn = w & 1;
    const int lhi = l >> 4, llo = l & 15;
    constexpr int NFR = BN / 64 * 2;  // n-fragments per wave: 4 (BN=128) or 2

    f32x4 acc[4][NFR];
    #pragma unroll
    for (int m = 0; m < 4; ++m)
        #pragma unroll
        for (int n = 0; n < NFR; ++n)
            acc[m][n] = f32x4{0.f, 0.f, 0.f, 0.f};

    const u16* Asrc = (bn * BN < asplit) ? A : A2;

    // staging: per instruction a wave covers 8 rows x 64 cols (linear LDS dest);
    // global source col is inverse-XOR-swizzled so ds_read can XOR-deswizzle.
    const int lr = l >> 3;                       // 0..7 row within strip
    const int lcz = ((l & 7) ^ lr) * 8;          // swizzled col chunk
    const u16* Ag = Asrc + (size_t)(bm * 128 + w * 8 + lr) * K + lcz;
    const u16* Bg = BT + (size_t)(bn * BN + w * 8 + lr) * K + lcz;
    u16* Al = As + w * 8 * 64;
    u16* Bl = Bs + w * 8 * 64;

    for (int kt = 0; kt < K; kt += 64) {
        #pragma unroll
        for (int ro = 0; ro < 4; ++ro)
            gload_lds16(Ag + (size_t)ro * 32 * K + kt, Al + ro * 32 * 64);
        #pragma unroll
        for (int ro = 0; ro < BN / 32; ++ro)
            gload_lds16(Bg + (size_t)ro * 32 * K + kt, Bl + ro * 32 * 64);
        __syncthreads();
        #pragma unroll
        for (int kk = 0; kk < 2; ++kk) {
            bf16x8 af[4], bfr[NFR];
            #pragma unroll
            for (int m = 0; m < 4; ++m) {
                const int row = wm * 64 + m * 16 + llo;
                const int ch = (kk * 4 + lhi) ^ (llo & 7);
                af[m] = *(const bf16x8*)(As + row * 64 + ch * 8);
            }
            #pragma unroll
            for (int n = 0; n < NFR; ++n) {
                const int row = wn * (BN / 2) + n * 16 + llo;
                const int ch = (kk * 4 + lhi) ^ (llo & 7);
                bfr[n] = *(const bf16x8*)(Bs + row * 64 + ch * 8);
            }
            #pragma unroll
            for (int m = 0; m < 4; ++m)
                #pragma unroll
                for (int n = 0; n < NFR; ++n)
                    acc[m][n] = __builtin_amdgcn_mfma_f32_16x16x32_bf16(
                        af[m], bfr[n], acc[m][n], 0, 0, 0);
        }
        __syncthreads();
    }

    const int colb = bn * BN + wn * (BN / 2);
    const int rowb = bm * 128 + wm * 64 + lhi * 4;
    #pragma unroll
    for (int n = 0; n < NFR; ++n) {
        const int col = colb + n * 16 + llo;
        const float bv = bias[col];
        #pragma unroll
        for (int m = 0; m < 4; ++m) {
            const int row = rowb + m * 16;
            if (EPI == 3) {
                float vv[4];
                #pragma unroll
                for (int r = 0; r < 4; ++r) vv[r] = acc[m][n][r] + bv;
                const int c = coloff + col;
                const int region = c >> 9;
                if (region == 0) {
                    #pragma unroll
                    for (int r = 0; r < 4; ++r)
                        outb[(size_t)(row + r) * 512 + c] = f2b(vv[r]);
                } else if (region == 1) {
                    const int hh = (c >> 6) & 7, d = c & 63;
                    #pragma unroll
                    for (int r = 0; r < 4; ++r) {
                        const int rr = row + r;
                        out_k[((size_t)(rr >> 9) * 8 + hh) * 32768 + (rr & 511) * 64 + d] = f2b(vv[r]);
                    }
                } else {
                    const int hh = (c >> 6) & 7, d = c & 63;
                    ushort4 pk;
                    pk.x = f2b(vv[0]); pk.y = f2b(vv[1]);
                    pk.z = f2b(vv[2]); pk.w = f2b(vv[3]);
                    const size_t idx = ((size_t)(row >> 9) * 8 + hh) * 32768
                                     + (size_t)d * 512 + (row & 511);
                    *(ushort4*)&out_v[idx] = pk;
                }
            } else {
                #pragma unroll
                for (int r = 0; r < 4; ++r) {
                    float v = acc[m][n][r] + bv;
                    const size_t off = (size_t)(row + r) * ldo + coloff + col;
                    if (EPI == 0) {
                        outb[off] = f2b(v);
                    } else if (EPI == 1) {
                        v = 0.5f * v * (1.f + erff(v * 0.70710678118654752f));
                        outb[off] = f2b(v);
                    } else {
                        outf[off] = v + resid[off];
                    }
                }
            }
        }
    }
}

// ---------------------------------------------------------------------------
// Fused flash attention, swapped QK^T (S^T = K.Q layout).
// 128-thread blocks (2 waves), grid (16, 128): fine-grained for load balance
// across variable lengths; each wave owns 16 query rows independently.
// ---------------------------------------------------------------------------
template<int DEC>
__global__ __launch_bounds__(128) void k_attn(
    const u16* __restrict__ qb, const u16* __restrict__ kc,
    const u16* __restrict__ vtp, const int* __restrict__ lengths,
    u16* __restrict__ out)
{
    __shared__ __align__(16) u16 plds[2][16][64];   // swizzled 16B chunks
    __shared__ float alds[2][16];
    __shared__ float llds[2][16];
    const int bh = blockIdx.y;      // 0..127
    const int b = bh >> 3;
    const int h = bh & 7;
    const int t = threadIdx.x, w = t >> 6, l = t & 63;
    const int lhi = l >> 4, llo = l & 15;
    const int len = lengths[b];
    const int qrow0 = blockIdx.x * 32 + w * 16;
    const int q = qrow0 + llo;

    // Q as B-operand: col=llo=q, k-chunk = lhi*8 within d 0..31 / 32..63
    const u16* qp = qb + (size_t)(b * TS + q) * 512 + h * 64 + lhi * 8;
    bf16x8 qf0 = *(const bf16x8*)(qp);
    bf16x8 qf1 = *(const bf16x8*)(qp + 32);

    const u16* kb = kc  + (size_t)bh * 32768;
    const u16* vb = vtp + (size_t)bh * 32768;

    const int qlim = DEC ? min(max(q, 1), len) : len;
    const int limw = DEC ? min(qrow0 + 15, len) : len;
    const int ktend = (limw + 63) >> 6;

    f32x4 o[4];
    #pragma unroll
    for (int g = 0; g < 4; ++g) o[g] = f32x4{0.f, 0.f, 0.f, 0.f};
    float mrun = -1e30f, lrun = 0.f;

    const float SC = 0.18033688011112042f;  // 0.125 * log2(e)

    auto loadK = [&](int kt, bf16x8 (&kf)[4][2]) {
        #pragma unroll
        for (int g = 0; g < 4; ++g) {
            const u16* kp = kb + ((kt * 64 + g * 16 + llo) << 6) + lhi * 8;
            kf[g][0] = *(const bf16x8*)kp;
            kf[g][1] = *(const bf16x8*)(kp + 32);
        }
    };

    int kt = 0;
    auto body = [&](bf16x8 (&kfc)[4][2], bf16x8 (&kfn)[4][2]) {
        // V for current tile (used at end; latency hidden under QK + softmax)
        bf16x8 vf[4][2];
        #pragma unroll
        for (int g = 0; g < 4; ++g) {
            const u16* vp = vb + (((g * 16 + llo) << 9) + kt * 64 + lhi * 8);
            vf[g][0] = *(const bf16x8*)vp;
            vf[g][1] = *(const bf16x8*)(vp + 32);
        }
        // S^T = K.Q : s[g][r] -> key = kt*64+g*16+lhi*4+r, query = llo
        f32x4 s[4];
        #pragma unroll
        for (int g = 0; g < 4; ++g) {
            s[g] = f32x4{0.f, 0.f, 0.f, 0.f};
            s[g] = __builtin_amdgcn_mfma_f32_16x16x32_bf16(kfc[g][0], qf0, s[g], 0, 0, 0);
            s[g] = __builtin_amdgcn_mfma_f32_16x16x32_bf16(kfc[g][1], qf1, s[g], 0, 0, 0);
        }
        // prefetch next K tile (stays in flight across softmax+PV)
        loadK(kt + 1 < ktend ? kt + 1 : kt, kfn);
        // mask + scale (exp2 domain)
        #pragma unroll
        for (int g = 0; g < 4; ++g) {
            const int key = kt * 64 + g * 16 + lhi * 4;
            #pragma unroll
            for (int r = 0; r < 4; ++r)
                s[g][r] = (key + r < qlim) ? s[g][r] * SC : -1e30f;
        }
        // in-register row max, cross-lhi reduce (2 shfls)
        float tm = fmaxf(fmaxf(fmaxf(s[0][0], s[0][1]), fmaxf(s[0][2], s[0][3])),
                         fmaxf(fmaxf(s[1][0], s[1][1]), fmaxf(s[1][2], s[1][3])));
        tm = fmaxf(tm, fmaxf(fmaxf(fmaxf(s[2][0], s[2][1]), fmaxf(s[2][2], s[2][3])),
                             fmaxf(fmaxf(s[3][0], s[3][1]), fmaxf(s[3][2], s[3][3]))));
        tm = fmaxf(tm, __shfl_xor(tm, 16));
        tm = fmaxf(tm, __shfl_xor(tm, 32));
        const float mnew = fmaxf(mrun, tm);
        const float alpha = exp2f(mrun - mnew);
        mrun = mnew;
        float rs = 0.f;
        ushort4 pk[4];
        #pragma unroll
        for (int g = 0; g < 4; ++g) {
            #pragma unroll
            for (int r = 0; r < 4; ++r) {
                const float p = exp2f(s[g][r] - mnew);
                rs += p;
                ((u16*)&pk[g])[r] = f2b(p);
            }
        }
        rs += __shfl_xor(rs, 16);
        rs += __shfl_xor(rs, 32);
        lrun = lrun * alpha + rs;
        if (lhi == 0) alds[w][llo] = alpha;
        // P -> LDS: lane writes keys g*16+lhi*4..+3 for row q=llo (8B each)
        #pragma unroll
        for (int g = 0; g < 4; ++g) {
            const int chw = (g * 2 + (lhi >> 1)) ^ (llo & 7);
            *(ushort4*)((char*)&plds[w][0][0] + llo * 128 + chw * 16 + (lhi & 1) * 8) = pk[g];
        }
        // rescale o by alpha of q = qrow0 + lhi*4 + r
        const float4 av = *(const float4*)&alds[w][lhi * 4];
        #pragma unroll
        for (int g = 0; g < 4; ++g) {
            o[g][0] *= av.x; o[g][1] *= av.y; o[g][2] *= av.z; o[g][3] *= av.w;
        }
        // PV: pa = P[q=llo][keys ks*32+lhi*8..+7]
        #pragma unroll
        for (int ks = 0; ks < 2; ++ks) {
            const int chr = (ks * 4 + lhi) ^ (llo & 7);
            bf16x8 pa = *(const bf16x8*)((const char*)&plds[w][0][0] + llo * 128 + chr * 16);
            #pragma unroll
            for (int g = 0; g < 4; ++g)
                o[g] = __builtin_amdgcn_mfma_f32_16x16x32_bf16(pa, vf[g][ks], o[g], 0, 0, 0);
        }
        ++kt;
    };

    bf16x8 kfA[4][2], kfB[4][2];
    loadK(0, kfA);
    while (kt < ktend) {
        body(kfA, kfB);
        if (kt >= ktend) break;
        body(kfB, kfA);
    }

    if (lhi == 0) llds[w][llo] = 1.f / lrun;
    __builtin_amdgcn_s_waitcnt(0);  // drain lgkm before cross-lane read
    const float4 linv = *(const float4*)&llds[w][lhi * 4];
    #pragma unroll
    for (int g = 0; g < 4; ++g) {
        const int d = h * 64 + g * 16 + llo;
        #pragma unroll
        for (int r = 0; r < 4; ++r) {
            const int qq = qrow0 + lhi * 4 + r;
            out[(size_t)(b * TS + qq) * 512 + d] = f2b(o[g][r] * ((const float*)&linv)[r]);
        }
    }
}

// ---------------------------------------------------------------------------
// LayerNorm over F=512; one wave per row; writes f32 + bf16
// ---------------------------------------------------------------------------
__global__ __launch_bounds__(256) void k_ln(
    const float* __restrict__ in, const float* __restrict__ gam,
    const float* __restrict__ bet, float* __restrict__ o32, u16* __restrict__ o16)
{
    const int row = blockIdx.x * 4 + (threadIdx.x >> 6);
    const int l = threadIdx.x & 63;
    const float* p = in + (size_t)row * 512 + l * 8;
    float x[8];
    *(float4*)&x[0] = *(const float4*)p;
    *(float4*)&x[4] = *(const float4*)(p + 4);
    float s = x[0] + x[1] + x[2] + x[3] + x[4] + x[5] + x[6] + x[7];
    #pragma unroll
    for (int off = 32; off; off >>= 1) s += __shfl_xor(s, off);
    const float mu = s * (1.f / 512.f);
    float v = 0.f;
    #pragma unroll
    for (int i = 0; i < 8; ++i) { const float d = x[i] - mu; v += d * d; }
    #pragma unroll
    for (int off = 32; off; off >>= 1) v += __shfl_xor(v, off);
    const float rstd = rsqrtf(v * (1.f / 512.f) + 1e-5f);
    float gg[8], bb[8];
    *(float4*)&gg[0] = *(const float4*)(gam + l * 8);
    *(float4*)&gg[4] = *(const float4*)(gam + l * 8 + 4);
    *(float4*)&bb[0] = *(const float4*)(bet + l * 8);
    *(float4*)&bb[4] = *(const float4*)(bet + l * 8 + 4);
    float y[8];
    #pragma unroll
    for (int i = 0; i < 8; ++i) y[i] = (x[i] - mu) * rstd * gg[i] + bb[i];
    float* op = o32 + (size_t)row * 512 + l * 8;
    *(float4*)op = *(float4*)&y[0];
    *(float4*)(op + 4) = *(float4*)&y[4];
    ushort4 pk0, pk1;
    pk0.x = f2b(y[0]); pk0.y = f2b(y[1]); pk0.z = f2b(y[2]); pk0.w = f2b(y[3]);
    pk1.x = f2b(y[4]); pk1.y = f2b(y[5]); pk1.z = f2b(y[6]); pk1.w = f2b(y[7]);
    ushort4* o16p = (ushort4*)(o16 + (size_t)row * 512 + l * 8);
    o16p[0] = pk0; o16p[1] = pk1;
}

// ---------------------------------------------------------------------------
__global__ __launch_bounds__(256) void k_rowdot(
    const float* __restrict__ x, const float* __restrict__ wv, float* __restrict__ out)
{
    const int row = blockIdx.x * 4 + (threadIdx.x >> 6);
    const int l = threadIdx.x & 63;
    const float* p = x + (size_t)row * 512 + l * 8;
    float4 a = *(const float4*)p;
    float4 b = *(const float4*)(p + 4);
    float4 wa = *(const float4*)(wv + l * 8);
    float4 wb = *(const float4*)(wv + l * 8 + 4);
    float s = a.x * wa.x + a.y * wa.y + a.z * wa.z + a.w * wa.w
            + b.x * wb.x + b.y * wb.y + b.z * wb.z + b.w * wb.w;
    #pragma unroll
    for (int off = 32; off; off >>= 1) s += __shfl_xor(s, off);
    if (l == 0) out[row] = s;
}

// ---------------------------------------------------------------------------
__global__ __launch_bounds__(256) void k_ptr_out(
    const float* __restrict__ wq, const float* __restrict__ wk, float* __restrict__ out)
{
    const int bi = blockIdx.x;          // b*512 + i
    const int b = bi >> 9;
    const float wki = wk[bi];
    #pragma unroll
    for (int j = threadIdx.x; j < 512; j += 256) {
        float r = 0.f;
        if (j != 0) {
            const float z = (wq[b * 512 + j] + wki) * 0.044194173824159216f;
            r = 1.f / (1.f + __expf(-z));
        }
        out[(size_t)bi * 512 + j] = r;
    }
}

// ---------------------------------------------------------------------------
extern "C" void kernel_launch(void* const* d_in, const int* in_sizes, int n_in,
                              void* d_out, int out_size, void* d_ws, size_t ws_size,
                              hipStream_t stream)
{
    const float* emb = (const float*)d_in[0];
    const int* lengths = (const int*)d_in[1];
    struct Pw {
        const float *wqkv, *bqkv, *wo, *bo, *ln1g, *ln1b, *w1, *b1, *w2, *b2, *ln2g, *ln2b;
    } pp[2];
    for (int p = 0; p < 2; ++p) {
        const int base = 2 + p * 12;
        pp[p].wqkv = (const float*)d_in[base + 0];
        pp[p].bqkv = (const float*)d_in[base + 1];
        pp[p].wo   = (const float*)d_in[base + 2];
        pp[p].bo   = (const float*)d_in[base + 3];
        pp[p].ln1g = (const float*)d_in[base + 4];
        pp[p].ln1b = (const float*)d_in[base + 5];
        pp[p].w1   = (const float*)d_in[base + 6];
        pp[p].b1   = (const float*)d_in[base + 7];
        pp[p].w2   = (const float*)d_in[base + 8];
        pp[p].b2   = (const float*)d_in[base + 9];
        pp[p].ln2g = (const float*)d_in[base + 10];
        pp[p].ln2b = (const float*)d_in[base + 11];
    }
    const float* pwq = (const float*)d_in[26];
    const float* pwk = (const float*)d_in[27];

    // workspace layout
    char* ws = (char*)d_ws;
    auto alloc = [&](size_t bytes) {
        char* p = ws;
        ws += (bytes + 255) & ~(size_t)255;
        return p;
    };
    u16* wqkvT[2], *woT[2], *w1T[2], *w2T[2];
    for (int p = 0; p < 2; ++p) {
        wqkvT[p] = (u16*)alloc((size_t)TL * 1536 * 512 * 2);
        woT[p]   = (u16*)alloc((size_t)TL * 512 * 512 * 2);
        w1T[p]   = (u16*)alloc((size_t)TL * 2048 * 512 * 2);
        w2T[p]   = (u16*)alloc((size_t)TL * 512 * 2048 * 2);
    }
    const size_t MR = (size_t)TB * TS;  // 8192 rows
    float* x32   = (float*)alloc(MR * 512 * 4);
    u16*   x16   = (u16*)alloc(MR * 512 * 2);
    float* mem32 = (float*)alloc(MR * 512 * 4);
    u16*   mem16 = (u16*)alloc(MR * 512 * 2);
    u16*   qbuf  = (u16*)alloc(MR * 512 * 2);
    u16*   kcb   = (u16*)alloc((size_t)TB * TH * 512 * 64 * 2);
    u16*   vtb   = (u16*)alloc((size_t)TB * TH * 64 * 512 * 2);
    u16*   att16 = (u16*)alloc(MR * 512 * 2);
    float* preln = (float*)alloc(MR * 512 * 4);
    u16*   h16   = (u16*)alloc(MR * 2048 * 2);
    float* wqb   = (float*)alloc(MR * 4);
    float* wkb   = (float*)alloc(MR * 4);

    // weight transposes (fp32 -> bf16 N x K)
    for (int p = 0; p < 2; ++p) {
        k_transpose_w<<<dim3(16, 16, 9), 256, 0, stream>>>(pp[p].wqkv, wqkvT[p], 512, 512);
        k_transpose_w<<<dim3(16, 16, 3), 256, 0, stream>>>(pp[p].wo, woT[p], 512, 512);
        k_transpose_w<<<dim3(64, 16, 3), 256, 0, stream>>>(pp[p].w1, w1T[p], 512, 2048);
        k_transpose_w<<<dim3(16, 64, 3), 256, 0, stream>>>(pp[p].w2, w2T[p], 2048, 512);
    }

    const int n4 = (int)(MR * 512 / 4);  // 1048576
    k_cvt<<<4096, 256, 0, stream>>>(emb, x32, x16, n4);

    // ---------------- encoder ----------------
    for (int i = 0; i < TL; ++i) {
        k_gemm<3, 128><<<dim3(12, 64), 256, 0, stream>>>(
            x16, x16, 1536, wqkvT[0] + (size_t)i * 1536 * 512, pp[0].bqkv + i * 1536,
            nullptr, qbuf, nullptr, kcb, vtb, 1536, 512, 1536, 0);
        k_attn<0><<<dim3(16, 128), 128, 0, stream>>>(qbuf, kcb, vtb, lengths, att16);
        k_gemm<2, 64><<<dim3(8, 64), 256, 0, stream>>>(
            att16, att16, 512, woT[0] + (size_t)i * 512 * 512, pp[0].bo + i * 512,
            x32, nullptr, preln, nullptr, nullptr, 512, 512, 512, 0);
        k_ln<<<2048, 256, 0, stream>>>(preln, pp[0].ln1g + i * 512, pp[0].ln1b + i * 512, x32, x16);
        k_gemm<1, 128><<<dim3(16, 64), 256, 0, stream>>>(
            x16, x16, 2048, w1T[0] + (size_t)i * 2048 * 512, pp[0].b1 + i * 2048,
            nullptr, h16, nullptr, nullptr, nullptr, 2048, 512, 2048, 0);
        k_gemm<2, 64><<<dim3(8, 64), 256, 0, stream>>>(
            h16, h16, 512, w2T[0] + (size_t)i * 512 * 2048, pp[0].b2 + i * 512,
            x32, nullptr, preln, nullptr, nullptr, 512, 2048, 512, 0);
        k_ln<<<2048, 256, 0, stream>>>(preln, pp[0].ln2g + i * 512, pp[0].ln2b + i * 512, x32, x16);
    }
    k_cvt<<<4096, 256, 0, stream>>>(x32, mem32, mem16, n4);   // memory
    k_cvt<<<4096, 256, 0, stream>>>(emb, x32, x16, n4);       // decoder input

    // ---------------- decoder ----------------
    for (int i = 0; i < TL; ++i) {
        // fused q (from y) + k,v (from memory) in one dispatch
        k_gemm<3, 128><<<dim3(12, 64), 256, 0, stream>>>(
            x16, mem16, 512, wqkvT[1] + (size_t)i * 1536 * 512, pp[1].bqkv + i * 1536,
            nullptr, qbuf, nullptr, kcb, vtb, 1536, 512, 1536, 0);
        k_attn<1><<<dim3(16, 128), 128, 0, stream>>>(qbuf, kcb, vtb, lengths, att16);
        k_gemm<2, 64><<<dim3(8, 64), 256, 0, stream>>>(
            att16, att16, 512, woT[1] + (size_t)i * 512 * 512, pp[1].bo + i * 512,
            x32, nullptr, preln, nullptr, nullptr, 512, 512, 512, 0);
        k_ln<<<2048, 256, 0, stream>>>(preln, pp[1].ln1g + i * 512, pp[1].ln1b + i * 512, x32, x16);
        k_gemm<1, 128><<<dim3(16, 64), 256, 0, stream>>>(
            x16, x16, 2048, w1T[1] + (size_t)i * 2048 * 512, pp[1].b1 + i * 2048,
            nullptr, h16, nullptr, nullptr, nullptr, 2048, 512, 2048, 0);
        k_gemm<2, 64><<<dim3(8, 64), 256, 0, stream>>>(
            h16, h16, 512, w2T[1] + (size_t)i * 512 * 2048, pp[1].b2 + i * 512,
            x32, nullptr, preln, nullptr, nullptr, 512, 2048, 512, 0);
        k_ln<<<2048, 256, 0, stream>>>(preln, pp[1].ln2g + i * 512, pp[1].ln2b + i * 512, x32, x16);
    }

    // ---------------- pointer head ----------------
    k_rowdot<<<2048, 256, 0, stream>>>(x32, pwq, wqb);
    k_rowdot<<<2048, 256, 0, stream>>>(mem32, pwk, wkb);
    k_ptr_out<<<TB * TS, 256, 0, stream>>>(wqb, wkb, (float*)d_out);
}

// Round 5
// 1079.401 us; speedup vs baseline: 1.3123x; 1.1207x over previous
//
#include <hip/hip_runtime.h>
#include <hip/hip_bf16.h>
#include <math.h>

#define TB 16
#define TS 512
#define TF 512
#define TH 8
#define TFF 2048
#define TL 3

typedef unsigned short u16;
typedef short bf16x8 __attribute__((ext_vector_type(8)));
typedef float f32x4 __attribute__((ext_vector_type(4)));

__device__ __forceinline__ u16 f2b(float f) {
    __hip_bfloat16 h = __float2bfloat16(f);
    return *reinterpret_cast<u16*>(&h);
}

__device__ __forceinline__ void gload_lds16(const void* g, void* l) {
    __builtin_amdgcn_global_load_lds(
        (const __attribute__((address_space(1))) unsigned int*)g,
        (__attribute__((address_space(3))) unsigned int*)l, 16, 0, 0);
}

// ---------------------------------------------------------------------------
// Batched transpose + fp32->bf16: src z matrices K x N (row-major) -> dst N x K
// ---------------------------------------------------------------------------
__global__ __launch_bounds__(256) void k_transpose_w(
    const float* __restrict__ src, u16* __restrict__ dst, int K, int N)
{
    __shared__ float tile[32][33];
    const int z = blockIdx.z;
    src += (size_t)z * K * N;
    dst += (size_t)z * K * N;
    const int n0 = blockIdx.x * 32, k0 = blockIdx.y * 32;
    const int tx = threadIdx.x & 31, ty = threadIdx.x >> 5;  // 32 x 8
    #pragma unroll
    for (int i = 0; i < 32; i += 8)
        tile[ty + i][tx] = src[(size_t)(k0 + ty + i) * N + n0 + tx];
    __syncthreads();
    #pragma unroll
    for (int i = 0; i < 32; i += 8)
        dst[(size_t)(n0 + ty + i) * K + k0 + tx] = f2b(tile[tx][ty + i]);
}

// ---------------------------------------------------------------------------
// fp32 -> fp32 copy + bf16 convert (vectorized by 4)
// ---------------------------------------------------------------------------
__global__ __launch_bounds__(256) void k_cvt(
    const float* __restrict__ src, float* __restrict__ d32,
    u16* __restrict__ d16, int n4)
{
    const int i = blockIdx.x * 256 + threadIdx.x;
    if (i >= n4) return;
    float4 v = ((const float4*)src)[i];
    if (d32) ((float4*)d32)[i] = v;
    ushort4 p;
    p.x = f2b(v.x); p.y = f2b(v.y); p.z = f2b(v.z); p.w = f2b(v.w);
    ((ushort4*)d16)[i] = p;
}

// ---------------------------------------------------------------------------
// bf16 GEMM: C(MxN) = A(MxK) @ BT(NxK)^T + epilogue.  BK=64, XOR-swizzled LDS.
// Tile: 128 x BN (BN = 128 or 64), 4 waves as 2x2, per-wave 64 x BN/2.
// Dual-A: blocks with bn*BN >= asplit read A2 instead of A (decoder qkv fuse).
// EPI 0: +bias -> bf16 out (ldo, coloff)
// EPI 1: +bias, exact gelu -> bf16 out
// EPI 2: +bias, +resid -> f32 out
// EPI 3: +bias, scatter to q/k/v attention layouts
// ---------------------------------------------------------------------------
template<int EPI, int BN>
__global__ __launch_bounds__(256) void k_gemm(
    const u16* __restrict__ A, const u16* __restrict__ A2, int asplit,
    const u16* __restrict__ BT,
    const float* __restrict__ bias, const float* __restrict__ resid,
    u16* __restrict__ outb, float* __restrict__ outf,
    u16* __restrict__ out_k, u16* __restrict__ out_v,
    int N, int K, int ldo, int coloff)
{
    __shared__ __align__(16) u16 As[128 * 64];
    __shared__ __align__(16) u16 Bs[BN * 64];
    const int bn = blockIdx.x, bm = blockIdx.y;
    const int t = threadIdx.x;
    const int w = t >> 6, l = t & 63;
    const int wm = w >> 1, wn = w & 1;
    const int lhi = l >> 4, llo = l & 15;
    constexpr int NFR = BN / 64 * 2;  // n-fragments per wave: 4 (BN=128) or 2

    f32x4 acc[4][NFR];
    #pragma unroll
    for (int m = 0; m < 4; ++m)
        #pragma unroll
        for (int n = 0; n < NFR; ++n)
            acc[m][n] = f32x4{0.f, 0.f, 0.f, 0.f};

    const u16* Asrc = (bn * BN < asplit) ? A : A2;

    // staging: per instruction a wave covers 8 rows x 64 cols (linear LDS dest);
    // global source col is inverse-XOR-swizzled so ds_read can XOR-deswizzle.
    const int lr = l >> 3;                       // 0..7 row within strip
    const int lcz = ((l & 7) ^ lr) * 8;          // swizzled col chunk
    const u16* Ag = Asrc + (size_t)(bm * 128 + w * 8 + lr) * K + lcz;
    const u16* Bg = BT + (size_t)(bn * BN + w * 8 + lr) * K + lcz;
    u16* Al = As + w * 8 * 64;
    u16* Bl = Bs + w * 8 * 64;

    for (int kt = 0; kt < K; kt += 64) {
        #pragma unroll
        for (int ro = 0; ro < 4; ++ro)
            gload_lds16(Ag + (size_t)ro * 32 * K + kt, Al + ro * 32 * 64);
        #pragma unroll
        for (int ro = 0; ro < BN / 32; ++ro)
            gload_lds16(Bg + (size_t)ro * 32 * K + kt, Bl + ro * 32 * 64);
        __syncthreads();
        #pragma unroll
        for (int kk = 0; kk < 2; ++kk) {
            bf16x8 af[4], bfr[NFR];
            #pragma unroll
            for (int m = 0; m < 4; ++m) {
                const int row = wm * 64 + m * 16 + llo;
                const int ch = (kk * 4 + lhi) ^ (llo & 7);
                af[m] = *(const bf16x8*)(As + row * 64 + ch * 8);
            }
            #pragma unroll
            for (int n = 0; n < NFR; ++n) {
                const int row = wn * (BN / 2) + n * 16 + llo;
                const int ch = (kk * 4 + lhi) ^ (llo & 7);
                bfr[n] = *(const bf16x8*)(Bs + row * 64 + ch * 8);
            }
            #pragma unroll
            for (int m = 0; m < 4; ++m)
                #pragma unroll
                for (int n = 0; n < NFR; ++n)
                    acc[m][n] = __builtin_amdgcn_mfma_f32_16x16x32_bf16(
                        af[m], bfr[n], acc[m][n], 0, 0, 0);
        }
        __syncthreads();
    }

    const int colb = bn * BN + wn * (BN / 2);
    const int rowb = bm * 128 + wm * 64 + lhi * 4;
    #pragma unroll
    for (int n = 0; n < NFR; ++n) {
        const int col = colb + n * 16 + llo;
        const float bv = bias[col];
        #pragma unroll
        for (int m = 0; m < 4; ++m) {
            const int row = rowb + m * 16;
            if (EPI == 3) {
                float vv[4];
                #pragma unroll
                for (int r = 0; r < 4; ++r) vv[r] = acc[m][n][r] + bv;
                const int c = coloff + col;
                const int region = c >> 9;
                if (region == 0) {
                    #pragma unroll
                    for (int r = 0; r < 4; ++r)
                        outb[(size_t)(row + r) * 512 + c] = f2b(vv[r]);
                } else if (region == 1) {
                    const int hh = (c >> 6) & 7, d = c & 63;
                    #pragma unroll
                    for (int r = 0; r < 4; ++r) {
                        const int rr = row + r;
                        out_k[((size_t)(rr >> 9) * 8 + hh) * 32768 + (rr & 511) * 64 + d] = f2b(vv[r]);
                    }
                } else {
                    const int hh = (c >> 6) & 7, d = c & 63;
                    ushort4 pk;
                    pk.x = f2b(vv[0]); pk.y = f2b(vv[1]);
                    pk.z = f2b(vv[2]); pk.w = f2b(vv[3]);
                    const size_t idx = ((size_t)(row >> 9) * 8 + hh) * 32768
                                     + (size_t)d * 512 + (row & 511);
                    *(ushort4*)&out_v[idx] = pk;
                }
            } else {
                #pragma unroll
                for (int r = 0; r < 4; ++r) {
                    float v = acc[m][n][r] + bv;
                    const size_t off = (size_t)(row + r) * ldo + coloff + col;
                    if (EPI == 0) {
                        outb[off] = f2b(v);
                    } else if (EPI == 1) {
                        v = 0.5f * v * (1.f + erff(v * 0.70710678118654752f));
                        outb[off] = f2b(v);
                    } else {
                        outf[off] = v + resid[off];
                    }
                }
            }
        }
    }
}

// ---------------------------------------------------------------------------
// Fused flash attention, swapped QK^T, block-level LDS K/V staging.
// 4 waves/block; block owns (bh, 64 q-rows); wave w owns 16 q-rows.
// K and V tiles (64x64 bf16 each) staged via global_load_lds, double-buffered,
// counted vmcnt(4) so next-tile loads stay in flight across the barrier (T3/T4).
// LDS XOR-swizzle: LDS[row][c] = G[row][c ^ (row&7)] (16B chunks), read with
// the same XOR -> bank-balanced ds_read_b128.
// ---------------------------------------------------------------------------
template<int DEC>
__global__ __launch_bounds__(256) void k_attn(
    const u16* __restrict__ qb, const u16* __restrict__ kc,
    const u16* __restrict__ vtp, const int* __restrict__ lengths,
    u16* __restrict__ out)
{
    __shared__ __align__(16) u16 Ks[2][64 * 64];
    __shared__ __align__(16) u16 Vs[2][64 * 64];
    __shared__ __align__(16) u16 plds[4][16][64];
    __shared__ float alds[4][16];
    __shared__ float llds[4][16];
    const int qt = blockIdx.x;      // 0..7 (64-row q tile)
    const int bh = blockIdx.y;      // 0..127
    const int b = bh >> 3;
    const int h = bh & 7;
    const int t = threadIdx.x, w = t >> 6, l = t & 63;
    const int lhi = l >> 4, llo = l & 15;
    const int len = lengths[b];
    const int qrow0 = qt * 64 + w * 16;
    const int q = qrow0 + llo;

    const u16* qp = qb + (size_t)(b * TS + q) * 512 + h * 64 + lhi * 8;
    bf16x8 qf0 = *(const bf16x8*)(qp);
    bf16x8 qf1 = *(const bf16x8*)(qp + 32);

    const u16* kb = kc  + (size_t)bh * 32768;
    const u16* vb = vtp + (size_t)bh * 32768;

    const int qlim = DEC ? min(max(q, 1), len) : len;
    const int limb = DEC ? min(qt * 64 + 63, len) : len;
    const int ktend = (limb + 63) >> 6;          // block-uniform

    f32x4 o[4];
    #pragma unroll
    for (int g = 0; g < 4; ++g) o[g] = f32x4{0.f, 0.f, 0.f, 0.f};
    float mrun = -1e30f, lrun = 0.f;

    const float SC = 0.18033688011112042f;  // 0.125 * log2(e)

    // stage one 64-key tile of K and V into LDS buffer `buf`
    const int sr = w * 8 + (l >> 3);                 // staging row 0..31 (+32)
    const int sc = (((l & 7) ^ (sr & 7)) << 3);      // swizzled source chunk (u16)
    auto stage = [&](int buf, int ktt) {
        gload_lds16(kb + ((ktt * 64 + sr) << 6) + sc,        &Ks[buf][(w * 8) * 64]);
        gload_lds16(kb + ((ktt * 64 + 32 + sr) << 6) + sc,   &Ks[buf][(32 + w * 8) * 64]);
        gload_lds16(vb + (size_t)sr * 512 + ktt * 64 + sc,   &Vs[buf][(w * 8) * 64]);
        gload_lds16(vb + (size_t)(32 + sr) * 512 + ktt * 64 + sc, &Vs[buf][(32 + w * 8) * 64]);
    };

    stage(0, 0);
    for (int kt = 0; kt < ktend; ++kt) {
        const int cur = kt & 1;
        if (kt + 1 < ktend) {
            stage(cur ^ 1, kt + 1);
            asm volatile("s_waitcnt vmcnt(4)" ::: "memory");
        } else {
            asm volatile("s_waitcnt vmcnt(0)" ::: "memory");
        }
        __builtin_amdgcn_s_barrier();
        __builtin_amdgcn_sched_barrier(0);

        // fragments from LDS (XOR-deswizzle)
        bf16x8 kf[4][2], vf[4][2];
        #pragma unroll
        for (int g = 0; g < 4; ++g) {
            const int row = g * 16 + llo;
            const int x = row & 7;
            kf[g][0] = *(const bf16x8*)&Ks[cur][row * 64 + ((lhi) ^ x) * 8];
            kf[g][1] = *(const bf16x8*)&Ks[cur][row * 64 + ((4 + lhi) ^ x) * 8];
            vf[g][0] = *(const bf16x8*)&Vs[cur][row * 64 + ((lhi) ^ x) * 8];
            vf[g][1] = *(const bf16x8*)&Vs[cur][row * 64 + ((4 + lhi) ^ x) * 8];
        }
        // S^T = K.Q : s[g][r] -> key = kt*64+g*16+lhi*4+r, query = llo
        f32x4 s[4];
        #pragma unroll
        for (int g = 0; g < 4; ++g) {
            s[g] = f32x4{0.f, 0.f, 0.f, 0.f};
            s[g] = __builtin_amdgcn_mfma_f32_16x16x32_bf16(kf[g][0], qf0, s[g], 0, 0, 0);
            s[g] = __builtin_amdgcn_mfma_f32_16x16x32_bf16(kf[g][1], qf1, s[g], 0, 0, 0);
        }
        // mask + scale (exp2 domain)
        #pragma unroll
        for (int g = 0; g < 4; ++g) {
            const int key = kt * 64 + g * 16 + lhi * 4;
            #pragma unroll
            for (int r = 0; r < 4; ++r)
                s[g][r] = (key + r < qlim) ? s[g][r] * SC : -1e30f;
        }
        // in-register row max, cross-lhi reduce (2 shfls)
        float tm = fmaxf(fmaxf(fmaxf(s[0][0], s[0][1]), fmaxf(s[0][2], s[0][3])),
                         fmaxf(fmaxf(s[1][0], s[1][1]), fmaxf(s[1][2], s[1][3])));
        tm = fmaxf(tm, fmaxf(fmaxf(fmaxf(s[2][0], s[2][1]), fmaxf(s[2][2], s[2][3])),
                             fmaxf(fmaxf(s[3][0], s[3][1]), fmaxf(s[3][2], s[3][3]))));
        tm = fmaxf(tm, __shfl_xor(tm, 16));
        tm = fmaxf(tm, __shfl_xor(tm, 32));
        const float mnew = fmaxf(mrun, tm);
        const float alpha = exp2f(mrun - mnew);
        mrun = mnew;
        float rs = 0.f;
        ushort4 pk[4];
        #pragma unroll
        for (int g = 0; g < 4; ++g) {
            #pragma unroll
            for (int r = 0; r < 4; ++r) {
                const float p = exp2f(s[g][r] - mnew);
                rs += p;
                ((u16*)&pk[g])[r] = f2b(p);
            }
        }
        rs += __shfl_xor(rs, 16);
        rs += __shfl_xor(rs, 32);
        lrun = lrun * alpha + rs;
        if (lhi == 0) alds[w][llo] = alpha;
        // P -> LDS (wave-private), swizzled 16B chunks
        #pragma unroll
        for (int g = 0; g < 4; ++g) {
            const int chw = (g * 2 + (lhi >> 1)) ^ (llo & 7);
            *(ushort4*)((char*)&plds[w][0][0] + llo * 128 + chw * 16 + (lhi & 1) * 8) = pk[g];
        }
        // rescale o by alpha of q = qrow0 + lhi*4 + r
        const float4 av = *(const float4*)&alds[w][lhi * 4];
        #pragma unroll
        for (int g = 0; g < 4; ++g) {
            o[g][0] *= av.x; o[g][1] *= av.y; o[g][2] *= av.z; o[g][3] *= av.w;
        }
        // PV: pa = P[q=llo][keys ks*32+lhi*8..+7]
        #pragma unroll
        for (int ks = 0; ks < 2; ++ks) {
            const int chr = (ks * 4 + lhi) ^ (llo & 7);
            bf16x8 pa = *(const bf16x8*)((const char*)&plds[w][0][0] + llo * 128 + chr * 16);
            #pragma unroll
            for (int g = 0; g < 4; ++g)
                o[g] = __builtin_amdgcn_mfma_f32_16x16x32_bf16(pa, vf[g][ks], o[g], 0, 0, 0);
        }
        __builtin_amdgcn_sched_barrier(0);
        __builtin_amdgcn_s_barrier();
    }

    if (lhi == 0) llds[w][llo] = 1.f / lrun;
    __builtin_amdgcn_s_waitcnt(0);  // drain lgkm before cross-lane read
    const float4 linv = *(const float4*)&llds[w][lhi * 4];
    #pragma unroll
    for (int g = 0; g < 4; ++g) {
        const int d = h * 64 + g * 16 + llo;
        #pragma unroll
        for (int r = 0; r < 4; ++r) {
            const int qq = qrow0 + lhi * 4 + r;
            out[(size_t)(b * TS + qq) * 512 + d] = f2b(o[g][r] * ((const float*)&linv)[r]);
        }
    }
}

// ---------------------------------------------------------------------------
// LayerNorm over F=512; one wave per row; writes f32 + bf16
// ---------------------------------------------------------------------------
__global__ __launch_bounds__(256) void k_ln(
    const float* __restrict__ in, const float* __restrict__ gam,
    const float* __restrict__ bet, float* __restrict__ o32, u16* __restrict__ o16)
{
    const int row = blockIdx.x * 4 + (threadIdx.x >> 6);
    const int l = threadIdx.x & 63;
    const float* p = in + (size_t)row * 512 + l * 8;
    float x[8];
    *(float4*)&x[0] = *(const float4*)p;
    *(float4*)&x[4] = *(const float4*)(p + 4);
    float s = x[0] + x[1] + x[2] + x[3] + x[4] + x[5] + x[6] + x[7];
    #pragma unroll
    for (int off = 32; off; off >>= 1) s += __shfl_xor(s, off);
    const float mu = s * (1.f / 512.f);
    float v = 0.f;
    #pragma unroll
    for (int i = 0; i < 8; ++i) { const float d = x[i] - mu; v += d * d; }
    #pragma unroll
    for (int off = 32; off; off >>= 1) v += __shfl_xor(v, off);
    const float rstd = rsqrtf(v * (1.f / 512.f) + 1e-5f);
    float gg[8], bb[8];
    *(float4*)&gg[0] = *(const float4*)(gam + l * 8);
    *(float4*)&gg[4] = *(const float4*)(gam + l * 8 + 4);
    *(float4*)&bb[0] = *(const float4*)(bet + l * 8);
    *(float4*)&bb[4] = *(const float4*)(bet + l * 8 + 4);
    float y[8];
    #pragma unroll
    for (int i = 0; i < 8; ++i) y[i] = (x[i] - mu) * rstd * gg[i] + bb[i];
    float* op = o32 + (size_t)row * 512 + l * 8;
    *(float4*)op = *(float4*)&y[0];
    *(float4*)(op + 4) = *(float4*)&y[4];
    ushort4 pk0, pk1;
    pk0.x = f2b(y[0]); pk0.y = f2b(y[1]); pk0.z = f2b(y[2]); pk0.w = f2b(y[3]);
    pk1.x = f2b(y[4]); pk1.y = f2b(y[5]); pk1.z = f2b(y[6]); pk1.w = f2b(y[7]);
    ushort4* o16p = (ushort4*)(o16 + (size_t)row * 512 + l * 8);
    o16p[0] = pk0; o16p[1] = pk1;
}

// ---------------------------------------------------------------------------
__global__ __launch_bounds__(256) void k_rowdot(
    const float* __restrict__ x, const float* __restrict__ wv, float* __restrict__ out)
{
    const int row = blockIdx.x * 4 + (threadIdx.x >> 6);
    const int l = threadIdx.x & 63;
    const float* p = x + (size_t)row * 512 + l * 8;
    float4 a = *(const float4*)p;
    float4 b = *(const float4*)(p + 4);
    float4 wa = *(const float4*)(wv + l * 8);
    float4 wb = *(const float4*)(wv + l * 8 + 4);
    float s = a.x * wa.x + a.y * wa.y + a.z * wa.z + a.w * wa.w
            + b.x * wb.x + b.y * wb.y + b.z * wb.z + b.w * wb.w;
    #pragma unroll
    for (int off = 32; off; off >>= 1) s += __shfl_xor(s, off);
    if (l == 0) out[row] = s;
}

// ---------------------------------------------------------------------------
__global__ __launch_bounds__(256) void k_ptr_out(
    const float* __restrict__ wq, const float* __restrict__ wk, float* __restrict__ out)
{
    const int bi = blockIdx.x;          // b*512 + i
    const int b = bi >> 9;
    const float wki = wk[bi];
    #pragma unroll
    for (int j = threadIdx.x; j < 512; j += 256) {
        float r = 0.f;
        if (j != 0) {
            const float z = (wq[b * 512 + j] + wki) * 0.044194173824159216f;
            r = 1.f / (1.f + __expf(-z));
        }
        out[(size_t)bi * 512 + j] = r;
    }
}

// ---------------------------------------------------------------------------
extern "C" void kernel_launch(void* const* d_in, const int* in_sizes, int n_in,
                              void* d_out, int out_size, void* d_ws, size_t ws_size,
                              hipStream_t stream)
{
    const float* emb = (const float*)d_in[0];
    const int* lengths = (const int*)d_in[1];
    struct Pw {
        const float *wqkv, *bqkv, *wo, *bo, *ln1g, *ln1b, *w1, *b1, *w2, *b2, *ln2g, *ln2b;
    } pp[2];
    for (int p = 0; p < 2; ++p) {
        const int base = 2 + p * 12;
        pp[p].wqkv = (const float*)d_in[base + 0];
        pp[p].bqkv = (const float*)d_in[base + 1];
        pp[p].wo   = (const float*)d_in[base + 2];
        pp[p].bo   = (const float*)d_in[base + 3];
        pp[p].ln1g = (const float*)d_in[base + 4];
        pp[p].ln1b = (const float*)d_in[base + 5];
        pp[p].w1   = (const float*)d_in[base + 6];
        pp[p].b1   = (const float*)d_in[base + 7];
        pp[p].w2   = (const float*)d_in[base + 8];
        pp[p].b2   = (const float*)d_in[base + 9];
        pp[p].ln2g = (const float*)d_in[base + 10];
        pp[p].ln2b = (const float*)d_in[base + 11];
    }
    const float* pwq = (const float*)d_in[26];
    const float* pwk = (const float*)d_in[27];

    // workspace layout
    char* ws = (char*)d_ws;
    auto alloc = [&](size_t bytes) {
        char* p = ws;
        ws += (bytes + 255) & ~(size_t)255;
        return p;
    };
    u16* wqkvT[2], *woT[2], *w1T[2], *w2T[2];
    for (int p = 0; p < 2; ++p) {
        wqkvT[p] = (u16*)alloc((size_t)TL * 1536 * 512 * 2);
        woT[p]   = (u16*)alloc((size_t)TL * 512 * 512 * 2);
        w1T[p]   = (u16*)alloc((size_t)TL * 2048 * 512 * 2);
        w2T[p]   = (u16*)alloc((size_t)TL * 512 * 2048 * 2);
    }
    const size_t MR = (size_t)TB * TS;  // 8192 rows
    float* x32   = (float*)alloc(MR * 512 * 4);
    u16*   x16   = (u16*)alloc(MR * 512 * 2);
    float* mem32 = (float*)alloc(MR * 512 * 4);
    u16*   mem16 = (u16*)alloc(MR * 512 * 2);
    u16*   qbuf  = (u16*)alloc(MR * 512 * 2);
    u16*   kcb   = (u16*)alloc((size_t)TB * TH * 512 * 64 * 2);
    u16*   vtb   = (u16*)alloc((size_t)TB * TH * 64 * 512 * 2);
    u16*   att16 = (u16*)alloc(MR * 512 * 2);
    float* preln = (float*)alloc(MR * 512 * 4);
    u16*   h16   = (u16*)alloc(MR * 2048 * 2);
    float* wqb   = (float*)alloc(MR * 4);
    float* wkb   = (float*)alloc(MR * 4);

    // weight transposes (fp32 -> bf16 N x K)
    for (int p = 0; p < 2; ++p) {
        k_transpose_w<<<dim3(16, 16, 9), 256, 0, stream>>>(pp[p].wqkv, wqkvT[p], 512, 512);
        k_transpose_w<<<dim3(16, 16, 3), 256, 0, stream>>>(pp[p].wo, woT[p], 512, 512);
        k_transpose_w<<<dim3(64, 16, 3), 256, 0, stream>>>(pp[p].w1, w1T[p], 512, 2048);
        k_transpose_w<<<dim3(16, 64, 3), 256, 0, stream>>>(pp[p].w2, w2T[p], 2048, 512);
    }

    const int n4 = (int)(MR * 512 / 4);  // 1048576
    k_cvt<<<4096, 256, 0, stream>>>(emb, x32, x16, n4);

    // ---------------- encoder ----------------
    for (int i = 0; i < TL; ++i) {
        k_gemm<3, 128><<<dim3(12, 64), 256, 0, stream>>>(
            x16, x16, 1536, wqkvT[0] + (size_t)i * 1536 * 512, pp[0].bqkv + i * 1536,
            nullptr, qbuf, nullptr, kcb, vtb, 1536, 512, 1536, 0);
        k_attn<0><<<dim3(8, 128), 256, 0, stream>>>(qbuf, kcb, vtb, lengths, att16);
        k_gemm<2, 64><<<dim3(8, 64), 256, 0, stream>>>(
            att16, att16, 512, woT[0] + (size_t)i * 512 * 512, pp[0].bo + i * 512,
            x32, nullptr, preln, nullptr, nullptr, 512, 512, 512, 0);
        k_ln<<<2048, 256, 0, stream>>>(preln, pp[0].ln1g + i * 512, pp[0].ln1b + i * 512, x32, x16);
        k_gemm<1, 128><<<dim3(16, 64), 256, 0, stream>>>(
            x16, x16, 2048, w1T[0] + (size_t)i * 2048 * 512, pp[0].b1 + i * 2048,
            nullptr, h16, nullptr, nullptr, nullptr, 2048, 512, 2048, 0);
        k_gemm<2, 64><<<dim3(8, 64), 256, 0, stream>>>(
            h16, h16, 512, w2T[0] + (size_t)i * 512 * 2048, pp[0].b2 + i * 512,
            x32, nullptr, preln, nullptr, nullptr, 512, 2048, 512, 0);
        k_ln<<<2048, 256, 0, stream>>>(preln, pp[0].ln2g + i * 512, pp[0].ln2b + i * 512, x32, x16);
    }
    k_cvt<<<4096, 256, 0, stream>>>(x32, mem32, mem16, n4);   // memory
    k_cvt<<<4096, 256, 0, stream>>>(emb, x32, x16, n4);       // decoder input

    // ---------------- decoder ----------------
    for (int i = 0; i < TL; ++i) {
        // fused q (from y) + k,v (from memory) in one dispatch
        k_gemm<3, 128><<<dim3(12, 64), 256, 0, stream>>>(
            x16, mem16, 512, wqkvT[1] + (size_t)i * 1536 * 512, pp[1].bqkv + i * 1536,
            nullptr, qbuf, nullptr, kcb, vtb, 1536, 512, 1536, 0);
        k_attn<1><<<dim3(8, 128), 256, 0, stream>>>(qbuf, kcb, vtb, lengths, att16);
        k_gemm<2, 64><<<dim3(8, 64), 256, 0, stream>>>(
            att16, att16, 512, woT[1] + (size_t)i * 512 * 512, pp[1].bo + i * 512,
            x32, nullptr, preln, nullptr, nullptr, 512, 512, 512, 0);
        k_ln<<<2048, 256, 0, stream>>>(preln, pp[1].ln1g + i * 512, pp[1].ln1b + i * 512, x32, x16);
        k_gemm<1, 128><<<dim3(16, 64), 256, 0, stream>>>(
            x16, x16, 2048, w1T[1] + (size_t)i * 2048 * 512, pp[1].b1 + i * 2048,
            nullptr, h16, nullptr, nullptr, nullptr, 2048, 512, 2048, 0);
        k_gemm<2, 64><<<dim3(8, 64), 256, 0, stream>>>(
            h16, h16, 512, w2T[1] + (size_t)i * 512 * 2048, pp[1].b2 + i * 512,
            x32, nullptr, preln, nullptr, nullptr, 512, 2048, 512, 0);
        k_ln<<<2048, 256, 0, stream>>>(preln, pp[1].ln2g + i * 512, pp[1].ln2b + i * 512, x32, x16);
    }

    // ---------------- pointer head ----------------
    k_rowdot<<<2048, 256, 0, stream>>>(x32, pwq, wqb);
    k_rowdot<<<2048, 256, 0, stream>>>(mem32, pwk, wkb);
    k_ptr_out<<<TB * TS, 256, 0, stream>>>(wqb, wkb, (float*)d_out);
}

// Round 7
// 1022.577 us; speedup vs baseline: 1.3853x; 1.0556x over previous
//
#include <hip/hip_runtime.h>
#include <hip/hip_bf16.h>
#include <math.h>

#define TB 16
#define TS 512
#define TF 512
#define TH 8
#define TFF 2048
#define TL 3

typedef unsigned short u16;
typedef short bf16x8 __attribute__((ext_vector_type(8)));
typedef float f32x4 __attribute__((ext_vector_type(4)));

__device__ __forceinline__ u16 f2b(float f) {
    __hip_bfloat16 h = __float2bfloat16(f);
    return *reinterpret_cast<u16*>(&h);
}

__device__ __forceinline__ void gload_lds16(const void* g, void* l) {
    __builtin_amdgcn_global_load_lds(
        (const __attribute__((address_space(1))) unsigned int*)g,
        (__attribute__((address_space(3))) unsigned int*)l, 16, 0, 0);
}

// ---------------------------------------------------------------------------
// Batched transpose + fp32->bf16: src z matrices K x N (row-major) -> dst N x K
// ---------------------------------------------------------------------------
__global__ __launch_bounds__(256) void k_transpose_w(
    const float* __restrict__ src, u16* __restrict__ dst, int K, int N)
{
    __shared__ float tile[32][33];
    const int z = blockIdx.z;
    src += (size_t)z * K * N;
    dst += (size_t)z * K * N;
    const int n0 = blockIdx.x * 32, k0 = blockIdx.y * 32;
    const int tx = threadIdx.x & 31, ty = threadIdx.x >> 5;  // 32 x 8
    #pragma unroll
    for (int i = 0; i < 32; i += 8)
        tile[ty + i][tx] = src[(size_t)(k0 + ty + i) * N + n0 + tx];
    __syncthreads();
    #pragma unroll
    for (int i = 0; i < 32; i += 8)
        dst[(size_t)(n0 + ty + i) * K + k0 + tx] = f2b(tile[tx][ty + i]);
}

// ---------------------------------------------------------------------------
// fp32 -> fp32 copy + bf16 convert (vectorized by 4)
// ---------------------------------------------------------------------------
__global__ __launch_bounds__(256) void k_cvt(
    const float* __restrict__ src, float* __restrict__ d32,
    u16* __restrict__ d16, int n4)
{
    const int i = blockIdx.x * 256 + threadIdx.x;
    if (i >= n4) return;
    float4 v = ((const float4*)src)[i];
    if (d32) ((float4*)d32)[i] = v;
    ushort4 p;
    p.x = f2b(v.x); p.y = f2b(v.y); p.z = f2b(v.z); p.w = f2b(v.w);
    ((ushort4*)d16)[i] = p;
}

// ---------------------------------------------------------------------------
// bf16 GEMM: C(MxN) = A(MxK) @ BT(NxK)^T + epilogue.  BK=64, XOR-swizzled LDS,
// double-buffered staging with counted vmcnt (T3/T4), XCD-chunk block swizzle.
// Tile: 128 x BN (BN = 128 or 64), 4 waves as 2x2, per-wave 64 x BN/2.
// Dual-A: blocks with bn*BN >= asplit read A2 instead of A (decoder qkv fuse).
// EPI 0: +bias -> bf16 out;  EPI 1: +bias, exact gelu -> bf16
// EPI 2: +bias, +resid -> f32 out
// EPI 3: +bias, scatter to q/k layouts; V-region via LDS-bounce transpose
//        to coalesced [d][s] stores.
// ---------------------------------------------------------------------------
template<int EPI, int BN>
__global__ __launch_bounds__(256) void k_gemm(
    const u16* __restrict__ A, const u16* __restrict__ A2, int asplit,
    const u16* __restrict__ BT,
    const float* __restrict__ bias, const float* __restrict__ resid,
    u16* __restrict__ outb, float* __restrict__ outf,
    u16* __restrict__ out_k, u16* __restrict__ out_v,
    int N, int K, int ldo, int coloff)
{
    __shared__ __align__(16) u16 As[2][128 * 64];
    __shared__ __align__(16) u16 Bs[2][BN * 64];
    // XCD-aware bijective swizzle (grid sizes are multiples of 8)
    const int gx = gridDim.x;
    int bid = blockIdx.y * gx + blockIdx.x;
    const int cpx = (gx * gridDim.y) >> 3;
    bid = (bid & 7) * cpx + (bid >> 3);
    const int bn = bid % gx, bm = bid / gx;

    const int t = threadIdx.x;
    const int w = t >> 6, l = t & 63;
    const int wm = w >> 1, wn = w & 1;
    const int lhi = l >> 4, llo = l & 15;
    constexpr int NFR = BN / 64 * 2;  // n-fragments per wave: 4 (BN=128) or 2

    f32x4 acc[4][NFR];
    #pragma unroll
    for (int m = 0; m < 4; ++m)
        #pragma unroll
        for (int n = 0; n < NFR; ++n)
            acc[m][n] = f32x4{0.f, 0.f, 0.f, 0.f};

    const u16* Asrc = (bn * BN < asplit) ? A : A2;

    // staging: linear LDS dest; global source col inverse-XOR-swizzled
    const int lr = l >> 3;                       // 0..7 row within strip
    const int lcz = ((l & 7) ^ lr) * 8;          // swizzled col chunk
    const u16* Ag = Asrc + (size_t)(bm * 128 + w * 8 + lr) * K + lcz;
    const u16* Bg = BT + (size_t)(bn * BN + w * 8 + lr) * K + lcz;

    auto stage = [&](int buf, int kofs) {
        #pragma unroll
        for (int ro = 0; ro < 4; ++ro)
            gload_lds16(Ag + (size_t)ro * 32 * K + kofs, &As[buf][(w * 8 + ro * 32) * 64]);
        #pragma unroll
        for (int ro = 0; ro < BN / 32; ++ro)
            gload_lds16(Bg + (size_t)ro * 32 * K + kofs, &Bs[buf][(w * 8 + ro * 32) * 64]);
    };

    const int NT = K >> 6;
    stage(0, 0);
    for (int kt = 0; kt < NT; ++kt) {
        const int cur = kt & 1;
        if (kt + 1 < NT) {
            stage(cur ^ 1, (kt + 1) << 6);
            if constexpr (BN == 128) asm volatile("s_waitcnt vmcnt(8)" ::: "memory");
            else                     asm volatile("s_waitcnt vmcnt(6)" ::: "memory");
        } else {
            asm volatile("s_waitcnt vmcnt(0)" ::: "memory");
        }
        __builtin_amdgcn_s_barrier();
        __builtin_amdgcn_sched_barrier(0);
        #pragma unroll
        for (int kk = 0; kk < 2; ++kk) {
            bf16x8 af[4], bfr[NFR];
            #pragma unroll
            for (int m = 0; m < 4; ++m) {
                const int row = wm * 64 + m * 16 + llo;
                const int ch = (kk * 4 + lhi) ^ (llo & 7);
                af[m] = *(const bf16x8*)(&As[cur][row * 64 + ch * 8]);
            }
            #pragma unroll
            for (int n = 0; n < NFR; ++n) {
                const int row = wn * (BN / 2) + n * 16 + llo;
                const int ch = (kk * 4 + lhi) ^ (llo & 7);
                bfr[n] = *(const bf16x8*)(&Bs[cur][row * 64 + ch * 8]);
            }
            #pragma unroll
            for (int m = 0; m < 4; ++m)
                #pragma unroll
                for (int n = 0; n < NFR; ++n)
                    acc[m][n] = __builtin_amdgcn_mfma_f32_16x16x32_bf16(
                        af[m], bfr[n], acc[m][n], 0, 0, 0);
        }
        __builtin_amdgcn_sched_barrier(0);
        __builtin_amdgcn_s_barrier();
    }

    const int colb = bn * BN + wn * (BN / 2);
    const int rowb = bm * 128 + wm * 64 + lhi * 4;
    const int c0 = coloff + bn * BN;

    if (EPI == 3 && c0 >= 1024) {
        // ---- V region: wave-local [s][d] -> [d][s] transpose via LDS ----
        // write: element (d=dl, s=sl) at tb[dl*64 + ((sl>>3)^(dl&7))*8 + (sl&7)]
        u16* tb = &As[0][0] + w * 4096;   // 8 KB scratch per wave (As is dead)
        #pragma unroll
        for (int n = 0; n < 4; ++n) {
            const int dl = n * 16 + llo;          // 0..63 within head
            const float bv = bias[colb + n * 16 + llo];
            #pragma unroll
            for (int m = 0; m < 4; ++m) {
                ushort4 pk;
                #pragma unroll
                for (int r = 0; r < 4; ++r)
                    ((u16*)&pk)[r] = f2b(acc[m][n][r] + bv);
                const int slc = m * 2 + (lhi >> 1);          // sl>>3
                const int addr = dl * 64 + ((slc ^ (dl & 7)) << 3) + ((lhi & 1) << 2);
                *(ushort4*)(tb + addr) = pk;
            }
        }
        asm volatile("s_waitcnt lgkmcnt(0)" ::: "memory");
        __builtin_amdgcn_sched_barrier(0);
        const int sbase = bm * 128 + wm * 64;
        const int bidx = sbase >> 9;
        const int srem = sbase & 511;
        const int hh = ((c0 + wn * 64) >> 6) & 7;
        u16* vo = out_v + ((size_t)bidx * 8 + hh) * 32768 + srem;
        const int cchunk = l & 7;                 // s-chunk 0..7
        #pragma unroll
        for (int rr = 0; rr < 8; ++rr) {
            const int dl2 = (l >> 3) + rr * 8;    // d-row 0..63
            const int ch = cchunk ^ (dl2 & 7);
            bf16x8 vv = *(const bf16x8*)(tb + dl2 * 64 + ch * 8);
            *(bf16x8*)(vo + (size_t)dl2 * 512 + cchunk * 8) = vv;
        }
        return;
    }

    #pragma unroll
    for (int n = 0; n < NFR; ++n) {
        const int col = colb + n * 16 + llo;
        const float bv = bias[col];
        #pragma unroll
        for (int m = 0; m < 4; ++m) {
            const int row = rowb + m * 16;
            if (EPI == 3) {
                float vv[4];
                #pragma unroll
                for (int r = 0; r < 4; ++r) vv[r] = acc[m][n][r] + bv;
                const int c = coloff + col;
                if ((c >> 9) == 0) {
                    #pragma unroll
                    for (int r = 0; r < 4; ++r)
                        outb[(size_t)(row + r) * 512 + c] = f2b(vv[r]);
                } else {
                    const int hh = (c >> 6) & 7, d = c & 63;
                    #pragma unroll
                    for (int r = 0; r < 4; ++r) {
                        const int rr = row + r;
                        out_k[((size_t)(rr >> 9) * 8 + hh) * 32768 + (rr & 511) * 64 + d] = f2b(vv[r]);
                    }
                }
            } else {
                #pragma unroll
                for (int r = 0; r < 4; ++r) {
                    float v = acc[m][n][r] + bv;
                    const size_t off = (size_t)(row + r) * ldo + coloff + col;
                    if (EPI == 0) {
                        outb[off] = f2b(v);
                    } else if (EPI == 1) {
                        v = 0.5f * v * (1.f + erff(v * 0.70710678118654752f));
                        outb[off] = f2b(v);
                    } else {
                        outf[off] = v + resid[off];
                    }
                }
            }
        }
    }
}

// ---------------------------------------------------------------------------
// Fused flash attention, swapped QK^T, block-level LDS K/V staging,
// double-buffered with counted vmcnt.
// ---------------------------------------------------------------------------
template<int DEC>
__global__ __launch_bounds__(256) void k_attn(
    const u16* __restrict__ qb, const u16* __restrict__ kc,
    const u16* __restrict__ vtp, const int* __restrict__ lengths,
    u16* __restrict__ out)
{
    __shared__ __align__(16) u16 Ks[2][64 * 64];
    __shared__ __align__(16) u16 Vs[2][64 * 64];
    __shared__ __align__(16) u16 plds[4][16][64];
    __shared__ float alds[4][16];
    __shared__ float llds[4][16];
    const int qt = blockIdx.x;      // 0..7 (64-row q tile)
    const int bh = blockIdx.y;      // 0..127
    const int b = bh >> 3;
    const int h = bh & 7;
    const int t = threadIdx.x, w = t >> 6, l = t & 63;
    const int lhi = l >> 4, llo = l & 15;
    const int len = lengths[b];
    const int qrow0 = qt * 64 + w * 16;
    const int q = qrow0 + llo;

    const u16* qp = qb + (size_t)(b * TS + q) * 512 + h * 64 + lhi * 8;
    bf16x8 qf0 = *(const bf16x8*)(qp);
    bf16x8 qf1 = *(const bf16x8*)(qp + 32);

    const u16* kb = kc  + (size_t)bh * 32768;
    const u16* vb = vtp + (size_t)bh * 32768;

    const int qlim = DEC ? min(max(q, 1), len) : len;
    const int limb = DEC ? min(qt * 64 + 63, len) : len;
    const int ktend = (limb + 63) >> 6;          // block-uniform

    f32x4 o[4];
    #pragma unroll
    for (int g = 0; g < 4; ++g) o[g] = f32x4{0.f, 0.f, 0.f, 0.f};
    float mrun = -1e30f, lrun = 0.f;

    const float SC = 0.18033688011112042f;  // 0.125 * log2(e)

    const int sr = w * 8 + (l >> 3);                 // staging row 0..31 (+32)
    const int sc = (((l & 7) ^ (sr & 7)) << 3);      // swizzled source chunk (u16)
    auto stage = [&](int buf, int ktt) {
        gload_lds16(kb + ((ktt * 64 + sr) << 6) + sc,        &Ks[buf][(w * 8) * 64]);
        gload_lds16(kb + ((ktt * 64 + 32 + sr) << 6) + sc,   &Ks[buf][(32 + w * 8) * 64]);
        gload_lds16(vb + (size_t)sr * 512 + ktt * 64 + sc,   &Vs[buf][(w * 8) * 64]);
        gload_lds16(vb + (size_t)(32 + sr) * 512 + ktt * 64 + sc, &Vs[buf][(32 + w * 8) * 64]);
    };

    stage(0, 0);
    for (int kt = 0; kt < ktend; ++kt) {
        const int cur = kt & 1;
        if (kt + 1 < ktend) {
            stage(cur ^ 1, kt + 1);
            asm volatile("s_waitcnt vmcnt(4)" ::: "memory");
        } else {
            asm volatile("s_waitcnt vmcnt(0)" ::: "memory");
        }
        __builtin_amdgcn_s_barrier();
        __builtin_amdgcn_sched_barrier(0);

        bf16x8 kf[4][2], vf[4][2];
        #pragma unroll
        for (int g = 0; g < 4; ++g) {
            const int row = g * 16 + llo;
            const int x = row & 7;
            kf[g][0] = *(const bf16x8*)&Ks[cur][row * 64 + ((lhi) ^ x) * 8];
            kf[g][1] = *(const bf16x8*)&Ks[cur][row * 64 + ((4 + lhi) ^ x) * 8];
            vf[g][0] = *(const bf16x8*)&Vs[cur][row * 64 + ((lhi) ^ x) * 8];
            vf[g][1] = *(const bf16x8*)&Vs[cur][row * 64 + ((4 + lhi) ^ x) * 8];
        }
        f32x4 s[4];
        #pragma unroll
        for (int g = 0; g < 4; ++g) {
            s[g] = f32x4{0.f, 0.f, 0.f, 0.f};
            s[g] = __builtin_amdgcn_mfma_f32_16x16x32_bf16(kf[g][0], qf0, s[g], 0, 0, 0);
            s[g] = __builtin_amdgcn_mfma_f32_16x16x32_bf16(kf[g][1], qf1, s[g], 0, 0, 0);
        }
        #pragma unroll
        for (int g = 0; g < 4; ++g) {
            const int key = kt * 64 + g * 16 + lhi * 4;
            #pragma unroll
            for (int r = 0; r < 4; ++r)
                s[g][r] = (key + r < qlim) ? s[g][r] * SC : -1e30f;
        }
        float tm = fmaxf(fmaxf(fmaxf(s[0][0], s[0][1]), fmaxf(s[0][2], s[0][3])),
                         fmaxf(fmaxf(s[1][0], s[1][1]), fmaxf(s[1][2], s[1][3])));
        tm = fmaxf(tm, fmaxf(fmaxf(fmaxf(s[2][0], s[2][1]), fmaxf(s[2][2], s[2][3])),
                             fmaxf(fmaxf(s[3][0], s[3][1]), fmaxf(s[3][2], s[3][3]))));
        tm = fmaxf(tm, __shfl_xor(tm, 16));
        tm = fmaxf(tm, __shfl_xor(tm, 32));
        const float mnew = fmaxf(mrun, tm);
        const float alpha = exp2f(mrun - mnew);
        mrun = mnew;
        float rs = 0.f;
        ushort4 pk[4];
        #pragma unroll
        for (int g = 0; g < 4; ++g) {
            #pragma unroll
            for (int r = 0; r < 4; ++r) {
                const float p = exp2f(s[g][r] - mnew);
                rs += p;
                ((u16*)&pk[g])[r] = f2b(p);
            }
        }
        rs += __shfl_xor(rs, 16);
        rs += __shfl_xor(rs, 32);
        lrun = lrun * alpha + rs;
        if (lhi == 0) alds[w][llo] = alpha;
        #pragma unroll
        for (int g = 0; g < 4; ++g) {
            const int chw = (g * 2 + (lhi >> 1)) ^ (llo & 7);
            *(ushort4*)((char*)&plds[w][0][0] + llo * 128 + chw * 16 + (lhi & 1) * 8) = pk[g];
        }
        const float4 av = *(const float4*)&alds[w][lhi * 4];
        #pragma unroll
        for (int g = 0; g < 4; ++g) {
            o[g][0] *= av.x; o[g][1] *= av.y; o[g][2] *= av.z; o[g][3] *= av.w;
        }
        #pragma unroll
        for (int ks = 0; ks < 2; ++ks) {
            const int chr = (ks * 4 + lhi) ^ (llo & 7);
            bf16x8 pa = *(const bf16x8*)((const char*)&plds[w][0][0] + llo * 128 + chr * 16);
            #pragma unroll
            for (int g = 0; g < 4; ++g)
                o[g] = __builtin_amdgcn_mfma_f32_16x16x32_bf16(pa, vf[g][ks], o[g], 0, 0, 0);
        }
        __builtin_amdgcn_sched_barrier(0);
        __builtin_amdgcn_s_barrier();
    }

    if (lhi == 0) llds[w][llo] = 1.f / lrun;
    __builtin_amdgcn_s_waitcnt(0);
    const float4 linv = *(const float4*)&llds[w][lhi * 4];
    #pragma unroll
    for (int g = 0; g < 4; ++g) {
        const int d = h * 64 + g * 16 + llo;
        #pragma unroll
        for (int r = 0; r < 4; ++r) {
            const int qq = qrow0 + lhi * 4 + r;
            out[(size_t)(b * TS + qq) * 512 + d] = f2b(o[g][r] * ((const float*)&linv)[r]);
        }
    }
}

// ---------------------------------------------------------------------------
// LayerNorm over F=512; one wave per row; writes f32 + bf16
// ---------------------------------------------------------------------------
__global__ __launch_bounds__(256) void k_ln(
    const float* __restrict__ in, const float* __restrict__ gam,
    const float* __restrict__ bet, float* __restrict__ o32, u16* __restrict__ o16)
{
    const int row = blockIdx.x * 4 + (threadIdx.x >> 6);
    const int l = threadIdx.x & 63;
    const float* p = in + (size_t)row * 512 + l * 8;
    float x[8];
    *(float4*)&x[0] = *(const float4*)p;
    *(float4*)&x[4] = *(const float4*)(p + 4);
    float s = x[0] + x[1] + x[2] + x[3] + x[4] + x[5] + x[6] + x[7];
    #pragma unroll
    for (int off = 32; off; off >>= 1) s += __shfl_xor(s, off);
    const float mu = s * (1.f / 512.f);
    float v = 0.f;
    #pragma unroll
    for (int i = 0; i < 8; ++i) { const float d = x[i] - mu; v += d * d; }
    #pragma unroll
    for (int off = 32; off; off >>= 1) v += __shfl_xor(v, off);
    const float rstd = rsqrtf(v * (1.f / 512.f) + 1e-5f);
    float gg[8], bb[8];
    *(float4*)&gg[0] = *(const float4*)(gam + l * 8);
    *(float4*)&gg[4] = *(const float4*)(gam + l * 8 + 4);
    *(float4*)&bb[0] = *(const float4*)(bet + l * 8);
    *(float4*)&bb[4] = *(const float4*)(bet + l * 8 + 4);
    float y[8];
    #pragma unroll
    for (int i = 0; i < 8; ++i) y[i] = (x[i] - mu) * rstd * gg[i] + bb[i];
    float* op = o32 + (size_t)row * 512 + l * 8;
    *(float4*)op = *(float4*)&y[0];
    *(float4*)(op + 4) = *(float4*)&y[4];
    ushort4 pk0, pk1;
    pk0.x = f2b(y[0]); pk0.y = f2b(y[1]); pk0.z = f2b(y[2]); pk0.w = f2b(y[3]);
    pk1.x = f2b(y[4]); pk1.y = f2b(y[5]); pk1.z = f2b(y[6]); pk1.w = f2b(y[7]);
    ushort4* o16p = (ushort4*)(o16 + (size_t)row * 512 + l * 8);
    o16p[0] = pk0; o16p[1] = pk1;
}

// ---------------------------------------------------------------------------
__global__ __launch_bounds__(256) void k_rowdot(
    const float* __restrict__ x, const float* __restrict__ wv, float* __restrict__ out)
{
    const int row = blockIdx.x * 4 + (threadIdx.x >> 6);
    const int l = threadIdx.x & 63;
    const float* p = x + (size_t)row * 512 + l * 8;
    float4 a = *(const float4*)p;
    float4 b = *(const float4*)(p + 4);
    float4 wa = *(const float4*)(wv + l * 8);
    float4 wb = *(const float4*)(wv + l * 8 + 4);
    float s = a.x * wa.x + a.y * wa.y + a.z * wa.z + a.w * wa.w
            + b.x * wb.x + b.y * wb.y + b.z * wb.z + b.w * wb.w;
    #pragma unroll
    for (int off = 32; off; off >>= 1) s += __shfl_xor(s, off);
    if (l == 0) out[row] = s;
}

// ---------------------------------------------------------------------------
__global__ __launch_bounds__(256) void k_ptr_out(
    const float* __restrict__ wq, const float* __restrict__ wk, float* __restrict__ out)
{
    const int bi = blockIdx.x;          // b*512 + i
    const int b = bi >> 9;
    const float wki = wk[bi];
    #pragma unroll
    for (int j = threadIdx.x; j < 512; j += 256) {
        float r = 0.f;
        if (j != 0) {
            const float z = (wq[b * 512 + j] + wki) * 0.044194173824159216f;
            r = 1.f / (1.f + __expf(-z));
        }
        out[(size_t)bi * 512 + j] = r;
    }
}

// ---------------------------------------------------------------------------
extern "C" void kernel_launch(void* const* d_in, const int* in_sizes, int n_in,
                              void* d_out, int out_size, void* d_ws, size_t ws_size,
                              hipStream_t stream)
{
    const float* emb = (const float*)d_in[0];
    const int* lengths = (const int*)d_in[1];
    struct Pw {
        const float *wqkv, *bqkv, *wo, *bo, *ln1g, *ln1b, *w1, *b1, *w2, *b2, *ln2g, *ln2b;
    } pp[2];
    for (int p = 0; p < 2; ++p) {
        const int base = 2 + p * 12;
        pp[p].wqkv = (const float*)d_in[base + 0];
        pp[p].bqkv = (const float*)d_in[base + 1];
        pp[p].wo   = (const float*)d_in[base + 2];
        pp[p].bo   = (const float*)d_in[base + 3];
        pp[p].ln1g = (const float*)d_in[base + 4];
        pp[p].ln1b = (const float*)d_in[base + 5];
        pp[p].w1   = (const float*)d_in[base + 6];
        pp[p].b1   = (const float*)d_in[base + 7];
        pp[p].w2   = (const float*)d_in[base + 8];
        pp[p].b2   = (const float*)d_in[base + 9];
        pp[p].ln2g = (const float*)d_in[base + 10];
        pp[p].ln2b = (const float*)d_in[base + 11];
    }
    const float* pwq = (const float*)d_in[26];
    const float* pwk = (const float*)d_in[27];

    // workspace layout
    char* ws = (char*)d_ws;
    auto alloc = [&](size_t bytes) {
        char* p = ws;
        ws += (bytes + 255) & ~(size_t)255;
        return p;
    };
    u16* wqkvT[2], *woT[2], *w1T[2], *w2T[2];
    for (int p = 0; p < 2; ++p) {
        wqkvT[p] = (u16*)alloc((size_t)TL * 1536 * 512 * 2);
        woT[p]   = (u16*)alloc((size_t)TL * 512 * 512 * 2);
        w1T[p]   = (u16*)alloc((size_t)TL * 2048 * 512 * 2);
        w2T[p]   = (u16*)alloc((size_t)TL * 512 * 2048 * 2);
    }
    const size_t MR = (size_t)TB * TS;  // 8192 rows
    float* x32   = (float*)alloc(MR * 512 * 4);
    u16*   x16   = (u16*)alloc(MR * 512 * 2);
    float* mem32 = (float*)alloc(MR * 512 * 4);
    u16*   mem16 = (u16*)alloc(MR * 512 * 2);
    u16*   qbuf  = (u16*)alloc(MR * 512 * 2);
    u16*   kcb   = (u16*)alloc((size_t)TB * TH * 512 * 64 * 2);
    u16*   vtb   = (u16*)alloc((size_t)TB * TH * 64 * 512 * 2);
    u16*   att16 = (u16*)alloc(MR * 512 * 2);
    float* preln = (float*)alloc(MR * 512 * 4);
    u16*   h16   = (u16*)alloc(MR * 2048 * 2);
    float* wqb   = (float*)alloc(MR * 4);
    float* wkb   = (float*)alloc(MR * 4);

    // weight transposes (fp32 -> bf16 N x K)
    for (int p = 0; p < 2; ++p) {
        k_transpose_w<<<dim3(16, 16, 9), 256, 0, stream>>>(pp[p].wqkv, wqkvT[p], 512, 512);
        k_transpose_w<<<dim3(16, 16, 3), 256, 0, stream>>>(pp[p].wo, woT[p], 512, 512);
        k_transpose_w<<<dim3(64, 16, 3), 256, 0, stream>>>(pp[p].w1, w1T[p], 512, 2048);
        k_transpose_w<<<dim3(16, 64, 3), 256, 0, stream>>>(pp[p].w2, w2T[p], 2048, 512);
    }

    const int n4 = (int)(MR * 512 / 4);  // 1048576
    k_cvt<<<4096, 256, 0, stream>>>(emb, x32, x16, n4);

    // ---------------- encoder ----------------
    for (int i = 0; i < TL; ++i) {
        k_gemm<3, 128><<<dim3(12, 64), 256, 0, stream>>>(
            x16, x16, 1536, wqkvT[0] + (size_t)i * 1536 * 512, pp[0].bqkv + i * 1536,
            nullptr, qbuf, nullptr, kcb, vtb, 1536, 512, 1536, 0);
        k_attn<0><<<dim3(8, 128), 256, 0, stream>>>(qbuf, kcb, vtb, lengths, att16);
        k_gemm<2, 64><<<dim3(8, 64), 256, 0, stream>>>(
            att16, att16, 512, woT[0] + (size_t)i * 512 * 512, pp[0].bo + i * 512,
            x32, nullptr, preln, nullptr, nullptr, 512, 512, 512, 0);
        k_ln<<<2048, 256, 0, stream>>>(preln, pp[0].ln1g + i * 512, pp[0].ln1b + i * 512, x32, x16);
        k_gemm<1, 128><<<dim3(16, 64), 256, 0, stream>>>(
            x16, x16, 2048, w1T[0] + (size_t)i * 2048 * 512, pp[0].b1 + i * 2048,
            nullptr, h16, nullptr, nullptr, nullptr, 2048, 512, 2048, 0);
        k_gemm<2, 64><<<dim3(8, 64), 256, 0, stream>>>(
            h16, h16, 512, w2T[0] + (size_t)i * 512 * 2048, pp[0].b2 + i * 512,
            x32, nullptr, preln, nullptr, nullptr, 512, 2048, 512, 0);
        if (i == TL - 1)
            k_ln<<<2048, 256, 0, stream>>>(preln, pp[0].ln2g + i * 512, pp[0].ln2b + i * 512, mem32, mem16);
        else
            k_ln<<<2048, 256, 0, stream>>>(preln, pp[0].ln2g + i * 512, pp[0].ln2b + i * 512, x32, x16);
    }
    k_cvt<<<4096, 256, 0, stream>>>(emb, x32, x16, n4);       // decoder input

    // ---------------- decoder ----------------
    for (int i = 0; i < TL; ++i) {
        // fused q (from y) + k,v (from memory) in one dispatch
        k_gemm<3, 128><<<dim3(12, 64), 256, 0, stream>>>(
            x16, mem16, 512, wqkvT[1] + (size_t)i * 1536 * 512, pp[1].bqkv + i * 1536,
            nullptr, qbuf, nullptr, kcb, vtb, 1536, 512, 1536, 0);
        k_attn<1><<<dim3(8, 128), 256, 0, stream>>>(qbuf, kcb, vtb, lengths, att16);
        k_gemm<2, 64><<<dim3(8, 64), 256, 0, stream>>>(
            att16, att16, 512, woT[1] + (size_t)i * 512 * 512, pp[1].bo + i * 512,
            x32, nullptr, preln, nullptr, nullptr, 512, 512, 512, 0);
        k_ln<<<2048, 256, 0, stream>>>(preln, pp[1].ln1g + i * 512, pp[1].ln1b + i * 512, x32, x16);
        k_gemm<1, 128><<<dim3(16, 64), 256, 0, stream>>>(
            x16, x16, 2048, w1T[1] + (size_t)i * 2048 * 512, pp[1].b1 + i * 2048,
            nullptr, h16, nullptr, nullptr, nullptr, 2048, 512, 2048, 0);
        k_gemm<2, 64><<<dim3(8, 64), 256, 0, stream>>>(
            h16, h16, 512, w2T[1] + (size_t)i * 512 * 2048, pp[1].b2 + i * 512,
            x32, nullptr, preln, nullptr, nullptr, 512, 2048, 512, 0);
        k_ln<<<2048, 256, 0, stream>>>(preln, pp[1].ln2g + i * 512, pp[1].ln2b + i * 512, x32, x16);
    }

    // ---------------- pointer head ----------------
    k_rowdot<<<2048, 256, 0, stream>>>(x32, pwq, wqb);
    k_rowdot<<<2048, 256, 0, stream>>>(mem32, pwk, wkb);
    k_ptr_out<<<TB * TS, 256, 0, stream>>>(wqb, wkb, (float*)d_out);
}

// Round 8
// 977.542 us; speedup vs baseline: 1.4491x; 1.0461x over previous
//
#include <hip/hip_runtime.h>
#include <hip/hip_bf16.h>
#include <math.h>

#define TB 16
#define TS 512
#define TF 512
#define TH 8
#define TFF 2048
#define TL 3

typedef unsigned short u16;
typedef short bf16x8 __attribute__((ext_vector_type(8)));
typedef float f32x4 __attribute__((ext_vector_type(4)));

__device__ __forceinline__ u16 f2b(float f) {
    __hip_bfloat16 h = __float2bfloat16(f);
    return *reinterpret_cast<u16*>(&h);
}

__device__ __forceinline__ void gload_lds16(const void* g, void* l) {
    __builtin_amdgcn_global_load_lds(
        (const __attribute__((address_space(1))) unsigned int*)g,
        (__attribute__((address_space(3))) unsigned int*)l, 16, 0, 0);
}

// ---------------------------------------------------------------------------
// Batched transpose + fp32->bf16: src z matrices K x N (row-major) -> dst N x K
// ---------------------------------------------------------------------------
__global__ __launch_bounds__(256) void k_transpose_w(
    const float* __restrict__ src, u16* __restrict__ dst, int K, int N)
{
    __shared__ float tile[32][33];
    const int z = blockIdx.z;
    src += (size_t)z * K * N;
    dst += (size_t)z * K * N;
    const int n0 = blockIdx.x * 32, k0 = blockIdx.y * 32;
    const int tx = threadIdx.x & 31, ty = threadIdx.x >> 5;  // 32 x 8
    #pragma unroll
    for (int i = 0; i < 32; i += 8)
        tile[ty + i][tx] = src[(size_t)(k0 + ty + i) * N + n0 + tx];
    __syncthreads();
    #pragma unroll
    for (int i = 0; i < 32; i += 8)
        dst[(size_t)(n0 + ty + i) * K + k0 + tx] = f2b(tile[tx][ty + i]);
}

// ---------------------------------------------------------------------------
// fp32 -> fp32 copy + bf16 convert (vectorized by 4)
// ---------------------------------------------------------------------------
__global__ __launch_bounds__(256) void k_cvt(
    const float* __restrict__ src, float* __restrict__ d32,
    u16* __restrict__ d16, int n4)
{
    const int i = blockIdx.x * 256 + threadIdx.x;
    if (i >= n4) return;
    float4 v = ((const float4*)src)[i];
    if (d32) ((float4*)d32)[i] = v;
    ushort4 p;
    p.x = f2b(v.x); p.y = f2b(v.y); p.z = f2b(v.z); p.w = f2b(v.w);
    ((ushort4*)d16)[i] = p;
}

// ---------------------------------------------------------------------------
// 8-wave bf16 GEMM, deep-pipelined (T3/T4-style): BM=128 x BN (256 or 128),
// BK=64, 512 threads as 2x4 waves, per-wave 64 x BN/4.
// Per K-tile: vmcnt(NL) gate (2-tile lookahead, never 0 mid-loop) -> barrier ->
// front-loaded ds_reads (all operands) -> lgkmcnt(0) -> MFMA half1 -> barrier
// (buffer free) -> issue stage(t+2) -> MFMA half2.
// Dual-A split at asplit (decoder qkv fuse). XCD-chunk block swizzle.
// EPI 0: +bias->bf16; 1: +bias,gelu->bf16; 2: +bias,+resid->f32;
// EPI 3 (BN=256 only): scatter q/k; V via wave-local LDS-bounce transpose.
// ---------------------------------------------------------------------------
template<int EPI, int BN>
__global__ __launch_bounds__(512, 1) void k_g8(
    const u16* __restrict__ A, const u16* __restrict__ A2, int asplit,
    const u16* __restrict__ BT,
    const float* __restrict__ bias, const float* __restrict__ resid,
    u16* __restrict__ outb, float* __restrict__ outf,
    u16* __restrict__ out_k, u16* __restrict__ out_v,
    int N, int K, int ldo, int coloff)
{
    constexpr int NFB = BN / 64;          // n-frags per wave (4 or 2)
    constexpr int NL = 2 + BN / 64;       // gload instrs per wave per tile
    __shared__ __align__(16) u16 SH[2 * 128 * 64 + 2 * BN * 64];
    u16* Asm = SH;                        // [2][128*64]
    u16* Bsm = SH + 2 * 128 * 64;         // [2][BN*64]

    const int gx = gridDim.x;
    int bid = blockIdx.y * gx + blockIdx.x;
    const int cpx = (gx * gridDim.y) >> 3;
    bid = (bid & 7) * cpx + (bid >> 3);
    const int bn = bid % gx, bm = bid / gx;

    const int t = threadIdx.x;
    const int w = t >> 6, l = t & 63;
    const int wm = w >> 2, wn = w & 3;    // 2 x 4 waves
    const int lhi = l >> 4, llo = l & 15;

    f32x4 acc[4][NFB];
    #pragma unroll
    for (int m = 0; m < 4; ++m)
        #pragma unroll
        for (int n = 0; n < NFB; ++n)
            acc[m][n] = f32x4{0.f, 0.f, 0.f, 0.f};

    const u16* Asrc = (bn * BN < asplit) ? A : A2;
    const int lr = l >> 3;
    const int lcz = ((l & 7) ^ lr) * 8;   // inverse-swizzled source chunk
    const u16* Ag = Asrc + (size_t)(bm * 128 + w * 8 + lr) * K + lcz;
    const u16* Bg = BT + (size_t)(bn * BN + w * 8 + lr) * K + lcz;

    auto stage = [&](int buf, int tt) {
        const int kofs = tt << 6;
        gload_lds16(Ag + kofs,          Asm + buf * 8192 + (w * 8) * 64);
        gload_lds16(Ag + 64 * K + kofs, Asm + buf * 8192 + (64 + w * 8) * 64);
        #pragma unroll
        for (int i = 0; i < BN / 64; ++i)
            gload_lds16(Bg + (size_t)i * 64 * K + kofs,
                        Bsm + buf * (BN * 64) + (i * 64 + w * 8) * 64);
    };

    const int NT = K >> 6;
    stage(0, 0);
    stage(1, 1);
    for (int tt = 0; tt < NT; ++tt) {
        const int cur = tt & 1;
        if (tt + 1 < NT) {
            if constexpr (BN == 256) asm volatile("s_waitcnt vmcnt(6)" ::: "memory");
            else                     asm volatile("s_waitcnt vmcnt(4)" ::: "memory");
        } else {
            asm volatile("s_waitcnt vmcnt(0)" ::: "memory");
        }
        __builtin_amdgcn_s_barrier();
        __builtin_amdgcn_sched_barrier(0);

        bf16x8 af[4][2], bfr[NFB][2];
        #pragma unroll
        for (int m = 0; m < 4; ++m) {
            const int row = wm * 64 + m * 16 + llo;
            const int x = row & 7;
            af[m][0] = *(const bf16x8*)(Asm + cur * 8192 + row * 64 + ((lhi) ^ x) * 8);
            af[m][1] = *(const bf16x8*)(Asm + cur * 8192 + row * 64 + ((4 + lhi) ^ x) * 8);
        }
        #pragma unroll
        for (int n = 0; n < NFB; ++n) {
            const int row = wn * (BN / 4) + n * 16 + llo;
            const int x = row & 7;
            bfr[n][0] = *(const bf16x8*)(Bsm + cur * (BN * 64) + row * 64 + ((lhi) ^ x) * 8);
            bfr[n][1] = *(const bf16x8*)(Bsm + cur * (BN * 64) + row * 64 + ((4 + lhi) ^ x) * 8);
        }
        asm volatile("s_waitcnt lgkmcnt(0)" ::: "memory");
        __builtin_amdgcn_sched_barrier(0);
        __builtin_amdgcn_s_setprio(1);
        #pragma unroll
        for (int m = 0; m < 2; ++m)
            #pragma unroll
            for (int n = 0; n < NFB; ++n) {
                acc[m][n] = __builtin_amdgcn_mfma_f32_16x16x32_bf16(af[m][0], bfr[n][0], acc[m][n], 0, 0, 0);
                acc[m][n] = __builtin_amdgcn_mfma_f32_16x16x32_bf16(af[m][1], bfr[n][1], acc[m][n], 0, 0, 0);
            }
        __builtin_amdgcn_s_setprio(0);
        __builtin_amdgcn_sched_barrier(0);
        __builtin_amdgcn_s_barrier();          // all waves done reading buf[cur]
        if (tt + 2 < NT) stage(cur, tt + 2);   // 2-tile-ahead prefetch
        __builtin_amdgcn_s_setprio(1);
        #pragma unroll
        for (int m = 2; m < 4; ++m)
            #pragma unroll
            for (int n = 0; n < NFB; ++n) {
                acc[m][n] = __builtin_amdgcn_mfma_f32_16x16x32_bf16(af[m][0], bfr[n][0], acc[m][n], 0, 0, 0);
                acc[m][n] = __builtin_amdgcn_mfma_f32_16x16x32_bf16(af[m][1], bfr[n][1], acc[m][n], 0, 0, 0);
            }
        __builtin_amdgcn_s_setprio(0);
    }

    const int colb = bn * BN + wn * (BN / 4);
    const int rowb = bm * 128 + wm * 64 + lhi * 4;
    const int c0w = coloff + colb;

    if constexpr (EPI == 3 && BN == 256) {
        if (c0w >= 1024) {
            // ---- V region: wave-local 64s x 64d transpose via LDS ----
            u16* tb = SH + w * 4096;   // 8 KB per wave (SH dead after loop)
            #pragma unroll
            for (int n = 0; n < 4; ++n) {
                const int dl = n * 16 + llo;
                const float bv = bias[colb + n * 16 + llo];
                #pragma unroll
                for (int m = 0; m < 4; ++m) {
                    ushort4 pk;
                    #pragma unroll
                    for (int r = 0; r < 4; ++r)
                        ((u16*)&pk)[r] = f2b(acc[m][n][r] + bv);
                    const int slc = m * 2 + (lhi >> 1);
                    const int addr = dl * 64 + ((slc ^ (dl & 7)) << 3) + ((lhi & 1) << 2);
                    *(ushort4*)(tb + addr) = pk;
                }
            }
            asm volatile("s_waitcnt lgkmcnt(0)" ::: "memory");
            __builtin_amdgcn_sched_barrier(0);
            const int sbase = bm * 128 + wm * 64;
            const int bidx = sbase >> 9;
            const int srem = sbase & 511;
            const int hh = (c0w >> 6) & 7;
            u16* vo = out_v + ((size_t)bidx * 8 + hh) * 32768 + srem;
            const int cchunk = l & 7;
            #pragma unroll
            for (int rr = 0; rr < 8; ++rr) {
                const int dl2 = (l >> 3) + rr * 8;
                const int ch = cchunk ^ (dl2 & 7);
                bf16x8 vv = *(const bf16x8*)(tb + dl2 * 64 + ch * 8);
                *(bf16x8*)(vo + (size_t)dl2 * 512 + cchunk * 8) = vv;
            }
            return;
        }
    }

    #pragma unroll
    for (int n = 0; n < NFB; ++n) {
        const int col = colb + n * 16 + llo;
        const float bv = bias[col];
        #pragma unroll
        for (int m = 0; m < 4; ++m) {
            const int row = rowb + m * 16;
            if (EPI == 3) {
                float vv[4];
                #pragma unroll
                for (int r = 0; r < 4; ++r) vv[r] = acc[m][n][r] + bv;
                const int c = coloff + col;
                if ((c >> 9) == 0) {
                    #pragma unroll
                    for (int r = 0; r < 4; ++r)
                        outb[(size_t)(row + r) * 512 + c] = f2b(vv[r]);
                } else {
                    const int hh = (c >> 6) & 7, d = c & 63;
                    #pragma unroll
                    for (int r = 0; r < 4; ++r) {
                        const int rr = row + r;
                        out_k[((size_t)(rr >> 9) * 8 + hh) * 32768 + (rr & 511) * 64 + d] = f2b(vv[r]);
                    }
                }
            } else {
                #pragma unroll
                for (int r = 0; r < 4; ++r) {
                    float v = acc[m][n][r] + bv;
                    const size_t off = (size_t)(row + r) * ldo + coloff + col;
                    if (EPI == 0) {
                        outb[off] = f2b(v);
                    } else if (EPI == 1) {
                        v = 0.5f * v * (1.f + erff(v * 0.70710678118654752f));
                        outb[off] = f2b(v);
                    } else {
                        outf[off] = v + resid[off];
                    }
                }
            }
        }
    }
}

// ---------------------------------------------------------------------------
// Fused flash attention, swapped QK^T, block-level LDS K/V staging,
// double-buffered with counted vmcnt (unchanged).
// ---------------------------------------------------------------------------
template<int DEC>
__global__ __launch_bounds__(256) void k_attn(
    const u16* __restrict__ qb, const u16* __restrict__ kc,
    const u16* __restrict__ vtp, const int* __restrict__ lengths,
    u16* __restrict__ out)
{
    __shared__ __align__(16) u16 Ks[2][64 * 64];
    __shared__ __align__(16) u16 Vs[2][64 * 64];
    __shared__ __align__(16) u16 plds[4][16][64];
    __shared__ float alds[4][16];
    __shared__ float llds[4][16];
    const int qt = blockIdx.x;
    const int bh = blockIdx.y;
    const int b = bh >> 3;
    const int h = bh & 7;
    const int t = threadIdx.x, w = t >> 6, l = t & 63;
    const int lhi = l >> 4, llo = l & 15;
    const int len = lengths[b];
    const int qrow0 = qt * 64 + w * 16;
    const int q = qrow0 + llo;

    const u16* qp = qb + (size_t)(b * TS + q) * 512 + h * 64 + lhi * 8;
    bf16x8 qf0 = *(const bf16x8*)(qp);
    bf16x8 qf1 = *(const bf16x8*)(qp + 32);

    const u16* kb = kc  + (size_t)bh * 32768;
    const u16* vb = vtp + (size_t)bh * 32768;

    const int qlim = DEC ? min(max(q, 1), len) : len;
    const int limb = DEC ? min(qt * 64 + 63, len) : len;
    const int ktend = (limb + 63) >> 6;

    f32x4 o[4];
    #pragma unroll
    for (int g = 0; g < 4; ++g) o[g] = f32x4{0.f, 0.f, 0.f, 0.f};
    float mrun = -1e30f, lrun = 0.f;

    const float SC = 0.18033688011112042f;  // 0.125 * log2(e)

    const int sr = w * 8 + (l >> 3);
    const int sc = (((l & 7) ^ (sr & 7)) << 3);
    auto stage = [&](int buf, int ktt) {
        gload_lds16(kb + ((ktt * 64 + sr) << 6) + sc,        &Ks[buf][(w * 8) * 64]);
        gload_lds16(kb + ((ktt * 64 + 32 + sr) << 6) + sc,   &Ks[buf][(32 + w * 8) * 64]);
        gload_lds16(vb + (size_t)sr * 512 + ktt * 64 + sc,   &Vs[buf][(w * 8) * 64]);
        gload_lds16(vb + (size_t)(32 + sr) * 512 + ktt * 64 + sc, &Vs[buf][(32 + w * 8) * 64]);
    };

    stage(0, 0);
    for (int kt = 0; kt < ktend; ++kt) {
        const int cur = kt & 1;
        if (kt + 1 < ktend) {
            stage(cur ^ 1, kt + 1);
            asm volatile("s_waitcnt vmcnt(4)" ::: "memory");
        } else {
            asm volatile("s_waitcnt vmcnt(0)" ::: "memory");
        }
        __builtin_amdgcn_s_barrier();
        __builtin_amdgcn_sched_barrier(0);

        bf16x8 kf[4][2], vf[4][2];
        #pragma unroll
        for (int g = 0; g < 4; ++g) {
            const int row = g * 16 + llo;
            const int x = row & 7;
            kf[g][0] = *(const bf16x8*)&Ks[cur][row * 64 + ((lhi) ^ x) * 8];
            kf[g][1] = *(const bf16x8*)&Ks[cur][row * 64 + ((4 + lhi) ^ x) * 8];
            vf[g][0] = *(const bf16x8*)&Vs[cur][row * 64 + ((lhi) ^ x) * 8];
            vf[g][1] = *(const bf16x8*)&Vs[cur][row * 64 + ((4 + lhi) ^ x) * 8];
        }
        f32x4 s[4];
        #pragma unroll
        for (int g = 0; g < 4; ++g) {
            s[g] = f32x4{0.f, 0.f, 0.f, 0.f};
            s[g] = __builtin_amdgcn_mfma_f32_16x16x32_bf16(kf[g][0], qf0, s[g], 0, 0, 0);
            s[g] = __builtin_amdgcn_mfma_f32_16x16x32_bf16(kf[g][1], qf1, s[g], 0, 0, 0);
        }
        #pragma unroll
        for (int g = 0; g < 4; ++g) {
            const int key = kt * 64 + g * 16 + lhi * 4;
            #pragma unroll
            for (int r = 0; r < 4; ++r)
                s[g][r] = (key + r < qlim) ? s[g][r] * SC : -1e30f;
        }
        float tm = fmaxf(fmaxf(fmaxf(s[0][0], s[0][1]), fmaxf(s[0][2], s[0][3])),
                         fmaxf(fmaxf(s[1][0], s[1][1]), fmaxf(s[1][2], s[1][3])));
        tm = fmaxf(tm, fmaxf(fmaxf(fmaxf(s[2][0], s[2][1]), fmaxf(s[2][2], s[2][3])),
                             fmaxf(fmaxf(s[3][0], s[3][1]), fmaxf(s[3][2], s[3][3]))));
        tm = fmaxf(tm, __shfl_xor(tm, 16));
        tm = fmaxf(tm, __shfl_xor(tm, 32));
        const float mnew = fmaxf(mrun, tm);
        const float alpha = exp2f(mrun - mnew);
        mrun = mnew;
        float rs = 0.f;
        ushort4 pk[4];
        #pragma unroll
        for (int g = 0; g < 4; ++g) {
            #pragma unroll
            for (int r = 0; r < 4; ++r) {
                const float p = exp2f(s[g][r] - mnew);
                rs += p;
                ((u16*)&pk[g])[r] = f2b(p);
            }
        }
        rs += __shfl_xor(rs, 16);
        rs += __shfl_xor(rs, 32);
        lrun = lrun * alpha + rs;
        if (lhi == 0) alds[w][llo] = alpha;
        #pragma unroll
        for (int g = 0; g < 4; ++g) {
            const int chw = (g * 2 + (lhi >> 1)) ^ (llo & 7);
            *(ushort4*)((char*)&plds[w][0][0] + llo * 128 + chw * 16 + (lhi & 1) * 8) = pk[g];
        }
        const float4 av = *(const float4*)&alds[w][lhi * 4];
        #pragma unroll
        for (int g = 0; g < 4; ++g) {
            o[g][0] *= av.x; o[g][1] *= av.y; o[g][2] *= av.z; o[g][3] *= av.w;
        }
        #pragma unroll
        for (int ks = 0; ks < 2; ++ks) {
            const int chr = (ks * 4 + lhi) ^ (llo & 7);
            bf16x8 pa = *(const bf16x8*)((const char*)&plds[w][0][0] + llo * 128 + chr * 16);
            #pragma unroll
            for (int g = 0; g < 4; ++g)
                o[g] = __builtin_amdgcn_mfma_f32_16x16x32_bf16(pa, vf[g][ks], o[g], 0, 0, 0);
        }
        __builtin_amdgcn_sched_barrier(0);
        __builtin_amdgcn_s_barrier();
    }

    if (lhi == 0) llds[w][llo] = 1.f / lrun;
    __builtin_amdgcn_s_waitcnt(0);
    const float4 linv = *(const float4*)&llds[w][lhi * 4];
    #pragma unroll
    for (int g = 0; g < 4; ++g) {
        const int d = h * 64 + g * 16 + llo;
        #pragma unroll
        for (int r = 0; r < 4; ++r) {
            const int qq = qrow0 + lhi * 4 + r;
            out[(size_t)(b * TS + qq) * 512 + d] = f2b(o[g][r] * ((const float*)&linv)[r]);
        }
    }
}

// ---------------------------------------------------------------------------
// LayerNorm over F=512; one wave per row; writes f32 + bf16
// ---------------------------------------------------------------------------
__global__ __launch_bounds__(256) void k_ln(
    const float* __restrict__ in, const float* __restrict__ gam,
    const float* __restrict__ bet, float* __restrict__ o32, u16* __restrict__ o16)
{
    const int row = blockIdx.x * 4 + (threadIdx.x >> 6);
    const int l = threadIdx.x & 63;
    const float* p = in + (size_t)row * 512 + l * 8;
    float x[8];
    *(float4*)&x[0] = *(const float4*)p;
    *(float4*)&x[4] = *(const float4*)(p + 4);
    float s = x[0] + x[1] + x[2] + x[3] + x[4] + x[5] + x[6] + x[7];
    #pragma unroll
    for (int off = 32; off; off >>= 1) s += __shfl_xor(s, off);
    const float mu = s * (1.f / 512.f);
    float v = 0.f;
    #pragma unroll
    for (int i = 0; i < 8; ++i) { const float d = x[i] - mu; v += d * d; }
    #pragma unroll
    for (int off = 32; off; off >>= 1) v += __shfl_xor(v, off);
    const float rstd = rsqrtf(v * (1.f / 512.f) + 1e-5f);
    float gg[8], bb[8];
    *(float4*)&gg[0] = *(const float4*)(gam + l * 8);
    *(float4*)&gg[4] = *(const float4*)(gam + l * 8 + 4);
    *(float4*)&bb[0] = *(const float4*)(bet + l * 8);
    *(float4*)&bb[4] = *(const float4*)(bet + l * 8 + 4);
    float y[8];
    #pragma unroll
    for (int i = 0; i < 8; ++i) y[i] = (x[i] - mu) * rstd * gg[i] + bb[i];
    float* op = o32 + (size_t)row * 512 + l * 8;
    *(float4*)op = *(float4*)&y[0];
    *(float4*)(op + 4) = *(float4*)&y[4];
    ushort4 pk0, pk1;
    pk0.x = f2b(y[0]); pk0.y = f2b(y[1]); pk0.z = f2b(y[2]); pk0.w = f2b(y[3]);
    pk1.x = f2b(y[4]); pk1.y = f2b(y[5]); pk1.z = f2b(y[6]); pk1.w = f2b(y[7]);
    ushort4* o16p = (ushort4*)(o16 + (size_t)row * 512 + l * 8);
    o16p[0] = pk0; o16p[1] = pk1;
}

// ---------------------------------------------------------------------------
__global__ __launch_bounds__(256) void k_rowdot(
    const float* __restrict__ x, const float* __restrict__ wv, float* __restrict__ out)
{
    const int row = blockIdx.x * 4 + (threadIdx.x >> 6);
    const int l = threadIdx.x & 63;
    const float* p = x + (size_t)row * 512 + l * 8;
    float4 a = *(const float4*)p;
    float4 b = *(const float4*)(p + 4);
    float4 wa = *(const float4*)(wv + l * 8);
    float4 wb = *(const float4*)(wv + l * 8 + 4);
    float s = a.x * wa.x + a.y * wa.y + a.z * wa.z + a.w * wa.w
            + b.x * wb.x + b.y * wb.y + b.z * wb.z + b.w * wb.w;
    #pragma unroll
    for (int off = 32; off; off >>= 1) s += __shfl_xor(s, off);
    if (l == 0) out[row] = s;
}

// ---------------------------------------------------------------------------
__global__ __launch_bounds__(256) void k_ptr_out(
    const float* __restrict__ wq, const float* __restrict__ wk, float* __restrict__ out)
{
    const int bi = blockIdx.x;
    const int b = bi >> 9;
    const float wki = wk[bi];
    #pragma unroll
    for (int j = threadIdx.x; j < 512; j += 256) {
        float r = 0.f;
        if (j != 0) {
            const float z = (wq[b * 512 + j] + wki) * 0.044194173824159216f;
            r = 1.f / (1.f + __expf(-z));
        }
        out[(size_t)bi * 512 + j] = r;
    }
}

// ---------------------------------------------------------------------------
extern "C" void kernel_launch(void* const* d_in, const int* in_sizes, int n_in,
                              void* d_out, int out_size, void* d_ws, size_t ws_size,
                              hipStream_t stream)
{
    const float* emb = (const float*)d_in[0];
    const int* lengths = (const int*)d_in[1];
    struct Pw {
        const float *wqkv, *bqkv, *wo, *bo, *ln1g, *ln1b, *w1, *b1, *w2, *b2, *ln2g, *ln2b;
    } pp[2];
    for (int p = 0; p < 2; ++p) {
        const int base = 2 + p * 12;
        pp[p].wqkv = (const float*)d_in[base + 0];
        pp[p].bqkv = (const float*)d_in[base + 1];
        pp[p].wo   = (const float*)d_in[base + 2];
        pp[p].bo   = (const float*)d_in[base + 3];
        pp[p].ln1g = (const float*)d_in[base + 4];
        pp[p].ln1b = (const float*)d_in[base + 5];
        pp[p].w1   = (const float*)d_in[base + 6];
        pp[p].b1   = (const float*)d_in[base + 7];
        pp[p].w2   = (const float*)d_in[base + 8];
        pp[p].b2   = (const float*)d_in[base + 9];
        pp[p].ln2g = (const float*)d_in[base + 10];
        pp[p].ln2b = (const float*)d_in[base + 11];
    }
    const float* pwq = (const float*)d_in[26];
    const float* pwk = (const float*)d_in[27];

    char* ws = (char*)d_ws;
    auto alloc = [&](size_t bytes) {
        char* p = ws;
        ws += (bytes + 255) & ~(size_t)255;
        return p;
    };
    u16* wqkvT[2], *woT[2], *w1T[2], *w2T[2];
    for (int p = 0; p < 2; ++p) {
        wqkvT[p] = (u16*)alloc((size_t)TL * 1536 * 512 * 2);
        woT[p]   = (u16*)alloc((size_t)TL * 512 * 512 * 2);
        w1T[p]   = (u16*)alloc((size_t)TL * 2048 * 512 * 2);
        w2T[p]   = (u16*)alloc((size_t)TL * 512 * 2048 * 2);
    }
    const size_t MR = (size_t)TB * TS;  // 8192 rows
    float* x32   = (float*)alloc(MR * 512 * 4);
    u16*   x16   = (u16*)alloc(MR * 512 * 2);
    float* mem32 = (float*)alloc(MR * 512 * 4);
    u16*   mem16 = (u16*)alloc(MR * 512 * 2);
    u16*   qbuf  = (u16*)alloc(MR * 512 * 2);
    u16*   kcb   = (u16*)alloc((size_t)TB * TH * 512 * 64 * 2);
    u16*   vtb   = (u16*)alloc((size_t)TB * TH * 64 * 512 * 2);
    u16*   att16 = (u16*)alloc(MR * 512 * 2);
    float* preln = (float*)alloc(MR * 512 * 4);
    u16*   h16   = (u16*)alloc(MR * 2048 * 2);
    float* wqb   = (float*)alloc(MR * 4);
    float* wkb   = (float*)alloc(MR * 4);

    for (int p = 0; p < 2; ++p) {
        k_transpose_w<<<dim3(16, 16, 9), 256, 0, stream>>>(pp[p].wqkv, wqkvT[p], 512, 512);
        k_transpose_w<<<dim3(16, 16, 3), 256, 0, stream>>>(pp[p].wo, woT[p], 512, 512);
        k_transpose_w<<<dim3(64, 16, 3), 256, 0, stream>>>(pp[p].w1, w1T[p], 512, 2048);
        k_transpose_w<<<dim3(16, 64, 3), 256, 0, stream>>>(pp[p].w2, w2T[p], 2048, 512);
    }

    const int n4 = (int)(MR * 512 / 4);
    k_cvt<<<4096, 256, 0, stream>>>(emb, x32, x16, n4);

    // ---------------- encoder ----------------
    for (int i = 0; i < TL; ++i) {
        k_g8<3, 256><<<dim3(6, 64), 512, 0, stream>>>(
            x16, x16, 1536, wqkvT[0] + (size_t)i * 1536 * 512, pp[0].bqkv + i * 1536,
            nullptr, qbuf, nullptr, kcb, vtb, 1536, 512, 1536, 0);
        k_attn<0><<<dim3(8, 128), 256, 0, stream>>>(qbuf, kcb, vtb, lengths, att16);
        k_g8<2, 128><<<dim3(4, 64), 512, 0, stream>>>(
            att16, att16, 512, woT[0] + (size_t)i * 512 * 512, pp[0].bo + i * 512,
            x32, nullptr, preln, nullptr, nullptr, 512, 512, 512, 0);
        k_ln<<<2048, 256, 0, stream>>>(preln, pp[0].ln1g + i * 512, pp[0].ln1b + i * 512, x32, x16);
        k_g8<1, 256><<<dim3(8, 64), 512, 0, stream>>>(
            x16, x16, 2048, w1T[0] + (size_t)i * 2048 * 512, pp[0].b1 + i * 2048,
            nullptr, h16, nullptr, nullptr, nullptr, 2048, 512, 2048, 0);
        k_g8<2, 128><<<dim3(4, 64), 512, 0, stream>>>(
            h16, h16, 512, w2T[0] + (size_t)i * 512 * 2048, pp[0].b2 + i * 512,
            x32, nullptr, preln, nullptr, nullptr, 512, 2048, 512, 0);
        if (i == TL - 1)
            k_ln<<<2048, 256, 0, stream>>>(preln, pp[0].ln2g + i * 512, pp[0].ln2b + i * 512, mem32, mem16);
        else
            k_ln<<<2048, 256, 0, stream>>>(preln, pp[0].ln2g + i * 512, pp[0].ln2b + i * 512, x32, x16);
    }
    k_cvt<<<4096, 256, 0, stream>>>(emb, x32, x16, n4);       // decoder input

    // ---------------- decoder ----------------
    for (int i = 0; i < TL; ++i) {
        k_g8<3, 256><<<dim3(6, 64), 512, 0, stream>>>(
            x16, mem16, 512, wqkvT[1] + (size_t)i * 1536 * 512, pp[1].bqkv + i * 1536,
            nullptr, qbuf, nullptr, kcb, vtb, 1536, 512, 1536, 0);
        k_attn<1><<<dim3(8, 128), 256, 0, stream>>>(qbuf, kcb, vtb, lengths, att16);
        k_g8<2, 128><<<dim3(4, 64), 512, 0, stream>>>(
            att16, att16, 512, woT[1] + (size_t)i * 512 * 512, pp[1].bo + i * 512,
            x32, nullptr, preln, nullptr, nullptr, 512, 512, 512, 0);
        k_ln<<<2048, 256, 0, stream>>>(preln, pp[1].ln1g + i * 512, pp[1].ln1b + i * 512, x32, x16);
        k_g8<1, 256><<<dim3(8, 64), 512, 0, stream>>>(
            x16, x16, 2048, w1T[1] + (size_t)i * 2048 * 512, pp[1].b1 + i * 2048,
            nullptr, h16, nullptr, nullptr, nullptr, 2048, 512, 2048, 0);
        k_g8<2, 128><<<dim3(4, 64), 512, 0, stream>>>(
            h16, h16, 512, w2T[1] + (size_t)i * 512 * 2048, pp[1].b2 + i * 512,
            x32, nullptr, preln, nullptr, nullptr, 512, 2048, 512, 0);
        k_ln<<<2048, 256, 0, stream>>>(preln, pp[1].ln2g + i * 512, pp[1].ln2b + i * 512, x32, x16);
    }

    // ---------------- pointer head ----------------
    k_rowdot<<<2048, 256, 0, stream>>>(x32, pwq, wqb);
    k_rowdot<<<2048, 256, 0, stream>>>(mem32, pwk, wkb);
    k_ptr_out<<<TB * TS, 256, 0, stream>>>(wqb, wkb, (float*)d_out);
}

// Round 9
// 873.464 us; speedup vs baseline: 1.6217x; 1.1192x over previous
//
#include <hip/hip_runtime.h>
#include <hip/hip_bf16.h>
#include <math.h>

#define TB 16
#define TS 512
#define TF 512
#define TH 8
#define TFF 2048
#define TL 3

typedef unsigned short u16;
typedef short bf16x8 __attribute__((ext_vector_type(8)));
typedef float f32x4 __attribute__((ext_vector_type(4)));

__device__ __forceinline__ u16 f2b(float f) {
    __hip_bfloat16 h = __float2bfloat16(f);
    return *reinterpret_cast<u16*>(&h);
}
__device__ __forceinline__ float b2f(u16 u) {
    unsigned int v = ((unsigned int)u) << 16;
    return __builtin_bit_cast(float, v);
}

__device__ __forceinline__ void gload_lds16(const void* g, void* l) {
    __builtin_amdgcn_global_load_lds(
        (const __attribute__((address_space(1))) unsigned int*)g,
        (__attribute__((address_space(3))) unsigned int*)l, 16, 0, 0);
}

// ---------------------------------------------------------------------------
// Batched transpose + fp32->bf16: src z matrices K x N (row-major) -> dst N x K
// ---------------------------------------------------------------------------
__global__ __launch_bounds__(256) void k_transpose_w(
    const float* __restrict__ src, u16* __restrict__ dst, int K, int N)
{
    __shared__ float tile[32][33];
    const int z = blockIdx.z;
    src += (size_t)z * K * N;
    dst += (size_t)z * K * N;
    const int n0 = blockIdx.x * 32, k0 = blockIdx.y * 32;
    const int tx = threadIdx.x & 31, ty = threadIdx.x >> 5;  // 32 x 8
    #pragma unroll
    for (int i = 0; i < 32; i += 8)
        tile[ty + i][tx] = src[(size_t)(k0 + ty + i) * N + n0 + tx];
    __syncthreads();
    #pragma unroll
    for (int i = 0; i < 32; i += 8)
        dst[(size_t)(n0 + ty + i) * K + k0 + tx] = f2b(tile[tx][ty + i]);
}

// ---------------------------------------------------------------------------
// fp32 -> bf16 convert (vectorized by 4)
// ---------------------------------------------------------------------------
__global__ __launch_bounds__(256) void k_cvt(
    const float* __restrict__ src, u16* __restrict__ d16, int n4)
{
    const int i = blockIdx.x * 256 + threadIdx.x;
    if (i >= n4) return;
    float4 v = ((const float4*)src)[i];
    ushort4 p;
    p.x = f2b(v.x); p.y = f2b(v.y); p.z = f2b(v.z); p.w = f2b(v.w);
    ((ushort4*)d16)[i] = p;
}

// ---------------------------------------------------------------------------
// 8-wave bf16 GEMM, deep-pipelined: BM=128 x BN (256 or 128), BK=64,
// 512 threads as 2x4 waves, per-wave 64 x BN/4. Counted vmcnt, 2-tile
// lookahead, front-loaded ds_reads, setprio MFMA halves. XCD block swizzle.
// EPI 0: +bias->bf16; 1: +bias,gelu->bf16; 2: +bias,+bf16 resid->bf16;
// EPI 3 (BN=256): scatter q/k; V via wave-local LDS-bounce transpose.
// ---------------------------------------------------------------------------
template<int EPI, int BN>
__global__ __launch_bounds__(512, 1) void k_g8(
    const u16* __restrict__ A, const u16* __restrict__ A2, int asplit,
    const u16* __restrict__ BT,
    const float* __restrict__ bias, const u16* __restrict__ residb,
    u16* __restrict__ outb,
    u16* __restrict__ out_k, u16* __restrict__ out_v,
    int N, int K, int ldo, int coloff)
{
    constexpr int NFB = BN / 64;
    __shared__ __align__(16) u16 SH[2 * 128 * 64 + 2 * BN * 64];
    u16* Asm = SH;
    u16* Bsm = SH + 2 * 128 * 64;

    const int gx = gridDim.x;
    int bid = blockIdx.y * gx + blockIdx.x;
    const int cpx = (gx * gridDim.y) >> 3;
    bid = (bid & 7) * cpx + (bid >> 3);
    const int bn = bid % gx, bm = bid / gx;

    const int t = threadIdx.x;
    const int w = t >> 6, l = t & 63;
    const int wm = w >> 2, wn = w & 3;
    const int lhi = l >> 4, llo = l & 15;

    f32x4 acc[4][NFB];
    #pragma unroll
    for (int m = 0; m < 4; ++m)
        #pragma unroll
        for (int n = 0; n < NFB; ++n)
            acc[m][n] = f32x4{0.f, 0.f, 0.f, 0.f};

    const u16* Asrc = (bn * BN < asplit) ? A : A2;
    const int lr = l >> 3;
    const int lcz = ((l & 7) ^ lr) * 8;
    const u16* Ag = Asrc + (size_t)(bm * 128 + w * 8 + lr) * K + lcz;
    const u16* Bg = BT + (size_t)(bn * BN + w * 8 + lr) * K + lcz;

    auto stage = [&](int buf, int tt) {
        const int kofs = tt << 6;
        gload_lds16(Ag + kofs,          Asm + buf * 8192 + (w * 8) * 64);
        gload_lds16(Ag + 64 * K + kofs, Asm + buf * 8192 + (64 + w * 8) * 64);
        #pragma unroll
        for (int i = 0; i < BN / 64; ++i)
            gload_lds16(Bg + (size_t)i * 64 * K + kofs,
                        Bsm + buf * (BN * 64) + (i * 64 + w * 8) * 64);
    };

    const int NT = K >> 6;
    stage(0, 0);
    stage(1, 1);
    for (int tt = 0; tt < NT; ++tt) {
        const int cur = tt & 1;
        if (tt + 1 < NT) {
            if constexpr (BN == 256) asm volatile("s_waitcnt vmcnt(6)" ::: "memory");
            else                     asm volatile("s_waitcnt vmcnt(4)" ::: "memory");
        } else {
            asm volatile("s_waitcnt vmcnt(0)" ::: "memory");
        }
        __builtin_amdgcn_s_barrier();
        __builtin_amdgcn_sched_barrier(0);

        bf16x8 af[4][2], bfr[NFB][2];
        #pragma unroll
        for (int m = 0; m < 4; ++m) {
            const int row = wm * 64 + m * 16 + llo;
            const int x = row & 7;
            af[m][0] = *(const bf16x8*)(Asm + cur * 8192 + row * 64 + ((lhi) ^ x) * 8);
            af[m][1] = *(const bf16x8*)(Asm + cur * 8192 + row * 64 + ((4 + lhi) ^ x) * 8);
        }
        #pragma unroll
        for (int n = 0; n < NFB; ++n) {
            const int row = wn * (BN / 4) + n * 16 + llo;
            const int x = row & 7;
            bfr[n][0] = *(const bf16x8*)(Bsm + cur * (BN * 64) + row * 64 + ((lhi) ^ x) * 8);
            bfr[n][1] = *(const bf16x8*)(Bsm + cur * (BN * 64) + row * 64 + ((4 + lhi) ^ x) * 8);
        }
        asm volatile("s_waitcnt lgkmcnt(0)" ::: "memory");
        __builtin_amdgcn_sched_barrier(0);
        __builtin_amdgcn_s_setprio(1);
        #pragma unroll
        for (int m = 0; m < 2; ++m)
            #pragma unroll
            for (int n = 0; n < NFB; ++n) {
                acc[m][n] = __builtin_amdgcn_mfma_f32_16x16x32_bf16(af[m][0], bfr[n][0], acc[m][n], 0, 0, 0);
                acc[m][n] = __builtin_amdgcn_mfma_f32_16x16x32_bf16(af[m][1], bfr[n][1], acc[m][n], 0, 0, 0);
            }
        __builtin_amdgcn_s_setprio(0);
        __builtin_amdgcn_sched_barrier(0);
        __builtin_amdgcn_s_barrier();
        if (tt + 2 < NT) stage(cur, tt + 2);
        __builtin_amdgcn_s_setprio(1);
        #pragma unroll
        for (int m = 2; m < 4; ++m)
            #pragma unroll
            for (int n = 0; n < NFB; ++n) {
                acc[m][n] = __builtin_amdgcn_mfma_f32_16x16x32_bf16(af[m][0], bfr[n][0], acc[m][n], 0, 0, 0);
                acc[m][n] = __builtin_amdgcn_mfma_f32_16x16x32_bf16(af[m][1], bfr[n][1], acc[m][n], 0, 0, 0);
            }
        __builtin_amdgcn_s_setprio(0);
    }

    const int colb = bn * BN + wn * (BN / 4);
    const int rowb = bm * 128 + wm * 64 + lhi * 4;
    const int c0w = coloff + colb;

    if constexpr (EPI == 3 && BN == 256) {
        if (c0w >= 1024) {
            // ---- V region: wave-local 64s x 64d transpose via LDS ----
            u16* tb = SH + w * 4096;
            #pragma unroll
            for (int n = 0; n < 4; ++n) {
                const int dl = n * 16 + llo;
                const float bv = bias[colb + n * 16 + llo];
                #pragma unroll
                for (int m = 0; m < 4; ++m) {
                    ushort4 pk;
                    #pragma unroll
                    for (int r = 0; r < 4; ++r)
                        ((u16*)&pk)[r] = f2b(acc[m][n][r] + bv);
                    const int slc = m * 2 + (lhi >> 1);
                    const int addr = dl * 64 + ((slc ^ (dl & 7)) << 3) + ((lhi & 1) << 2);
                    *(ushort4*)(tb + addr) = pk;
                }
            }
            asm volatile("s_waitcnt lgkmcnt(0)" ::: "memory");
            __builtin_amdgcn_sched_barrier(0);
            const int sbase = bm * 128 + wm * 64;
            const int bidx = sbase >> 9;
            const int srem = sbase & 511;
            const int hh = (c0w >> 6) & 7;
            u16* vo = out_v + ((size_t)bidx * 8 + hh) * 32768 + srem;
            const int cchunk = l & 7;
            #pragma unroll
            for (int rr = 0; rr < 8; ++rr) {
                const int dl2 = (l >> 3) + rr * 8;
                const int ch = cchunk ^ (dl2 & 7);
                bf16x8 vv = *(const bf16x8*)(tb + dl2 * 64 + ch * 8);
                *(bf16x8*)(vo + (size_t)dl2 * 512 + cchunk * 8) = vv;
            }
            return;
        }
    }

    #pragma unroll
    for (int n = 0; n < NFB; ++n) {
        const int col = colb + n * 16 + llo;
        const float bv = bias[col];
        #pragma unroll
        for (int m = 0; m < 4; ++m) {
            const int row = rowb + m * 16;
            if (EPI == 3) {
                float vv[4];
                #pragma unroll
                for (int r = 0; r < 4; ++r) vv[r] = acc[m][n][r] + bv;
                const int c = coloff + col;
                if ((c >> 9) == 0) {
                    #pragma unroll
                    for (int r = 0; r < 4; ++r)
                        outb[(size_t)(row + r) * 512 + c] = f2b(vv[r]);
                } else {
                    const int hh = (c >> 6) & 7, d = c & 63;
                    #pragma unroll
                    for (int r = 0; r < 4; ++r) {
                        const int rr = row + r;
                        out_k[((size_t)(rr >> 9) * 8 + hh) * 32768 + (rr & 511) * 64 + d] = f2b(vv[r]);
                    }
                }
            } else {
                #pragma unroll
                for (int r = 0; r < 4; ++r) {
                    float v = acc[m][n][r] + bv;
                    const size_t off = (size_t)(row + r) * ldo + coloff + col;
                    if (EPI == 0) {
                        outb[off] = f2b(v);
                    } else if (EPI == 1) {
                        v = 0.5f * v * (1.f + erff(v * 0.70710678118654752f));
                        outb[off] = f2b(v);
                    } else {  // EPI == 2: + bf16 residual -> bf16
                        v += b2f(residb[off]);
                        outb[off] = f2b(v);
                    }
                }
            }
        }
    }
}

// ---------------------------------------------------------------------------
// Fused flash attention, swapped QK^T, block-level LDS K/V staging,
// double-buffered with counted vmcnt (unchanged).
// ---------------------------------------------------------------------------
template<int DEC>
__global__ __launch_bounds__(256) void k_attn(
    const u16* __restrict__ qb, const u16* __restrict__ kc,
    const u16* __restrict__ vtp, const int* __restrict__ lengths,
    u16* __restrict__ out)
{
    __shared__ __align__(16) u16 Ks[2][64 * 64];
    __shared__ __align__(16) u16 Vs[2][64 * 64];
    __shared__ __align__(16) u16 plds[4][16][64];
    __shared__ float alds[4][16];
    __shared__ float llds[4][16];
    const int qt = blockIdx.x;
    const int bh = blockIdx.y;
    const int b = bh >> 3;
    const int h = bh & 7;
    const int t = threadIdx.x, w = t >> 6, l = t & 63;
    const int lhi = l >> 4, llo = l & 15;
    const int len = lengths[b];
    const int qrow0 = qt * 64 + w * 16;
    const int q = qrow0 + llo;

    const u16* qp = qb + (size_t)(b * TS + q) * 512 + h * 64 + lhi * 8;
    bf16x8 qf0 = *(const bf16x8*)(qp);
    bf16x8 qf1 = *(const bf16x8*)(qp + 32);

    const u16* kb = kc  + (size_t)bh * 32768;
    const u16* vb = vtp + (size_t)bh * 32768;

    const int qlim = DEC ? min(max(q, 1), len) : len;
    const int limb = DEC ? min(qt * 64 + 63, len) : len;
    const int ktend = (limb + 63) >> 6;

    f32x4 o[4];
    #pragma unroll
    for (int g = 0; g < 4; ++g) o[g] = f32x4{0.f, 0.f, 0.f, 0.f};
    float mrun = -1e30f, lrun = 0.f;

    const float SC = 0.18033688011112042f;  // 0.125 * log2(e)

    const int sr = w * 8 + (l >> 3);
    const int sc = (((l & 7) ^ (sr & 7)) << 3);
    auto stage = [&](int buf, int ktt) {
        gload_lds16(kb + ((ktt * 64 + sr) << 6) + sc,        &Ks[buf][(w * 8) * 64]);
        gload_lds16(kb + ((ktt * 64 + 32 + sr) << 6) + sc,   &Ks[buf][(32 + w * 8) * 64]);
        gload_lds16(vb + (size_t)sr * 512 + ktt * 64 + sc,   &Vs[buf][(w * 8) * 64]);
        gload_lds16(vb + (size_t)(32 + sr) * 512 + ktt * 64 + sc, &Vs[buf][(32 + w * 8) * 64]);
    };

    stage(0, 0);
    for (int kt = 0; kt < ktend; ++kt) {
        const int cur = kt & 1;
        if (kt + 1 < ktend) {
            stage(cur ^ 1, kt + 1);
            asm volatile("s_waitcnt vmcnt(4)" ::: "memory");
        } else {
            asm volatile("s_waitcnt vmcnt(0)" ::: "memory");
        }
        __builtin_amdgcn_s_barrier();
        __builtin_amdgcn_sched_barrier(0);

        bf16x8 kf[4][2], vf[4][2];
        #pragma unroll
        for (int g = 0; g < 4; ++g) {
            const int row = g * 16 + llo;
            const int x = row & 7;
            kf[g][0] = *(const bf16x8*)&Ks[cur][row * 64 + ((lhi) ^ x) * 8];
            kf[g][1] = *(const bf16x8*)&Ks[cur][row * 64 + ((4 + lhi) ^ x) * 8];
            vf[g][0] = *(const bf16x8*)&Vs[cur][row * 64 + ((lhi) ^ x) * 8];
            vf[g][1] = *(const bf16x8*)&Vs[cur][row * 64 + ((4 + lhi) ^ x) * 8];
        }
        f32x4 s[4];
        #pragma unroll
        for (int g = 0; g < 4; ++g) {
            s[g] = f32x4{0.f, 0.f, 0.f, 0.f};
            s[g] = __builtin_amdgcn_mfma_f32_16x16x32_bf16(kf[g][0], qf0, s[g], 0, 0, 0);
            s[g] = __builtin_amdgcn_mfma_f32_16x16x32_bf16(kf[g][1], qf1, s[g], 0, 0, 0);
        }
        #pragma unroll
        for (int g = 0; g < 4; ++g) {
            const int key = kt * 64 + g * 16 + lhi * 4;
            #pragma unroll
            for (int r = 0; r < 4; ++r)
                s[g][r] = (key + r < qlim) ? s[g][r] * SC : -1e30f;
        }
        float tm = fmaxf(fmaxf(fmaxf(s[0][0], s[0][1]), fmaxf(s[0][2], s[0][3])),
                         fmaxf(fmaxf(s[1][0], s[1][1]), fmaxf(s[1][2], s[1][3])));
        tm = fmaxf(tm, fmaxf(fmaxf(fmaxf(s[2][0], s[2][1]), fmaxf(s[2][2], s[2][3])),
                             fmaxf(fmaxf(s[3][0], s[3][1]), fmaxf(s[3][2], s[3][3]))));
        tm = fmaxf(tm, __shfl_xor(tm, 16));
        tm = fmaxf(tm, __shfl_xor(tm, 32));
        const float mnew = fmaxf(mrun, tm);
        const float alpha = exp2f(mrun - mnew);
        mrun = mnew;
        float rs = 0.f;
        ushort4 pk[4];
        #pragma unroll
        for (int g = 0; g < 4; ++g) {
            #pragma unroll
            for (int r = 0; r < 4; ++r) {
                const float p = exp2f(s[g][r] - mnew);
                rs += p;
                ((u16*)&pk[g])[r] = f2b(p);
            }
        }
        rs += __shfl_xor(rs, 16);
        rs += __shfl_xor(rs, 32);
        lrun = lrun * alpha + rs;
        if (lhi == 0) alds[w][llo] = alpha;
        #pragma unroll
        for (int g = 0; g < 4; ++g) {
            const int chw = (g * 2 + (lhi >> 1)) ^ (llo & 7);
            *(ushort4*)((char*)&plds[w][0][0] + llo * 128 + chw * 16 + (lhi & 1) * 8) = pk[g];
        }
        const float4 av = *(const float4*)&alds[w][lhi * 4];
        #pragma unroll
        for (int g = 0; g < 4; ++g) {
            o[g][0] *= av.x; o[g][1] *= av.y; o[g][2] *= av.z; o[g][3] *= av.w;
        }
        #pragma unroll
        for (int ks = 0; ks < 2; ++ks) {
            const int chr = (ks * 4 + lhi) ^ (llo & 7);
            bf16x8 pa = *(const bf16x8*)((const char*)&plds[w][0][0] + llo * 128 + chr * 16);
            #pragma unroll
            for (int g = 0; g < 4; ++g)
                o[g] = __builtin_amdgcn_mfma_f32_16x16x32_bf16(pa, vf[g][ks], o[g], 0, 0, 0);
        }
        __builtin_amdgcn_sched_barrier(0);
        __builtin_amdgcn_s_barrier();
    }

    if (lhi == 0) llds[w][llo] = 1.f / lrun;
    __builtin_amdgcn_s_waitcnt(0);
    const float4 linv = *(const float4*)&llds[w][lhi * 4];
    #pragma unroll
    for (int g = 0; g < 4; ++g) {
        const int d = h * 64 + g * 16 + llo;
        #pragma unroll
        for (int r = 0; r < 4; ++r) {
            const int qq = qrow0 + lhi * 4 + r;
            out[(size_t)(b * TS + qq) * 512 + d] = f2b(o[g][r] * ((const float*)&linv)[r]);
        }
    }
}

// ---------------------------------------------------------------------------
// LayerNorm over F=512, bf16 in -> bf16 out; one wave per row.
// Optional fused row-dot against a 512-f32 vector (on pre-rounding f32 y).
// ---------------------------------------------------------------------------
__global__ __launch_bounds__(256) void k_ln(
    const u16* __restrict__ in, const float* __restrict__ gam,
    const float* __restrict__ bet, u16* __restrict__ o16,
    const float* __restrict__ dotv, float* __restrict__ dotout)
{
    const int row = blockIdx.x * 4 + (threadIdx.x >> 6);
    const int l = threadIdx.x & 63;
    bf16x8 vin = *(const bf16x8*)(in + (size_t)row * 512 + l * 8);
    float x[8];
    #pragma unroll
    for (int i = 0; i < 8; ++i) x[i] = b2f((u16)vin[i]);
    float s = x[0] + x[1] + x[2] + x[3] + x[4] + x[5] + x[6] + x[7];
    #pragma unroll
    for (int off = 32; off; off >>= 1) s += __shfl_xor(s, off);
    const float mu = s * (1.f / 512.f);
    float v = 0.f;
    #pragma unroll
    for (int i = 0; i < 8; ++i) { const float d = x[i] - mu; v += d * d; }
    #pragma unroll
    for (int off = 32; off; off >>= 1) v += __shfl_xor(v, off);
    const float rstd = rsqrtf(v * (1.f / 512.f) + 1e-5f);
    float gg[8], bb[8];
    *(float4*)&gg[0] = *(const float4*)(gam + l * 8);
    *(float4*)&gg[4] = *(const float4*)(gam + l * 8 + 4);
    *(float4*)&bb[0] = *(const float4*)(bet + l * 8);
    *(float4*)&bb[4] = *(const float4*)(bet + l * 8 + 4);
    float y[8];
    #pragma unroll
    for (int i = 0; i < 8; ++i) y[i] = (x[i] - mu) * rstd * gg[i] + bb[i];
    ushort4 pk0, pk1;
    pk0.x = f2b(y[0]); pk0.y = f2b(y[1]); pk0.z = f2b(y[2]); pk0.w = f2b(y[3]);
    pk1.x = f2b(y[4]); pk1.y = f2b(y[5]); pk1.z = f2b(y[6]); pk1.w = f2b(y[7]);
    ushort4* o16p = (ushort4*)(o16 + (size_t)row * 512 + l * 8);
    o16p[0] = pk0; o16p[1] = pk1;
    if (dotv) {
        float wa[8];
        *(float4*)&wa[0] = *(const float4*)(dotv + l * 8);
        *(float4*)&wa[4] = *(const float4*)(dotv + l * 8 + 4);
        float ds = 0.f;
        #pragma unroll
        for (int i = 0; i < 8; ++i) ds += y[i] * wa[i];
        #pragma unroll
        for (int off = 32; off; off >>= 1) ds += __shfl_xor(ds, off);
        if (l == 0) dotout[row] = ds;
    }
}

// ---------------------------------------------------------------------------
__global__ __launch_bounds__(256) void k_ptr_out(
    const float* __restrict__ wq, const float* __restrict__ wk, float* __restrict__ out)
{
    const int bi = blockIdx.x;
    const int b = bi >> 9;
    const float wki = wk[bi];
    #pragma unroll
    for (int j = threadIdx.x; j < 512; j += 256) {
        float r = 0.f;
        if (j != 0) {
            const float z = (wq[b * 512 + j] + wki) * 0.044194173824159216f;
            r = 1.f / (1.f + __expf(-z));
        }
        out[(size_t)bi * 512 + j] = r;
    }
}

// ---------------------------------------------------------------------------
extern "C" void kernel_launch(void* const* d_in, const int* in_sizes, int n_in,
                              void* d_out, int out_size, void* d_ws, size_t ws_size,
                              hipStream_t stream)
{
    const float* emb = (const float*)d_in[0];
    const int* lengths = (const int*)d_in[1];
    struct Pw {
        const float *wqkv, *bqkv, *wo, *bo, *ln1g, *ln1b, *w1, *b1, *w2, *b2, *ln2g, *ln2b;
    } pp[2];
    for (int p = 0; p < 2; ++p) {
        const int base = 2 + p * 12;
        pp[p].wqkv = (const float*)d_in[base + 0];
        pp[p].bqkv = (const float*)d_in[base + 1];
        pp[p].wo   = (const float*)d_in[base + 2];
        pp[p].bo   = (const float*)d_in[base + 3];
        pp[p].ln1g = (const float*)d_in[base + 4];
        pp[p].ln1b = (const float*)d_in[base + 5];
        pp[p].w1   = (const float*)d_in[base + 6];
        pp[p].b1   = (const float*)d_in[base + 7];
        pp[p].w2   = (const float*)d_in[base + 8];
        pp[p].b2   = (const float*)d_in[base + 9];
        pp[p].ln2g = (const float*)d_in[base + 10];
        pp[p].ln2b = (const float*)d_in[base + 11];
    }
    const float* pwq = (const float*)d_in[26];
    const float* pwk = (const float*)d_in[27];

    char* ws = (char*)d_ws;
    auto alloc = [&](size_t bytes) {
        char* p = ws;
        ws += (bytes + 255) & ~(size_t)255;
        return p;
    };
    u16* wqkvT[2], *woT[2], *w1T[2], *w2T[2];
    for (int p = 0; p < 2; ++p) {
        wqkvT[p] = (u16*)alloc((size_t)TL * 1536 * 512 * 2);
        woT[p]   = (u16*)alloc((size_t)TL * 512 * 512 * 2);
        w1T[p]   = (u16*)alloc((size_t)TL * 2048 * 512 * 2);
        w2T[p]   = (u16*)alloc((size_t)TL * 512 * 2048 * 2);
    }
    const size_t MR = (size_t)TB * TS;  // 8192 rows
    u16*   x16   = (u16*)alloc(MR * 512 * 2);
    u16*   mem16 = (u16*)alloc(MR * 512 * 2);
    u16*   pre16 = (u16*)alloc(MR * 512 * 2);
    u16*   qbuf  = (u16*)alloc(MR * 512 * 2);
    u16*   kcb   = (u16*)alloc((size_t)TB * TH * 512 * 64 * 2);
    u16*   vtb   = (u16*)alloc((size_t)TB * TH * 64 * 512 * 2);
    u16*   att16 = (u16*)alloc(MR * 512 * 2);
    u16*   h16   = (u16*)alloc(MR * 2048 * 2);
    float* wqb   = (float*)alloc(MR * 4);
    float* wkb   = (float*)alloc(MR * 4);

    for (int p = 0; p < 2; ++p) {
        k_transpose_w<<<dim3(16, 16, 9), 256, 0, stream>>>(pp[p].wqkv, wqkvT[p], 512, 512);
        k_transpose_w<<<dim3(16, 16, 3), 256, 0, stream>>>(pp[p].wo, woT[p], 512, 512);
        k_transpose_w<<<dim3(64, 16, 3), 256, 0, stream>>>(pp[p].w1, w1T[p], 512, 2048);
        k_transpose_w<<<dim3(16, 64, 3), 256, 0, stream>>>(pp[p].w2, w2T[p], 2048, 512);
    }

    const int n4 = (int)(MR * 512 / 4);
    k_cvt<<<4096, 256, 0, stream>>>(emb, x16, n4);

    // ---------------- encoder ----------------
    for (int i = 0; i < TL; ++i) {
        k_g8<3, 256><<<dim3(6, 64), 512, 0, stream>>>(
            x16, x16, 1536, wqkvT[0] + (size_t)i * 1536 * 512, pp[0].bqkv + i * 1536,
            nullptr, qbuf, kcb, vtb, 1536, 512, 1536, 0);
        k_attn<0><<<dim3(8, 128), 256, 0, stream>>>(qbuf, kcb, vtb, lengths, att16);
        k_g8<2, 128><<<dim3(4, 64), 512, 0, stream>>>(
            att16, att16, 512, woT[0] + (size_t)i * 512 * 512, pp[0].bo + i * 512,
            x16, pre16, nullptr, nullptr, 512, 512, 512, 0);
        k_ln<<<2048, 256, 0, stream>>>(pre16, pp[0].ln1g + i * 512, pp[0].ln1b + i * 512,
                                       x16, nullptr, nullptr);
        k_g8<1, 256><<<dim3(8, 64), 512, 0, stream>>>(
            x16, x16, 2048, w1T[0] + (size_t)i * 2048 * 512, pp[0].b1 + i * 2048,
            nullptr, h16, nullptr, nullptr, 2048, 512, 2048, 0);
        k_g8<2, 128><<<dim3(4, 64), 512, 0, stream>>>(
            h16, h16, 512, w2T[0] + (size_t)i * 512 * 2048, pp[0].b2 + i * 512,
            x16, pre16, nullptr, nullptr, 512, 2048, 512, 0);
        if (i == TL - 1)
            k_ln<<<2048, 256, 0, stream>>>(pre16, pp[0].ln2g + i * 512, pp[0].ln2b + i * 512,
                                           mem16, pwk, wkb);
        else
            k_ln<<<2048, 256, 0, stream>>>(pre16, pp[0].ln2g + i * 512, pp[0].ln2b + i * 512,
                                           x16, nullptr, nullptr);
    }
    k_cvt<<<4096, 256, 0, stream>>>(emb, x16, n4);   // decoder input

    // ---------------- decoder ----------------
    for (int i = 0; i < TL; ++i) {
        k_g8<3, 256><<<dim3(6, 64), 512, 0, stream>>>(
            x16, mem16, 512, wqkvT[1] + (size_t)i * 1536 * 512, pp[1].bqkv + i * 1536,
            nullptr, qbuf, kcb, vtb, 1536, 512, 1536, 0);
        k_attn<1><<<dim3(8, 128), 256, 0, stream>>>(qbuf, kcb, vtb, lengths, att16);
        k_g8<2, 128><<<dim3(4, 64), 512, 0, stream>>>(
            att16, att16, 512, woT[1] + (size_t)i * 512 * 512, pp[1].bo + i * 512,
            x16, pre16, nullptr, nullptr, 512, 512, 512, 0);
        k_ln<<<2048, 256, 0, stream>>>(pre16, pp[1].ln1g + i * 512, pp[1].ln1b + i * 512,
                                       x16, nullptr, nullptr);
        k_g8<1, 256><<<dim3(8, 64), 512, 0, stream>>>(
            x16, x16, 2048, w1T[1] + (size_t)i * 2048 * 512, pp[1].b1 + i * 2048,
            nullptr, h16, nullptr, nullptr, 2048, 512, 2048, 0);
        k_g8<2, 128><<<dim3(4, 64), 512, 0, stream>>>(
            h16, h16, 512, w2T[1] + (size_t)i * 512 * 2048, pp[1].b2 + i * 512,
            x16, pre16, nullptr, nullptr, 512, 2048, 512, 0);
        if (i == TL - 1)
            k_ln<<<2048, 256, 0, stream>>>(pre16, pp[1].ln2g + i * 512, pp[1].ln2b + i * 512,
                                           x16, pwq, wqb);
        else
            k_ln<<<2048, 256, 0, stream>>>(pre16, pp[1].ln2g + i * 512, pp[1].ln2b + i * 512,
                                           x16, nullptr, nullptr);
    }

    // ---------------- pointer head ----------------
    k_ptr_out<<<TB * TS, 256, 0, stream>>>(wqb, wkb, (float*)d_out);
}

// Round 10
// 849.162 us; speedup vs baseline: 1.6681x; 1.0286x over previous
//
#include <hip/hip_runtime.h>
#include <hip/hip_bf16.h>
#include <math.h>

#define TB 16
#define TS 512
#define TF 512
#define TH 8
#define TFF 2048
#define TL 3

typedef unsigned short u16;
typedef short bf16x8 __attribute__((ext_vector_type(8)));
typedef float f32x4 __attribute__((ext_vector_type(4)));

__device__ __forceinline__ u16 f2b(float f) {
    __hip_bfloat16 h = __float2bfloat16(f);
    return *reinterpret_cast<u16*>(&h);
}
__device__ __forceinline__ float b2f(u16 u) {
    unsigned int v = ((unsigned int)u) << 16;
    return __builtin_bit_cast(float, v);
}

__device__ __forceinline__ void gload_lds16(const void* g, void* l) {
    __builtin_amdgcn_global_load_lds(
        (const __attribute__((address_space(1))) unsigned int*)g,
        (__attribute__((address_space(3))) unsigned int*)l, 16, 0, 0);
}

// ---------------------------------------------------------------------------
// Batched transpose + fp32->bf16: src z matrices K x N (row-major) -> dst N x K
// ---------------------------------------------------------------------------
__global__ __launch_bounds__(256) void k_transpose_w(
    const float* __restrict__ src, u16* __restrict__ dst, int K, int N)
{
    __shared__ float tile[32][33];
    const int z = blockIdx.z;
    src += (size_t)z * K * N;
    dst += (size_t)z * K * N;
    const int n0 = blockIdx.x * 32, k0 = blockIdx.y * 32;
    const int tx = threadIdx.x & 31, ty = threadIdx.x >> 5;  // 32 x 8
    #pragma unroll
    for (int i = 0; i < 32; i += 8)
        tile[ty + i][tx] = src[(size_t)(k0 + ty + i) * N + n0 + tx];
    __syncthreads();
    #pragma unroll
    for (int i = 0; i < 32; i += 8)
        dst[(size_t)(n0 + ty + i) * K + k0 + tx] = f2b(tile[tx][ty + i]);
}

// ---------------------------------------------------------------------------
// fp32 -> bf16 convert (vectorized by 4)
// ---------------------------------------------------------------------------
__global__ __launch_bounds__(256) void k_cvt(
    const float* __restrict__ src, u16* __restrict__ d16, int n4)
{
    const int i = blockIdx.x * 256 + threadIdx.x;
    if (i >= n4) return;
    float4 v = ((const float4*)src)[i];
    ushort4 p;
    p.x = f2b(v.x); p.y = f2b(v.y); p.z = f2b(v.z); p.w = f2b(v.w);
    ((ushort4*)d16)[i] = p;
}

// ---------------------------------------------------------------------------
// 8-wave bf16 GEMM, fine-phase pipeline: BM=128 x BN (256 or 128), BK=64,
// 512 threads as 2x4 waves, per-wave 64 x BN/4.
// 3-buffer LDS rotation; stage(t+2) issued after tile-t gate barrier (strictly
// race-free); counted vmcnt gate (6 / 4, never 0 mid-loop).
// Per K-tile: 4 phases (BN=256) / 2 phases (BN=128) of
//   {ds_read subtile -> s_barrier -> lgkmcnt(0) -> setprio(1) 8 MFMA setprio(0)}
// so waves slip phases and reads overlap MFMAs across waves (T3/T4/T5).
// EPI 0: +bias->bf16; 1: +bias,gelu->bf16; 2: +bias,+bf16 resid->bf16;
// EPI 3 (BN=256): scatter q/k; V via wave-local LDS-bounce transpose.
// ---------------------------------------------------------------------------
template<int EPI, int BN>
__global__ __launch_bounds__(512, 1) void k_g8(
    const u16* __restrict__ A, const u16* __restrict__ A2, int asplit,
    const u16* __restrict__ BT,
    const float* __restrict__ bias, const u16* __restrict__ residb,
    u16* __restrict__ outb,
    u16* __restrict__ out_k, u16* __restrict__ out_v,
    int N, int K, int ldo, int coloff)
{
    constexpr int NFB = BN / 64;          // n-frags per wave (4 or 2)
    __shared__ __align__(16) u16 SH[3 * 128 * 64 + 3 * BN * 64];
    u16* Asm = SH;                        // [3][128*64]
    u16* Bsm = SH + 3 * 128 * 64;         // [3][BN*64]

    const int gx = gridDim.x;
    int bid = blockIdx.y * gx + blockIdx.x;
    const int cpx = (gx * gridDim.y) >> 3;
    bid = (bid & 7) * cpx + (bid >> 3);
    const int bn = bid % gx, bm = bid / gx;

    const int t = threadIdx.x;
    const int w = t >> 6, l = t & 63;
    const int wm = w >> 2, wn = w & 3;    // 2 x 4 waves
    const int lhi = l >> 4, llo = l & 15;

    f32x4 acc[4][NFB];
    #pragma unroll
    for (int m = 0; m < 4; ++m)
        #pragma unroll
        for (int n = 0; n < NFB; ++n)
            acc[m][n] = f32x4{0.f, 0.f, 0.f, 0.f};

    const u16* Asrc = (bn * BN < asplit) ? A : A2;
    const int lr = l >> 3;
    const int lcz = ((l & 7) ^ lr) * 8;   // inverse-swizzled source chunk
    const u16* Ag = Asrc + (size_t)(bm * 128 + w * 8 + lr) * K + lcz;
    const u16* Bg = BT + (size_t)(bn * BN + w * 8 + lr) * K + lcz;

    auto stage = [&](int buf, int tt) {
        const int kofs = tt << 6;
        gload_lds16(Ag + kofs,          Asm + buf * 8192 + (w * 8) * 64);
        gload_lds16(Ag + 64 * K + kofs, Asm + buf * 8192 + (64 + w * 8) * 64);
        #pragma unroll
        for (int i = 0; i < BN / 64; ++i)
            gload_lds16(Bg + (size_t)i * 64 * K + kofs,
                        Bsm + buf * (BN * 64) + (i * 64 + w * 8) * 64);
    };

    const int NT = K >> 6;
    stage(0, 0);
    stage(1, 1);
    int cur = 0;
    for (int tt = 0; tt < NT; ++tt) {
        // gate: drain tile-tt's loads (tile tt+1's stay in flight)
        if (tt + 1 < NT) {
            if constexpr (BN == 256) asm volatile("s_waitcnt vmcnt(6)" ::: "memory");
            else                     asm volatile("s_waitcnt vmcnt(4)" ::: "memory");
        } else {
            asm volatile("s_waitcnt vmcnt(0)" ::: "memory");
        }
        __builtin_amdgcn_s_barrier();
        __builtin_amdgcn_sched_barrier(0);
        // prefetch tile tt+2 into the buffer whose reads ended before the barrier
        if (tt + 2 < NT) {
            int nb = cur + 2; if (nb >= 3) nb -= 3;
            stage(nb, tt + 2);
        }

        const u16* Ab = Asm + cur * 8192;
        const u16* Bb = Bsm + cur * (BN * 64);
        bf16x8 af[4][2], bfr[NFB][2];

        if constexpr (BN == 256) {
            // 4 phases: (kk, mh)
            #pragma unroll
            for (int kk = 0; kk < 2; ++kk) {
                #pragma unroll
                for (int mh = 0; mh < 2; ++mh) {
                    #pragma unroll
                    for (int mi = 0; mi < 2; ++mi) {
                        const int m = mh * 2 + mi;
                        const int row = wm * 64 + m * 16 + llo;
                        const int x = row & 7;
                        af[m][kk] = *(const bf16x8*)(Ab + row * 64 + ((kk * 4 + lhi) ^ x) * 8);
                    }
                    if (mh == 0) {
                        #pragma unroll
                        for (int n = 0; n < NFB; ++n) {
                            const int row = wn * (BN / 4) + n * 16 + llo;
                            const int x = row & 7;
                            bfr[n][kk] = *(const bf16x8*)(Bb + row * 64 + ((kk * 4 + lhi) ^ x) * 8);
                        }
                    }
                    __builtin_amdgcn_s_barrier();
                    asm volatile("s_waitcnt lgkmcnt(0)" ::: "memory");
                    __builtin_amdgcn_sched_barrier(0);
                    __builtin_amdgcn_s_setprio(1);
                    #pragma unroll
                    for (int mi = 0; mi < 2; ++mi) {
                        const int m = mh * 2 + mi;
                        #pragma unroll
                        for (int n = 0; n < NFB; ++n)
                            acc[m][n] = __builtin_amdgcn_mfma_f32_16x16x32_bf16(
                                af[m][kk], bfr[n][kk], acc[m][n], 0, 0, 0);
                    }
                    __builtin_amdgcn_s_setprio(0);
                    __builtin_amdgcn_sched_barrier(0);
                }
            }
        } else {
            // 2 phases: kk
            #pragma unroll
            for (int kk = 0; kk < 2; ++kk) {
                #pragma unroll
                for (int m = 0; m < 4; ++m) {
                    const int row = wm * 64 + m * 16 + llo;
                    const int x = row & 7;
                    af[m][kk] = *(const bf16x8*)(Ab + row * 64 + ((kk * 4 + lhi) ^ x) * 8);
                }
                #pragma unroll
                for (int n = 0; n < NFB; ++n) {
                    const int row = wn * (BN / 4) + n * 16 + llo;
                    const int x = row & 7;
                    bfr[n][kk] = *(const bf16x8*)(Bb + row * 64 + ((kk * 4 + lhi) ^ x) * 8);
                }
                __builtin_amdgcn_s_barrier();
                asm volatile("s_waitcnt lgkmcnt(0)" ::: "memory");
                __builtin_amdgcn_sched_barrier(0);
                __builtin_amdgcn_s_setprio(1);
                #pragma unroll
                for (int m = 0; m < 4; ++m)
                    #pragma unroll
                    for (int n = 0; n < NFB; ++n)
                        acc[m][n] = __builtin_amdgcn_mfma_f32_16x16x32_bf16(
                            af[m][kk], bfr[n][kk], acc[m][n], 0, 0, 0);
                __builtin_amdgcn_s_setprio(0);
                __builtin_amdgcn_sched_barrier(0);
            }
        }
        ++cur; if (cur >= 3) cur = 0;
    }

    const int colb = bn * BN + wn * (BN / 4);
    const int rowb = bm * 128 + wm * 64 + lhi * 4;
    const int c0w = coloff + colb;

    if constexpr (EPI == 3 && BN == 256) {
        if (c0w >= 1024) {
            __builtin_amdgcn_s_barrier();   // all waves done reading LDS
            // ---- V region: wave-local 64s x 64d transpose via LDS ----
            u16* tb = SH + w * 4096;
            #pragma unroll
            for (int n = 0; n < 4; ++n) {
                const int dl = n * 16 + llo;
                const float bv = bias[colb + n * 16 + llo];
                #pragma unroll
                for (int m = 0; m < 4; ++m) {
                    ushort4 pk;
                    #pragma unroll
                    for (int r = 0; r < 4; ++r)
                        ((u16*)&pk)[r] = f2b(acc[m][n][r] + bv);
                    const int slc = m * 2 + (lhi >> 1);
                    const int addr = dl * 64 + ((slc ^ (dl & 7)) << 3) + ((lhi & 1) << 2);
                    *(ushort4*)(tb + addr) = pk;
                }
            }
            asm volatile("s_waitcnt lgkmcnt(0)" ::: "memory");
            __builtin_amdgcn_sched_barrier(0);
            const int sbase = bm * 128 + wm * 64;
            const int bidx = sbase >> 9;
            const int srem = sbase & 511;
            const int hh = (c0w >> 6) & 7;
            u16* vo = out_v + ((size_t)bidx * 8 + hh) * 32768 + srem;
            const int cchunk = l & 7;
            #pragma unroll
            for (int rr = 0; rr < 8; ++rr) {
                const int dl2 = (l >> 3) + rr * 8;
                const int ch = cchunk ^ (dl2 & 7);
                bf16x8 vv = *(const bf16x8*)(tb + dl2 * 64 + ch * 8);
                *(bf16x8*)(vo + (size_t)dl2 * 512 + cchunk * 8) = vv;
            }
            return;
        }
    }

    #pragma unroll
    for (int n = 0; n < NFB; ++n) {
        const int col = colb + n * 16 + llo;
        const float bv = bias[col];
        #pragma unroll
        for (int m = 0; m < 4; ++m) {
            const int row = rowb + m * 16;
            if (EPI == 3) {
                float vv[4];
                #pragma unroll
                for (int r = 0; r < 4; ++r) vv[r] = acc[m][n][r] + bv;
                const int c = coloff + col;
                if ((c >> 9) == 0) {
                    #pragma unroll
                    for (int r = 0; r < 4; ++r)
                        outb[(size_t)(row + r) * 512 + c] = f2b(vv[r]);
                } else {
                    const int hh = (c >> 6) & 7, d = c & 63;
                    #pragma unroll
                    for (int r = 0; r < 4; ++r) {
                        const int rr = row + r;
                        out_k[((size_t)(rr >> 9) * 8 + hh) * 32768 + (rr & 511) * 64 + d] = f2b(vv[r]);
                    }
                }
            } else {
                #pragma unroll
                for (int r = 0; r < 4; ++r) {
                    float v = acc[m][n][r] + bv;
                    const size_t off = (size_t)(row + r) * ldo + coloff + col;
                    if (EPI == 0) {
                        outb[off] = f2b(v);
                    } else if (EPI == 1) {
                        v = 0.5f * v * (1.f + erff(v * 0.70710678118654752f));
                        outb[off] = f2b(v);
                    } else {  // EPI == 2: + bf16 residual -> bf16
                        v += b2f(residb[off]);
                        outb[off] = f2b(v);
                    }
                }
            }
        }
    }
}

// ---------------------------------------------------------------------------
// Fused flash attention, swapped QK^T, block-level LDS K/V staging,
// double-buffered with counted vmcnt (unchanged).
// ---------------------------------------------------------------------------
template<int DEC>
__global__ __launch_bounds__(256) void k_attn(
    const u16* __restrict__ qb, const u16* __restrict__ kc,
    const u16* __restrict__ vtp, const int* __restrict__ lengths,
    u16* __restrict__ out)
{
    __shared__ __align__(16) u16 Ks[2][64 * 64];
    __shared__ __align__(16) u16 Vs[2][64 * 64];
    __shared__ __align__(16) u16 plds[4][16][64];
    __shared__ float alds[4][16];
    __shared__ float llds[4][16];
    const int qt = blockIdx.x;
    const int bh = blockIdx.y;
    const int b = bh >> 3;
    const int h = bh & 7;
    const int t = threadIdx.x, w = t >> 6, l = t & 63;
    const int lhi = l >> 4, llo = l & 15;
    const int len = lengths[b];
    const int qrow0 = qt * 64 + w * 16;
    const int q = qrow0 + llo;

    const u16* qp = qb + (size_t)(b * TS + q) * 512 + h * 64 + lhi * 8;
    bf16x8 qf0 = *(const bf16x8*)(qp);
    bf16x8 qf1 = *(const bf16x8*)(qp + 32);

    const u16* kb = kc  + (size_t)bh * 32768;
    const u16* vb = vtp + (size_t)bh * 32768;

    const int qlim = DEC ? min(max(q, 1), len) : len;
    const int limb = DEC ? min(qt * 64 + 63, len) : len;
    const int ktend = (limb + 63) >> 6;

    f32x4 o[4];
    #pragma unroll
    for (int g = 0; g < 4; ++g) o[g] = f32x4{0.f, 0.f, 0.f, 0.f};
    float mrun = -1e30f, lrun = 0.f;

    const float SC = 0.18033688011112042f;  // 0.125 * log2(e)

    const int sr = w * 8 + (l >> 3);
    const int sc = (((l & 7) ^ (sr & 7)) << 3);
    auto stage = [&](int buf, int ktt) {
        gload_lds16(kb + ((ktt * 64 + sr) << 6) + sc,        &Ks[buf][(w * 8) * 64]);
        gload_lds16(kb + ((ktt * 64 + 32 + sr) << 6) + sc,   &Ks[buf][(32 + w * 8) * 64]);
        gload_lds16(vb + (size_t)sr * 512 + ktt * 64 + sc,   &Vs[buf][(w * 8) * 64]);
        gload_lds16(vb + (size_t)(32 + sr) * 512 + ktt * 64 + sc, &Vs[buf][(32 + w * 8) * 64]);
    };

    stage(0, 0);
    for (int kt = 0; kt < ktend; ++kt) {
        const int cur = kt & 1;
        if (kt + 1 < ktend) {
            stage(cur ^ 1, kt + 1);
            asm volatile("s_waitcnt vmcnt(4)" ::: "memory");
        } else {
            asm volatile("s_waitcnt vmcnt(0)" ::: "memory");
        }
        __builtin_amdgcn_s_barrier();
        __builtin_amdgcn_sched_barrier(0);

        bf16x8 kf[4][2], vf[4][2];
        #pragma unroll
        for (int g = 0; g < 4; ++g) {
            const int row = g * 16 + llo;
            const int x = row & 7;
            kf[g][0] = *(const bf16x8*)&Ks[cur][row * 64 + ((lhi) ^ x) * 8];
            kf[g][1] = *(const bf16x8*)&Ks[cur][row * 64 + ((4 + lhi) ^ x) * 8];
            vf[g][0] = *(const bf16x8*)&Vs[cur][row * 64 + ((lhi) ^ x) * 8];
            vf[g][1] = *(const bf16x8*)&Vs[cur][row * 64 + ((4 + lhi) ^ x) * 8];
        }
        f32x4 s[4];
        #pragma unroll
        for (int g = 0; g < 4; ++g) {
            s[g] = f32x4{0.f, 0.f, 0.f, 0.f};
            s[g] = __builtin_amdgcn_mfma_f32_16x16x32_bf16(kf[g][0], qf0, s[g], 0, 0, 0);
            s[g] = __builtin_amdgcn_mfma_f32_16x16x32_bf16(kf[g][1], qf1, s[g], 0, 0, 0);
        }
        #pragma unroll
        for (int g = 0; g < 4; ++g) {
            const int key = kt * 64 + g * 16 + lhi * 4;
            #pragma unroll
            for (int r = 0; r < 4; ++r)
                s[g][r] = (key + r < qlim) ? s[g][r] * SC : -1e30f;
        }
        float tm = fmaxf(fmaxf(fmaxf(s[0][0], s[0][1]), fmaxf(s[0][2], s[0][3])),
                         fmaxf(fmaxf(s[1][0], s[1][1]), fmaxf(s[1][2], s[1][3])));
        tm = fmaxf(tm, fmaxf(fmaxf(fmaxf(s[2][0], s[2][1]), fmaxf(s[2][2], s[2][3])),
                             fmaxf(fmaxf(s[3][0], s[3][1]), fmaxf(s[3][2], s[3][3]))));
        tm = fmaxf(tm, __shfl_xor(tm, 16));
        tm = fmaxf(tm, __shfl_xor(tm, 32));
        const float mnew = fmaxf(mrun, tm);
        const float alpha = exp2f(mrun - mnew);
        mrun = mnew;
        float rs = 0.f;
        ushort4 pk[4];
        #pragma unroll
        for (int g = 0; g < 4; ++g) {
            #pragma unroll
            for (int r = 0; r < 4; ++r) {
                const float p = exp2f(s[g][r] - mnew);
                rs += p;
                ((u16*)&pk[g])[r] = f2b(p);
            }
        }
        rs += __shfl_xor(rs, 16);
        rs += __shfl_xor(rs, 32);
        lrun = lrun * alpha + rs;
        if (lhi == 0) alds[w][llo] = alpha;
        #pragma unroll
        for (int g = 0; g < 4; ++g) {
            const int chw = (g * 2 + (lhi >> 1)) ^ (llo & 7);
            *(ushort4*)((char*)&plds[w][0][0] + llo * 128 + chw * 16 + (lhi & 1) * 8) = pk[g];
        }
        const float4 av = *(const float4*)&alds[w][lhi * 4];
        #pragma unroll
        for (int g = 0; g < 4; ++g) {
            o[g][0] *= av.x; o[g][1] *= av.y; o[g][2] *= av.z; o[g][3] *= av.w;
        }
        #pragma unroll
        for (int ks = 0; ks < 2; ++ks) {
            const int chr = (ks * 4 + lhi) ^ (llo & 7);
            bf16x8 pa = *(const bf16x8*)((const char*)&plds[w][0][0] + llo * 128 + chr * 16);
            #pragma unroll
            for (int g = 0; g < 4; ++g)
                o[g] = __builtin_amdgcn_mfma_f32_16x16x32_bf16(pa, vf[g][ks], o[g], 0, 0, 0);
        }
        __builtin_amdgcn_sched_barrier(0);
        __builtin_amdgcn_s_barrier();
    }

    if (lhi == 0) llds[w][llo] = 1.f / lrun;
    __builtin_amdgcn_s_waitcnt(0);
    const float4 linv = *(const float4*)&llds[w][lhi * 4];
    #pragma unroll
    for (int g = 0; g < 4; ++g) {
        const int d = h * 64 + g * 16 + llo;
        #pragma unroll
        for (int r = 0; r < 4; ++r) {
            const int qq = qrow0 + lhi * 4 + r;
            out[(size_t)(b * TS + qq) * 512 + d] = f2b(o[g][r] * ((const float*)&linv)[r]);
        }
    }
}

// ---------------------------------------------------------------------------
// LayerNorm over F=512, bf16 in -> bf16 out; one wave per row.
// Optional fused row-dot against a 512-f32 vector (on pre-rounding f32 y).
// ---------------------------------------------------------------------------
__global__ __launch_bounds__(256) void k_ln(
    const u16* __restrict__ in, const float* __restrict__ gam,
    const float* __restrict__ bet, u16* __restrict__ o16,
    const float* __restrict__ dotv, float* __restrict__ dotout)
{
    const int row = blockIdx.x * 4 + (threadIdx.x >> 6);
    const int l = threadIdx.x & 63;
    bf16x8 vin = *(const bf16x8*)(in + (size_t)row * 512 + l * 8);
    float x[8];
    #pragma unroll
    for (int i = 0; i < 8; ++i) x[i] = b2f((u16)vin[i]);
    float s = x[0] + x[1] + x[2] + x[3] + x[4] + x[5] + x[6] + x[7];
    #pragma unroll
    for (int off = 32; off; off >>= 1) s += __shfl_xor(s, off);
    const float mu = s * (1.f / 512.f);
    float v = 0.f;
    #pragma unroll
    for (int i = 0; i < 8; ++i) { const float d = x[i] - mu; v += d * d; }
    #pragma unroll
    for (int off = 32; off; off >>= 1) v += __shfl_xor(v, off);
    const float rstd = rsqrtf(v * (1.f / 512.f) + 1e-5f);
    float gg[8], bb[8];
    *(float4*)&gg[0] = *(const float4*)(gam + l * 8);
    *(float4*)&gg[4] = *(const float4*)(gam + l * 8 + 4);
    *(float4*)&bb[0] = *(const float4*)(bet + l * 8);
    *(float4*)&bb[4] = *(const float4*)(bet + l * 8 + 4);
    float y[8];
    #pragma unroll
    for (int i = 0; i < 8; ++i) y[i] = (x[i] - mu) * rstd * gg[i] + bb[i];
    ushort4 pk0, pk1;
    pk0.x = f2b(y[0]); pk0.y = f2b(y[1]); pk0.z = f2b(y[2]); pk0.w = f2b(y[3]);
    pk1.x = f2b(y[4]); pk1.y = f2b(y[5]); pk1.z = f2b(y[6]); pk1.w = f2b(y[7]);
    ushort4* o16p = (ushort4*)(o16 + (size_t)row * 512 + l * 8);
    o16p[0] = pk0; o16p[1] = pk1;
    if (dotv) {
        float wa[8];
        *(float4*)&wa[0] = *(const float4*)(dotv + l * 8);
        *(float4*)&wa[4] = *(const float4*)(dotv + l * 8 + 4);
        float ds = 0.f;
        #pragma unroll
        for (int i = 0; i < 8; ++i) ds += y[i] * wa[i];
        #pragma unroll
        for (int off = 32; off; off >>= 1) ds += __shfl_xor(ds, off);
        if (l == 0) dotout[row] = ds;
    }
}

// ---------------------------------------------------------------------------
__global__ __launch_bounds__(256) void k_ptr_out(
    const float* __restrict__ wq, const float* __restrict__ wk, float* __restrict__ out)
{
    const int bi = blockIdx.x;
    const int b = bi >> 9;
    const float wki = wk[bi];
    #pragma unroll
    for (int j = threadIdx.x; j < 512; j += 256) {
        float r = 0.f;
        if (j != 0) {
            const float z = (wq[b * 512 + j] + wki) * 0.044194173824159216f;
            r = 1.f / (1.f + __expf(-z));
        }
        out[(size_t)bi * 512 + j] = r;
    }
}

// ---------------------------------------------------------------------------
extern "C" void kernel_launch(void* const* d_in, const int* in_sizes, int n_in,
                              void* d_out, int out_size, void* d_ws, size_t ws_size,
                              hipStream_t stream)
{
    const float* emb = (const float*)d_in[0];
    const int* lengths = (const int*)d_in[1];
    struct Pw {
        const float *wqkv, *bqkv, *wo, *bo, *ln1g, *ln1b, *w1, *b1, *w2, *b2, *ln2g, *ln2b;
    } pp[2];
    for (int p = 0; p < 2; ++p) {
        const int base = 2 + p * 12;
        pp[p].wqkv = (const float*)d_in[base + 0];
        pp[p].bqkv = (const float*)d_in[base + 1];
        pp[p].wo   = (const float*)d_in[base + 2];
        pp[p].bo   = (const float*)d_in[base + 3];
        pp[p].ln1g = (const float*)d_in[base + 4];
        pp[p].ln1b = (const float*)d_in[base + 5];
        pp[p].w1   = (const float*)d_in[base + 6];
        pp[p].b1   = (const float*)d_in[base + 7];
        pp[p].w2   = (const float*)d_in[base + 8];
        pp[p].b2   = (const float*)d_in[base + 9];
        pp[p].ln2g = (const float*)d_in[base + 10];
        pp[p].ln2b = (const float*)d_in[base + 11];
    }
    const float* pwq = (const float*)d_in[26];
    const float* pwk = (const float*)d_in[27];

    char* ws = (char*)d_ws;
    auto alloc = [&](size_t bytes) {
        char* p = ws;
        ws += (bytes + 255) & ~(size_t)255;
        return p;
    };
    u16* wqkvT[2], *woT[2], *w1T[2], *w2T[2];
    for (int p = 0; p < 2; ++p) {
        wqkvT[p] = (u16*)alloc((size_t)TL * 1536 * 512 * 2);
        woT[p]   = (u16*)alloc((size_t)TL * 512 * 512 * 2);
        w1T[p]   = (u16*)alloc((size_t)TL * 2048 * 512 * 2);
        w2T[p]   = (u16*)alloc((size_t)TL * 512 * 2048 * 2);
    }
    const size_t MR = (size_t)TB * TS;  // 8192 rows
    u16*   emb16 = (u16*)alloc(MR * 512 * 2);
    u16*   x16   = (u16*)alloc(MR * 512 * 2);
    u16*   mem16 = (u16*)alloc(MR * 512 * 2);
    u16*   pre16 = (u16*)alloc(MR * 512 * 2);
    u16*   qbuf  = (u16*)alloc(MR * 512 * 2);
    u16*   kcb   = (u16*)alloc((size_t)TB * TH * 512 * 64 * 2);
    u16*   vtb   = (u16*)alloc((size_t)TB * TH * 64 * 512 * 2);
    u16*   att16 = (u16*)alloc(MR * 512 * 2);
    u16*   h16   = (u16*)alloc(MR * 2048 * 2);
    float* wqb   = (float*)alloc(MR * 4);
    float* wkb   = (float*)alloc(MR * 4);

    for (int p = 0; p < 2; ++p) {
        k_transpose_w<<<dim3(16, 16, 9), 256, 0, stream>>>(pp[p].wqkv, wqkvT[p], 512, 512);
        k_transpose_w<<<dim3(16, 16, 3), 256, 0, stream>>>(pp[p].wo, woT[p], 512, 512);
        k_transpose_w<<<dim3(64, 16, 3), 256, 0, stream>>>(pp[p].w1, w1T[p], 512, 2048);
        k_transpose_w<<<dim3(16, 64, 3), 256, 0, stream>>>(pp[p].w2, w2T[p], 2048, 512);
    }

    const int n4 = (int)(MR * 512 / 4);
    k_cvt<<<4096, 256, 0, stream>>>(emb, emb16, n4);

    // ---------------- encoder ----------------
    for (int i = 0; i < TL; ++i) {
        const u16* xin = (i == 0) ? emb16 : x16;
        k_g8<3, 256><<<dim3(6, 64), 512, 0, stream>>>(
            xin, xin, 1536, wqkvT[0] + (size_t)i * 1536 * 512, pp[0].bqkv + i * 1536,
            nullptr, qbuf, kcb, vtb, 1536, 512, 1536, 0);
        k_attn<0><<<dim3(8, 128), 256, 0, stream>>>(qbuf, kcb, vtb, lengths, att16);
        k_g8<2, 128><<<dim3(4, 64), 512, 0, stream>>>(
            att16, att16, 512, woT[0] + (size_t)i * 512 * 512, pp[0].bo + i * 512,
            xin, pre16, nullptr, nullptr, 512, 512, 512, 0);
        k_ln<<<2048, 256, 0, stream>>>(pre16, pp[0].ln1g + i * 512, pp[0].ln1b + i * 512,
                                       x16, nullptr, nullptr);
        k_g8<1, 256><<<dim3(8, 64), 512, 0, stream>>>(
            x16, x16, 2048, w1T[0] + (size_t)i * 2048 * 512, pp[0].b1 + i * 2048,
            nullptr, h16, nullptr, nullptr, 2048, 512, 2048, 0);
        k_g8<2, 128><<<dim3(4, 64), 512, 0, stream>>>(
            h16, h16, 512, w2T[0] + (size_t)i * 512 * 2048, pp[0].b2 + i * 512,
            x16, pre16, nullptr, nullptr, 512, 2048, 512, 0);
        if (i == TL - 1)
            k_ln<<<2048, 256, 0, stream>>>(pre16, pp[0].ln2g + i * 512, pp[0].ln2b + i * 512,
                                           mem16, pwk, wkb);
        else
            k_ln<<<2048, 256, 0, stream>>>(pre16, pp[0].ln2g + i * 512, pp[0].ln2b + i * 512,
                                           x16, nullptr, nullptr);
    }

    // ---------------- decoder ----------------
    for (int i = 0; i < TL; ++i) {
        const u16* yin = (i == 0) ? emb16 : x16;
        k_g8<3, 256><<<dim3(6, 64), 512, 0, stream>>>(
            yin, mem16, 512, wqkvT[1] + (size_t)i * 1536 * 512, pp[1].bqkv + i * 1536,
            nullptr, qbuf, kcb, vtb, 1536, 512, 1536, 0);
        k_attn<1><<<dim3(8, 128), 256, 0, stream>>>(qbuf, kcb, vtb, lengths, att16);
        k_g8<2, 128><<<dim3(4, 64), 512, 0, stream>>>(
            att16, att16, 512, woT[1] + (size_t)i * 512 * 512, pp[1].bo + i * 512,
            yin, pre16, nullptr, nullptr, 512, 512, 512, 0);
        k_ln<<<2048, 256, 0, stream>>>(pre16, pp[1].ln1g + i * 512, pp[1].ln1b + i * 512,
                                       x16, nullptr, nullptr);
        k_g8<1, 256><<<dim3(8, 64), 512, 0, stream>>>(
            x16, x16, 2048, w1T[1] + (size_t)i * 2048 * 512, pp[1].b1 + i * 2048,
            nullptr, h16, nullptr, nullptr, 2048, 512, 2048, 0);
        k_g8<2, 128><<<dim3(4, 64), 512, 0, stream>>>(
            h16, h16, 512, w2T[1] + (size_t)i * 512 * 2048, pp[1].b2 + i * 512,
            x16, pre16, nullptr, nullptr, 512, 2048, 512, 0);
        if (i == TL - 1)
            k_ln<<<2048, 256, 0, stream>>>(pre16, pp[1].ln2g + i * 512, pp[1].ln2b + i * 512,
                                           x16, pwq, wqb);
        else
            k_ln<<<2048, 256, 0, stream>>>(pre16, pp[1].ln2g + i * 512, pp[1].ln2b + i * 512,
                                           x16, nullptr, nullptr);
    }

    // ---------------- pointer head ----------------
    k_ptr_out<<<TB * TS, 256, 0, stream>>>(wqb, wkb, (float*)d_out);
}

// Round 11
// 836.523 us; speedup vs baseline: 1.6933x; 1.0151x over previous
//
#include <hip/hip_runtime.h>
#include <hip/hip_bf16.h>
#include <math.h>

#define TB 16
#define TS 512
#define TF 512
#define TH 8
#define TFF 2048
#define TL 3

typedef unsigned short u16;
typedef short bf16x8 __attribute__((ext_vector_type(8)));
typedef float f32x4 __attribute__((ext_vector_type(4)));

__device__ __forceinline__ u16 f2b(float f) {
    __hip_bfloat16 h = __float2bfloat16(f);
    return *reinterpret_cast<u16*>(&h);
}
__device__ __forceinline__ float b2f(u16 u) {
    unsigned int v = ((unsigned int)u) << 16;
    return __builtin_bit_cast(float, v);
}

__device__ __forceinline__ void gload_lds16(const void* g, void* l) {
    __builtin_amdgcn_global_load_lds(
        (const __attribute__((address_space(1))) unsigned int*)g,
        (__attribute__((address_space(3))) unsigned int*)l, 16, 0, 0);
}

// ---------------------------------------------------------------------------
// Batched transpose + fp32->bf16: src z matrices K x N (row-major) -> dst N x K
// ---------------------------------------------------------------------------
__global__ __launch_bounds__(256) void k_transpose_w(
    const float* __restrict__ src, u16* __restrict__ dst, int K, int N)
{
    __shared__ float tile[32][33];
    const int z = blockIdx.z;
    src += (size_t)z * K * N;
    dst += (size_t)z * K * N;
    const int n0 = blockIdx.x * 32, k0 = blockIdx.y * 32;
    const int tx = threadIdx.x & 31, ty = threadIdx.x >> 5;  // 32 x 8
    #pragma unroll
    for (int i = 0; i < 32; i += 8)
        tile[ty + i][tx] = src[(size_t)(k0 + ty + i) * N + n0 + tx];
    __syncthreads();
    #pragma unroll
    for (int i = 0; i < 32; i += 8)
        dst[(size_t)(n0 + ty + i) * K + k0 + tx] = f2b(tile[tx][ty + i]);
}

// ---------------------------------------------------------------------------
// fp32 -> bf16 convert (vectorized by 4)
// ---------------------------------------------------------------------------
__global__ __launch_bounds__(256) void k_cvt(
    const float* __restrict__ src, u16* __restrict__ d16, int n4)
{
    const int i = blockIdx.x * 256 + threadIdx.x;
    if (i >= n4) return;
    float4 v = ((const float4*)src)[i];
    ushort4 p;
    p.x = f2b(v.x); p.y = f2b(v.y); p.z = f2b(v.z); p.w = f2b(v.w);
    ((ushort4*)d16)[i] = p;
}

// ---------------------------------------------------------------------------
// 8-wave bf16 GEMM, tile BM x BN (256x256 or 128x128), BK=64, 512 threads.
// Wave grid: BM=256 -> 4x2 (per-wave 64x128, NFB=8); BM=128 -> 2x4 (64x32, NFB=2).
// 2-buffer LDS, counted vmcnt gate (= #gloads/wave/tile, never 0 mid-loop),
// stage(t+2) after all reads of buf[cur] complete. XCD-chunk block swizzle.
// EPI 0: +bias->bf16; 1: +bias,gelu->bf16; 2: +bias,+bf16 resid->bf16;
// EPI 3 (256x256): scatter q/k; V via wave-local LDS-bounce transpose.
// ---------------------------------------------------------------------------
template<int EPI, int BM, int BN>
__global__ __launch_bounds__(512, 2) void k_g8(
    const u16* __restrict__ A, const u16* __restrict__ A2, int asplit,
    const u16* __restrict__ BT,
    const float* __restrict__ bias, const u16* __restrict__ residb,
    u16* __restrict__ outb,
    u16* __restrict__ out_k, u16* __restrict__ out_v,
    int N, int K, int ldo, int coloff)
{
    constexpr int WN  = (BM == 256) ? 2 : 4;   // waves along N
    constexpr int CS  = BN / WN;               // col span per wave
    constexpr int NFB = CS / 16;               // n-fragments per wave
    constexpr int NLA = BM / 64, NLB = BN / 64;
    constexpr int NL  = NLA + NLB;             // gloads per wave per tile
    __shared__ __align__(16) u16 SH[2 * BM * 64 + 2 * BN * 64];
    u16* Asm = SH;                             // [2][BM*64]
    u16* Bsm = SH + 2 * BM * 64;               // [2][BN*64]

    const int gx = gridDim.x;
    int bid = blockIdx.y * gx + blockIdx.x;
    const int cpx = (gx * gridDim.y) >> 3;
    bid = (bid & 7) * cpx + (bid >> 3);
    const int bn = bid % gx, bm = bid / gx;

    const int t = threadIdx.x;
    const int w = t >> 6, l = t & 63;
    const int wm = w / WN, wn = w % WN;
    const int lhi = l >> 4, llo = l & 15;

    f32x4 acc[4][NFB];
    #pragma unroll
    for (int m = 0; m < 4; ++m)
        #pragma unroll
        for (int n = 0; n < NFB; ++n)
            acc[m][n] = f32x4{0.f, 0.f, 0.f, 0.f};

    const u16* Asrc = (bn * BN < asplit) ? A : A2;
    const int lr = l >> 3;
    const int lcz = ((l & 7) ^ lr) * 8;        // inverse-swizzled source chunk
    const u16* Ag = Asrc + (size_t)(bm * BM + w * 8 + lr) * K + lcz;
    const u16* Bg = BT + (size_t)(bn * BN + w * 8 + lr) * K + lcz;

    auto stage = [&](int buf, int tt) {
        const int kofs = tt << 6;
        #pragma unroll
        for (int i = 0; i < NLA; ++i)
            gload_lds16(Ag + (size_t)i * 64 * K + kofs,
                        Asm + buf * (BM * 64) + (i * 64 + w * 8) * 64);
        #pragma unroll
        for (int i = 0; i < NLB; ++i)
            gload_lds16(Bg + (size_t)i * 64 * K + kofs,
                        Bsm + buf * (BN * 64) + (i * 64 + w * 8) * 64);
    };

    const int NT = K >> 6;
    stage(0, 0);
    stage(1, 1);
    for (int tt = 0; tt < NT; ++tt) {
        const int cur = tt & 1;
        if (tt + 1 < NT) {
            if constexpr (NL == 8) asm volatile("s_waitcnt vmcnt(8)" ::: "memory");
            else                   asm volatile("s_waitcnt vmcnt(4)" ::: "memory");
        } else {
            asm volatile("s_waitcnt vmcnt(0)" ::: "memory");
        }
        __builtin_amdgcn_s_barrier();
        __builtin_amdgcn_sched_barrier(0);

        const u16* Ab = Asm + cur * (BM * 64);
        const u16* Bb = Bsm + cur * (BN * 64);
        bf16x8 af[4][2], bfr[NFB][2];
        #pragma unroll
        for (int m = 0; m < 4; ++m) {
            const int row = wm * 64 + m * 16 + llo;
            const int x = row & 7;
            af[m][0] = *(const bf16x8*)(Ab + row * 64 + ((lhi) ^ x) * 8);
            af[m][1] = *(const bf16x8*)(Ab + row * 64 + ((4 + lhi) ^ x) * 8);
        }
        #pragma unroll
        for (int n = 0; n < NFB; ++n) {
            const int row = wn * CS + n * 16 + llo;
            const int x = row & 7;
            bfr[n][0] = *(const bf16x8*)(Bb + row * 64 + ((lhi) ^ x) * 8);
            bfr[n][1] = *(const bf16x8*)(Bb + row * 64 + ((4 + lhi) ^ x) * 8);
        }
        asm volatile("s_waitcnt lgkmcnt(0)" ::: "memory");
        __builtin_amdgcn_sched_barrier(0);
        __builtin_amdgcn_s_barrier();          // all waves done reading buf[cur]
        if (tt + 2 < NT) stage(cur, tt + 2);   // safe: reads complete
        __builtin_amdgcn_s_setprio(1);
        #pragma unroll
        for (int kk = 0; kk < 2; ++kk)
            #pragma unroll
            for (int m = 0; m < 4; ++m)
                #pragma unroll
                for (int n = 0; n < NFB; ++n)
                    acc[m][n] = __builtin_amdgcn_mfma_f32_16x16x32_bf16(
                        af[m][kk], bfr[n][kk], acc[m][n], 0, 0, 0);
        __builtin_amdgcn_s_setprio(0);
        __builtin_amdgcn_sched_barrier(0);
    }

    const int colb = bn * BN + wn * CS;
    const int rowb = bm * BM + wm * 64 + lhi * 4;
    const int c0w = coloff + colb;

    if constexpr (EPI == 3 && BM == 256) {
        if (c0w >= 1024) {
            // ---- V region: per wave 2 heads x (64s x 64d) transpose via LDS ----
            __builtin_amdgcn_s_barrier();
            u16* tb = SH + w * 8192;    // 16 KB per wave
            #pragma unroll
            for (int nh = 0; nh < 2; ++nh) {
                #pragma unroll
                for (int ni = 0; ni < 4; ++ni) {
                    const int n = nh * 4 + ni;
                    const int dl = ni * 16 + llo;       // d_local 0..63
                    const float bv = bias[colb + n * 16 + llo];
                    #pragma unroll
                    for (int m = 0; m < 4; ++m) {
                        ushort4 pk;
                        #pragma unroll
                        for (int r = 0; r < 4; ++r)
                            ((u16*)&pk)[r] = f2b(acc[m][n][r] + bv);
                        const int slc = m * 2 + (lhi >> 1);
                        const int addr = nh * 4096 + dl * 64
                                       + ((slc ^ (dl & 7)) << 3) + ((lhi & 1) << 2);
                        *(ushort4*)(tb + addr) = pk;
                    }
                }
            }
            asm volatile("s_waitcnt lgkmcnt(0)" ::: "memory");
            __builtin_amdgcn_sched_barrier(0);
            const int sbase = bm * BM + wm * 64;
            const int bidx = sbase >> 9;
            const int srem = sbase & 511;
            const int cchunk = l & 7;
            #pragma unroll
            for (int nh = 0; nh < 2; ++nh) {
                const int hh = (((c0w >> 6) + nh) & 7);
                u16* vo = out_v + ((size_t)bidx * 8 + hh) * 32768 + srem;
                #pragma unroll
                for (int rr = 0; rr < 8; ++rr) {
                    const int dl2 = (l >> 3) + rr * 8;
                    const int ch = cchunk ^ (dl2 & 7);
                    bf16x8 vv = *(const bf16x8*)(tb + nh * 4096 + dl2 * 64 + ch * 8);
                    *(bf16x8*)(vo + (size_t)dl2 * 512 + cchunk * 8) = vv;
                }
            }
            return;
        }
    }

    #pragma unroll
    for (int n = 0; n < NFB; ++n) {
        const int col = colb + n * 16 + llo;
        const float bv = bias[col];
        #pragma unroll
        for (int m = 0; m < 4; ++m) {
            const int row = rowb + m * 16;
            if (EPI == 3) {
                float vv[4];
                #pragma unroll
                for (int r = 0; r < 4; ++r) vv[r] = acc[m][n][r] + bv;
                const int c = coloff + col;
                if ((c >> 9) == 0) {
                    #pragma unroll
                    for (int r = 0; r < 4; ++r)
                        outb[(size_t)(row + r) * 512 + c] = f2b(vv[r]);
                } else {
                    const int hh = (c >> 6) & 7, d = c & 63;
                    #pragma unroll
                    for (int r = 0; r < 4; ++r) {
                        const int rr = row + r;
                        out_k[((size_t)(rr >> 9) * 8 + hh) * 32768 + (rr & 511) * 64 + d] = f2b(vv[r]);
                    }
                }
            } else {
                #pragma unroll
                for (int r = 0; r < 4; ++r) {
                    float v = acc[m][n][r] + bv;
                    const size_t off = (size_t)(row + r) * ldo + coloff + col;
                    if (EPI == 0) {
                        outb[off] = f2b(v);
                    } else if (EPI == 1) {
                        v = 0.5f * v * (1.f + erff(v * 0.70710678118654752f));
                        outb[off] = f2b(v);
                    } else {  // EPI == 2: + bf16 residual -> bf16
                        v += b2f(residb[off]);
                        outb[off] = f2b(v);
                    }
                }
            }
        }
    }
}

// ---------------------------------------------------------------------------
// Fused flash attention, swapped QK^T, block-level LDS K/V staging,
// double-buffered with counted vmcnt (unchanged).
// ---------------------------------------------------------------------------
template<int DEC>
__global__ __launch_bounds__(256) void k_attn(
    const u16* __restrict__ qb, const u16* __restrict__ kc,
    const u16* __restrict__ vtp, const int* __restrict__ lengths,
    u16* __restrict__ out)
{
    __shared__ __align__(16) u16 Ks[2][64 * 64];
    __shared__ __align__(16) u16 Vs[2][64 * 64];
    __shared__ __align__(16) u16 plds[4][16][64];
    __shared__ float alds[4][16];
    __shared__ float llds[4][16];
    const int qt = blockIdx.x;
    const int bh = blockIdx.y;
    const int b = bh >> 3;
    const int h = bh & 7;
    const int t = threadIdx.x, w = t >> 6, l = t & 63;
    const int lhi = l >> 4, llo = l & 15;
    const int len = lengths[b];
    const int qrow0 = qt * 64 + w * 16;
    const int q = qrow0 + llo;

    const u16* qp = qb + (size_t)(b * TS + q) * 512 + h * 64 + lhi * 8;
    bf16x8 qf0 = *(const bf16x8*)(qp);
    bf16x8 qf1 = *(const bf16x8*)(qp + 32);

    const u16* kb = kc  + (size_t)bh * 32768;
    const u16* vb = vtp + (size_t)bh * 32768;

    const int qlim = DEC ? min(max(q, 1), len) : len;
    const int limb = DEC ? min(qt * 64 + 63, len) : len;
    const int ktend = (limb + 63) >> 6;

    f32x4 o[4];
    #pragma unroll
    for (int g = 0; g < 4; ++g) o[g] = f32x4{0.f, 0.f, 0.f, 0.f};
    float mrun = -1e30f, lrun = 0.f;

    const float SC = 0.18033688011112042f;  // 0.125 * log2(e)

    const int sr = w * 8 + (l >> 3);
    const int sc = (((l & 7) ^ (sr & 7)) << 3);
    auto stage = [&](int buf, int ktt) {
        gload_lds16(kb + ((ktt * 64 + sr) << 6) + sc,        &Ks[buf][(w * 8) * 64]);
        gload_lds16(kb + ((ktt * 64 + 32 + sr) << 6) + sc,   &Ks[buf][(32 + w * 8) * 64]);
        gload_lds16(vb + (size_t)sr * 512 + ktt * 64 + sc,   &Vs[buf][(w * 8) * 64]);
        gload_lds16(vb + (size_t)(32 + sr) * 512 + ktt * 64 + sc, &Vs[buf][(32 + w * 8) * 64]);
    };

    stage(0, 0);
    for (int kt = 0; kt < ktend; ++kt) {
        const int cur = kt & 1;
        if (kt + 1 < ktend) {
            stage(cur ^ 1, kt + 1);
            asm volatile("s_waitcnt vmcnt(4)" ::: "memory");
        } else {
            asm volatile("s_waitcnt vmcnt(0)" ::: "memory");
        }
        __builtin_amdgcn_s_barrier();
        __builtin_amdgcn_sched_barrier(0);

        bf16x8 kf[4][2], vf[4][2];
        #pragma unroll
        for (int g = 0; g < 4; ++g) {
            const int row = g * 16 + llo;
            const int x = row & 7;
            kf[g][0] = *(const bf16x8*)&Ks[cur][row * 64 + ((lhi) ^ x) * 8];
            kf[g][1] = *(const bf16x8*)&Ks[cur][row * 64 + ((4 + lhi) ^ x) * 8];
            vf[g][0] = *(const bf16x8*)&Vs[cur][row * 64 + ((lhi) ^ x) * 8];
            vf[g][1] = *(const bf16x8*)&Vs[cur][row * 64 + ((4 + lhi) ^ x) * 8];
        }
        f32x4 s[4];
        #pragma unroll
        for (int g = 0; g < 4; ++g) {
            s[g] = f32x4{0.f, 0.f, 0.f, 0.f};
            s[g] = __builtin_amdgcn_mfma_f32_16x16x32_bf16(kf[g][0], qf0, s[g], 0, 0, 0);
            s[g] = __builtin_amdgcn_mfma_f32_16x16x32_bf16(kf[g][1], qf1, s[g], 0, 0, 0);
        }
        #pragma unroll
        for (int g = 0; g < 4; ++g) {
            const int key = kt * 64 + g * 16 + lhi * 4;
            #pragma unroll
            for (int r = 0; r < 4; ++r)
                s[g][r] = (key + r < qlim) ? s[g][r] * SC : -1e30f;
        }
        float tm = fmaxf(fmaxf(fmaxf(s[0][0], s[0][1]), fmaxf(s[0][2], s[0][3])),
                         fmaxf(fmaxf(s[1][0], s[1][1]), fmaxf(s[1][2], s[1][3])));
        tm = fmaxf(tm, fmaxf(fmaxf(fmaxf(s[2][0], s[2][1]), fmaxf(s[2][2], s[2][3])),
                             fmaxf(fmaxf(s[3][0], s[3][1]), fmaxf(s[3][2], s[3][3]))));
        tm = fmaxf(tm, __shfl_xor(tm, 16));
        tm = fmaxf(tm, __shfl_xor(tm, 32));
        const float mnew = fmaxf(mrun, tm);
        const float alpha = exp2f(mrun - mnew);
        mrun = mnew;
        float rs = 0.f;
        ushort4 pk[4];
        #pragma unroll
        for (int g = 0; g < 4; ++g) {
            #pragma unroll
            for (int r = 0; r < 4; ++r) {
                const float p = exp2f(s[g][r] - mnew);
                rs += p;
                ((u16*)&pk[g])[r] = f2b(p);
            }
        }
        rs += __shfl_xor(rs, 16);
        rs += __shfl_xor(rs, 32);
        lrun = lrun * alpha + rs;
        if (lhi == 0) alds[w][llo] = alpha;
        #pragma unroll
        for (int g = 0; g < 4; ++g) {
            const int chw = (g * 2 + (lhi >> 1)) ^ (llo & 7);
            *(ushort4*)((char*)&plds[w][0][0] + llo * 128 + chw * 16 + (lhi & 1) * 8) = pk[g];
        }
        const float4 av = *(const float4*)&alds[w][lhi * 4];
        #pragma unroll
        for (int g = 0; g < 4; ++g) {
            o[g][0] *= av.x; o[g][1] *= av.y; o[g][2] *= av.z; o[g][3] *= av.w;
        }
        #pragma unroll
        for (int ks = 0; ks < 2; ++ks) {
            const int chr = (ks * 4 + lhi) ^ (llo & 7);
            bf16x8 pa = *(const bf16x8*)((const char*)&plds[w][0][0] + llo * 128 + chr * 16);
            #pragma unroll
            for (int g = 0; g < 4; ++g)
                o[g] = __builtin_amdgcn_mfma_f32_16x16x32_bf16(pa, vf[g][ks], o[g], 0, 0, 0);
        }
        __builtin_amdgcn_sched_barrier(0);
        __builtin_amdgcn_s_barrier();
    }

    if (lhi == 0) llds[w][llo] = 1.f / lrun;
    __builtin_amdgcn_s_waitcnt(0);
    const float4 linv = *(const float4*)&llds[w][lhi * 4];
    #pragma unroll
    for (int g = 0; g < 4; ++g) {
        const int d = h * 64 + g * 16 + llo;
        #pragma unroll
        for (int r = 0; r < 4; ++r) {
            const int qq = qrow0 + lhi * 4 + r;
            out[(size_t)(b * TS + qq) * 512 + d] = f2b(o[g][r] * ((const float*)&linv)[r]);
        }
    }
}

// ---------------------------------------------------------------------------
// LayerNorm over F=512, bf16 in -> bf16 out; one wave per row.
// Optional fused row-dot against a 512-f32 vector (on pre-rounding f32 y).
// ---------------------------------------------------------------------------
__global__ __launch_bounds__(256) void k_ln(
    const u16* __restrict__ in, const float* __restrict__ gam,
    const float* __restrict__ bet, u16* __restrict__ o16,
    const float* __restrict__ dotv, float* __restrict__ dotout)
{
    const int row = blockIdx.x * 4 + (threadIdx.x >> 6);
    const int l = threadIdx.x & 63;
    bf16x8 vin = *(const bf16x8*)(in + (size_t)row * 512 + l * 8);
    float x[8];
    #pragma unroll
    for (int i = 0; i < 8; ++i) x[i] = b2f((u16)vin[i]);
    float s = x[0] + x[1] + x[2] + x[3] + x[4] + x[5] + x[6] + x[7];
    #pragma unroll
    for (int off = 32; off; off >>= 1) s += __shfl_xor(s, off);
    const float mu = s * (1.f / 512.f);
    float v = 0.f;
    #pragma unroll
    for (int i = 0; i < 8; ++i) { const float d = x[i] - mu; v += d * d; }
    #pragma unroll
    for (int off = 32; off; off >>= 1) v += __shfl_xor(v, off);
    const float rstd = rsqrtf(v * (1.f / 512.f) + 1e-5f);
    float gg[8], bb[8];
    *(float4*)&gg[0] = *(const float4*)(gam + l * 8);
    *(float4*)&gg[4] = *(const float4*)(gam + l * 8 + 4);
    *(float4*)&bb[0] = *(const float4*)(bet + l * 8);
    *(float4*)&bb[4] = *(const float4*)(bet + l * 8 + 4);
    float y[8];
    #pragma unroll
    for (int i = 0; i < 8; ++i) y[i] = (x[i] - mu) * rstd * gg[i] + bb[i];
    ushort4 pk0, pk1;
    pk0.x = f2b(y[0]); pk0.y = f2b(y[1]); pk0.z = f2b(y[2]); pk0.w = f2b(y[3]);
    pk1.x = f2b(y[4]); pk1.y = f2b(y[5]); pk1.z = f2b(y[6]); pk1.w = f2b(y[7]);
    ushort4* o16p = (ushort4*)(o16 + (size_t)row * 512 + l * 8);
    o16p[0] = pk0; o16p[1] = pk1;
    if (dotv) {
        float wa[8];
        *(float4*)&wa[0] = *(const float4*)(dotv + l * 8);
        *(float4*)&wa[4] = *(const float4*)(dotv + l * 8 + 4);
        float ds = 0.f;
        #pragma unroll
        for (int i = 0; i < 8; ++i) ds += y[i] * wa[i];
        #pragma unroll
        for (int off = 32; off; off >>= 1) ds += __shfl_xor(ds, off);
        if (l == 0) dotout[row] = ds;
    }
}

// ---------------------------------------------------------------------------
__global__ __launch_bounds__(256) void k_ptr_out(
    const float* __restrict__ wq, const float* __restrict__ wk, float* __restrict__ out)
{
    const int bi = blockIdx.x;
    const int b = bi >> 9;
    const float wki = wk[bi];
    #pragma unroll
    for (int j = threadIdx.x; j < 512; j += 256) {
        float r = 0.f;
        if (j != 0) {
            const float z = (wq[b * 512 + j] + wki) * 0.044194173824159216f;
            r = 1.f / (1.f + __expf(-z));
        }
        out[(size_t)bi * 512 + j] = r;
    }
}

// ---------------------------------------------------------------------------
extern "C" void kernel_launch(void* const* d_in, const int* in_sizes, int n_in,
                              void* d_out, int out_size, void* d_ws, size_t ws_size,
                              hipStream_t stream)
{
    const float* emb = (const float*)d_in[0];
    const int* lengths = (const int*)d_in[1];
    struct Pw {
        const float *wqkv, *bqkv, *wo, *bo, *ln1g, *ln1b, *w1, *b1, *w2, *b2, *ln2g, *ln2b;
    } pp[2];
    for (int p = 0; p < 2; ++p) {
        const int base = 2 + p * 12;
        pp[p].wqkv = (const float*)d_in[base + 0];
        pp[p].bqkv = (const float*)d_in[base + 1];
        pp[p].wo   = (const float*)d_in[base + 2];
        pp[p].bo   = (const float*)d_in[base + 3];
        pp[p].ln1g = (const float*)d_in[base + 4];
        pp[p].ln1b = (const float*)d_in[base + 5];
        pp[p].w1   = (const float*)d_in[base + 6];
        pp[p].b1   = (const float*)d_in[base + 7];
        pp[p].w2   = (const float*)d_in[base + 8];
        pp[p].b2   = (const float*)d_in[base + 9];
        pp[p].ln2g = (const float*)d_in[base + 10];
        pp[p].ln2b = (const float*)d_in[base + 11];
    }
    const float* pwq = (const float*)d_in[26];
    const float* pwk = (const float*)d_in[27];

    char* ws = (char*)d_ws;
    auto alloc = [&](size_t bytes) {
        char* p = ws;
        ws += (bytes + 255) & ~(size_t)255;
        return p;
    };
    u16* wqkvT[2], *woT[2], *w1T[2], *w2T[2];
    for (int p = 0; p < 2; ++p) {
        wqkvT[p] = (u16*)alloc((size_t)TL * 1536 * 512 * 2);
        woT[p]   = (u16*)alloc((size_t)TL * 512 * 512 * 2);
        w1T[p]   = (u16*)alloc((size_t)TL * 2048 * 512 * 2);
        w2T[p]   = (u16*)alloc((size_t)TL * 512 * 2048 * 2);
    }
    const size_t MR = (size_t)TB * TS;  // 8192 rows
    u16*   emb16 = (u16*)alloc(MR * 512 * 2);
    u16*   x16   = (u16*)alloc(MR * 512 * 2);
    u16*   mem16 = (u16*)alloc(MR * 512 * 2);
    u16*   pre16 = (u16*)alloc(MR * 512 * 2);
    u16*   qbuf  = (u16*)alloc(MR * 512 * 2);
    u16*   kcb   = (u16*)alloc((size_t)TB * TH * 512 * 64 * 2);
    u16*   vtb   = (u16*)alloc((size_t)TB * TH * 64 * 512 * 2);
    u16*   att16 = (u16*)alloc(MR * 512 * 2);
    u16*   h16   = (u16*)alloc(MR * 2048 * 2);
    float* wqb   = (float*)alloc(MR * 4);
    float* wkb   = (float*)alloc(MR * 4);

    for (int p = 0; p < 2; ++p) {
        k_transpose_w<<<dim3(16, 16, 9), 256, 0, stream>>>(pp[p].wqkv, wqkvT[p], 512, 512);
        k_transpose_w<<<dim3(16, 16, 3), 256, 0, stream>>>(pp[p].wo, woT[p], 512, 512);
        k_transpose_w<<<dim3(64, 16, 3), 256, 0, stream>>>(pp[p].w1, w1T[p], 512, 2048);
        k_transpose_w<<<dim3(16, 64, 3), 256, 0, stream>>>(pp[p].w2, w2T[p], 2048, 512);
    }

    const int n4 = (int)(MR * 512 / 4);
    k_cvt<<<4096, 256, 0, stream>>>(emb, emb16, n4);

    // ---------------- encoder ----------------
    for (int i = 0; i < TL; ++i) {
        const u16* xin = (i == 0) ? emb16 : x16;
        k_g8<3, 256, 256><<<dim3(6, 32), 512, 0, stream>>>(
            xin, xin, 1536, wqkvT[0] + (size_t)i * 1536 * 512, pp[0].bqkv + i * 1536,
            nullptr, qbuf, kcb, vtb, 1536, 512, 1536, 0);
        k_attn<0><<<dim3(8, 128), 256, 0, stream>>>(qbuf, kcb, vtb, lengths, att16);
        k_g8<2, 128, 128><<<dim3(4, 64), 512, 0, stream>>>(
            att16, att16, 512, woT[0] + (size_t)i * 512 * 512, pp[0].bo + i * 512,
            xin, pre16, nullptr, nullptr, 512, 512, 512, 0);
        k_ln<<<2048, 256, 0, stream>>>(pre16, pp[0].ln1g + i * 512, pp[0].ln1b + i * 512,
                                       x16, nullptr, nullptr);
        k_g8<1, 256, 256><<<dim3(8, 32), 512, 0, stream>>>(
            x16, x16, 2048, w1T[0] + (size_t)i * 2048 * 512, pp[0].b1 + i * 2048,
            nullptr, h16, nullptr, nullptr, 2048, 512, 2048, 0);
        k_g8<2, 128, 128><<<dim3(4, 64), 512, 0, stream>>>(
            h16, h16, 512, w2T[0] + (size_t)i * 512 * 2048, pp[0].b2 + i * 512,
            x16, pre16, nullptr, nullptr, 512, 2048, 512, 0);
        if (i == TL - 1)
            k_ln<<<2048, 256, 0, stream>>>(pre16, pp[0].ln2g + i * 512, pp[0].ln2b + i * 512,
                                           mem16, pwk, wkb);
        else
            k_ln<<<2048, 256, 0, stream>>>(pre16, pp[0].ln2g + i * 512, pp[0].ln2b + i * 512,
                                           x16, nullptr, nullptr);
    }

    // ---------------- decoder ----------------
    for (int i = 0; i < TL; ++i) {
        const u16* yin = (i == 0) ? emb16 : x16;
        k_g8<3, 256, 256><<<dim3(6, 32), 512, 0, stream>>>(
            yin, mem16, 512, wqkvT[1] + (size_t)i * 1536 * 512, pp[1].bqkv + i * 1536,
            nullptr, qbuf, kcb, vtb, 1536, 512, 1536, 0);
        k_attn<1><<<dim3(8, 128), 256, 0, stream>>>(qbuf, kcb, vtb, lengths, att16);
        k_g8<2, 128, 128><<<dim3(4, 64), 512, 0, stream>>>(
            att16, att16, 512, woT[1] + (size_t)i * 512 * 512, pp[1].bo + i * 512,
            yin, pre16, nullptr, nullptr, 512, 512, 512, 0);
        k_ln<<<2048, 256, 0, stream>>>(pre16, pp[1].ln1g + i * 512, pp[1].ln1b + i * 512,
                                       x16, nullptr, nullptr);
        k_g8<1, 256, 256><<<dim3(8, 32), 512, 0, stream>>>(
            x16, x16, 2048, w1T[1] + (size_t)i * 2048 * 512, pp[1].b1 + i * 2048,
            nullptr, h16, nullptr, nullptr, 2048, 512, 2048, 0);
        k_g8<2, 128, 128><<<dim3(4, 64), 512, 0, stream>>>(
            h16, h16, 512, w2T[1] + (size_t)i * 512 * 2048, pp[1].b2 + i * 512,
            x16, pre16, nullptr, nullptr, 512, 2048, 512, 0);
        if (i == TL - 1)
            k_ln<<<2048, 256, 0, stream>>>(pre16, pp[1].ln2g + i * 512, pp[1].ln2b + i * 512,
                                           x16, pwq, wqb);
        else
            k_ln<<<2048, 256, 0, stream>>>(pre16, pp[1].ln2g + i * 512, pp[1].ln2b + i * 512,
                                           x16, nullptr, nullptr);
    }

    // ---------------- pointer head ----------------
    k_ptr_out<<<TB * TS, 256, 0, stream>>>(wqb, wkb, (float*)d_out);
}